// Round 6
// baseline (478.359 us; speedup 1.0000x reference)
//
#include <hip/hip_runtime.h>

#define NH 16
#define DM 1024
#define SQ 2048
#define BT 4

typedef __attribute__((ext_vector_type(8))) short bf16x8;
typedef __attribute__((ext_vector_type(4))) short sh4;
typedef __attribute__((ext_vector_type(4))) float f4;
typedef __attribute__((ext_vector_type(4))) float fv4;
typedef __attribute__((ext_vector_type(4))) unsigned uv4;
typedef unsigned short u16;

#define M2BIAS 23.083120654f   /* 16 * log2(e) */
#define SCALE2 0.18033688f     /* (1/8) * log2(e) */

__device__ __forceinline__ u16 f2bf(float f) {
    union { float f; unsigned u; } v; v.f = f;
    unsigned r = v.u + 0x7FFFu + ((v.u >> 16) & 1u);
    return (u16)(r >> 16);
}

__device__ __forceinline__ float fast_exp2(float x) {
#if __has_builtin(__builtin_amdgcn_exp2f)
    return __builtin_amdgcn_exp2f(x);
#else
    return exp2f(x);
#endif
}

// Key-position permutation: actual key s (within a 32-key group, s = 8q+4t+j)
// -> LDS/position index p = 16t + 4q + j. Makes the S^T output of two 16-key
// tiles land exactly in the A-fragment layout of mfma_f32_16x16x32_bf16
// (A[m=l16][k=8*quad+j] over actual keys), so PV needs no cross-lane exchange.
__device__ __forceinline__ int prem(int s) {
    return (s & ~31) | ((s & 4) << 2) | ((s >> 1) & 12) | (s & 3);
}

#define GLD16(gp, lp) __builtin_amdgcn_global_load_lds( \
    (const __attribute__((address_space(1))) void*)(gp), \
    (__attribute__((address_space(3))) void*)(lp), 16, 0, 0)

// ---------------- fp32 W[K][N] -> bf16 Wt[N][K], all three weights in one launch ----------------
__global__ __launch_bounds__(256) void cvt_wT3(const float* __restrict__ W0, const float* __restrict__ W1,
                                               const float* __restrict__ W2, u16* __restrict__ Wt) {
    __shared__ float t[64][65];
    const float* Wsrc = blockIdx.z == 0 ? W0 : (blockIdx.z == 1 ? W1 : W2);
    u16* dst = Wt + (size_t)blockIdx.z * DM * DM;
    int r0 = blockIdx.x * 64, c0 = blockIdx.y * 64;
    #pragma unroll
    for (int i = 0; i < 16; ++i) {
        int idx = i * 256 + threadIdx.x;
        int r = idx >> 6, c = idx & 63;
        t[r][c] = Wsrc[(size_t)(r0 + r) * DM + c0 + c];
    }
    __syncthreads();
    #pragma unroll
    for (int i = 0; i < 16; ++i) {
        int idx = i * 256 + threadIdx.x;
        int n = idx >> 6, k = idx & 63;
        dst[(size_t)(c0 + n) * DM + r0 + k] = f2bf(t[k][n]);
    }
}

// ---------------- mask -> float bias, stored at PERMUTED key position ----------------
__global__ __launch_bounds__(256) void mk_mbias(const int* __restrict__ mask, float* __restrict__ mb) {
    int i = blockIdx.x * 256 + threadIdx.x;
    mb[prem(i)] = mask[i] ? -M2BIAS : -__builtin_inff();
}

// ---------------- fused projection GEMMs: z in {Q,K,V}, [8192,1024]x[1024,1024]+bias ----------------
// A is read DIRECTLY as fp32 and converted to bf16 in registers during staging.
// DISTANCE-2 A-PREFETCH: round-5's counted-vmcnt left dur unchanged because the
// real stall was the compiler's implicit wait before the converts — A(kt) was
// issued only one iteration earlier (~600 cyc of cover vs ~900-1200 cyc HBM
// latency). Two register sets arA/arB (static indexing) let loadA(kt+2) be
// issued in iteration kt, giving every A tile two full iterations of cover.
// Wait accounting per sub-iteration k (verified for all k):
//   converts' implicit wait for A(k) leaves {B(k),A(k+1),B(k+1)} in flight;
//   pre-MFMA barrier only needs B(k) in LDS -> vmcnt(20) for k<=13
//   (outstanding B(k)4+A(k+1)8+B(k+1)4+A(k+2)8=24, drain exactly B(k) which is
//   a full iteration old), vmcnt(12) at k=14, vmcnt(0) at k=15 (peeled tail).
// z=0: Q -> [b][h][s][d];  z=1: K -> [b][h][prem(s)][d];  z=2: V -> [b][h][d][s]
__global__ __launch_bounds__(256, 3) void gemm3(const float* __restrict__ Qf, const float* __restrict__ Kf,
                                                const float* __restrict__ Vf, const u16* __restrict__ Wt3,
                                                const float* __restrict__ bq, const float* __restrict__ bk,
                                                const float* __restrict__ bv, u16* __restrict__ out3) {
    __shared__ u16 As[128 * 64];
    __shared__ u16 Bs[2][128 * 64];
    int z = blockIdx.z;
    const float* Af = z == 0 ? Qf : (z == 1 ? Kf : Vf);
    const float* bias = z == 0 ? bq : (z == 1 ? bk : bv);
    int vmode = z == 0 ? 0 : (z == 1 ? 2 : 1);
    const u16* Bg = Wt3 + (size_t)z * DM * DM + (size_t)blockIdx.y * 128 * DM;
    u16* outp = out3 + (size_t)z * 8388608u;   // 8192*1024 u16 per projection

    int tid = threadIdx.x;
    int w = tid >> 6, lane = tid & 63, quad = lane >> 4, l16 = lane & 15;
    int wm = w >> 1, wn = w & 1;
    int r8 = lane >> 3, cg = (lane & 7) ^ r8;

    // A reg-staging: load j covers rows arow0 + j*4 (j=0..7), 16 lanes span the
    // 64-wide fp32 K-slice (4 fp32 = 16B per lane; 4 rows x 256B per instr).
    int arow0 = w * 32 + (lane >> 4);
    int acol = (lane & 15) * 4;
    const float* Ag = Af + (size_t)(blockIdx.x * 128 + arow0) * DM + acol;
    int ach = (lane & 15) >> 1, asub = lane & 1;

    f4 acc[4][4];
    #pragma unroll
    for (int mt = 0; mt < 4; ++mt)
        #pragma unroll
        for (int nt = 0; nt < 4; ++nt) acc[mt][nt] = f4{0.f, 0.f, 0.f, 0.f};

    fv4 arA[8], arB[8];
    auto stageB = [&](int buf, int kt) {
        int kofs = kt * 64 + cg * 8;
        #pragma unroll
        for (int c = 0; c < 4; ++c) {
            int rbase = w * 32 + c * 8;
            GLD16(Bg + (size_t)(rbase + r8) * DM + kofs, &Bs[buf][rbase * 64]);
        }
    };

#define LOADA(ar, kt) do { \
        const float* _src = Ag + (kt) * 64; \
        _Pragma("unroll") \
        for (int j = 0; j < 8; ++j) (ar)[j] = *(const fv4*)(_src + (size_t)j * 4 * DM); \
    } while (0)

#define CVTA(ar) do { \
        _Pragma("unroll") \
        for (int j = 0; j < 8; ++j) { \
            unsigned lo, hi; \
            asm("v_cvt_pk_bf16_f32 %0, %1, %2" : "=v"(lo) : "v"((ar)[j][0]), "v"((ar)[j][1])); \
            asm("v_cvt_pk_bf16_f32 %0, %1, %2" : "=v"(hi) : "v"((ar)[j][2]), "v"((ar)[j][3])); \
            int row = arow0 + j * 4; \
            uint2 pk; pk.x = lo; pk.y = hi; \
            *(uint2*)&As[row * 64 + (ach ^ (row & 7)) * 8 + asub * 4] = pk; \
        } \
    } while (0)

#define MFMAPHASE(bufidx) do { \
        _Pragma("unroll") \
        for (int ks = 0; ks < 2; ++ks) { \
            bf16x8 afr[4], bfr[4]; \
            _Pragma("unroll") \
            for (int mt = 0; mt < 4; ++mt) { \
                int row = wm * 64 + mt * 16 + l16; \
                int ch = (ks * 4 + quad) ^ (row & 7); \
                afr[mt] = *(const bf16x8*)&As[row * 64 + ch * 8]; \
            } \
            _Pragma("unroll") \
            for (int nt = 0; nt < 4; ++nt) { \
                int row = wn * 64 + nt * 16 + l16; \
                int ch = (ks * 4 + quad) ^ (row & 7); \
                bfr[nt] = *(const bf16x8*)&Bs[bufidx][row * 64 + ch * 8]; \
            } \
            _Pragma("unroll") \
            for (int mt = 0; mt < 4; ++mt) \
                _Pragma("unroll") \
                for (int nt = 0; nt < 4; ++nt) \
                    acc[mt][nt] = __builtin_amdgcn_mfma_f32_16x16x32_bf16(afr[mt], bfr[nt], acc[mt][nt], 0, 0, 0); \
        } \
    } while (0)

// One K-step: prefetch B(k+1), convert A(k)->LDS (implicit wait for A(k)),
// prefetch A(k+2), counted-wait + barrier, MFMA, barrier.
#define SUBITER(k, ar, VM) do { \
        if ((k) + 1 < 16) stageB(((k) + 1) & 1, (k) + 1); \
        CVTA(ar); \
        if ((k) + 2 < 16) LOADA(ar, (k) + 2); \
        asm volatile("s_waitcnt vmcnt(" #VM ") lgkmcnt(0)" ::: "memory"); \
        __builtin_amdgcn_s_barrier(); \
        asm volatile("" ::: "memory"); \
        MFMAPHASE((k) & 1); \
        asm volatile("" ::: "memory"); \
        __builtin_amdgcn_s_barrier(); \
        asm volatile("" ::: "memory"); \
    } while (0)

    stageB(0, 0);
    LOADA(arA, 0);
    LOADA(arB, 1);

    for (int k = 0; k < 14; k += 2) {
        SUBITER(k, arA, 20);
        SUBITER(k + 1, arB, 20);
    }
    SUBITER(14, arA, 12);
    SUBITER(15, arB, 0);

#undef SUBITER
#undef MFMAPHASE
#undef CVTA
#undef LOADA

    #pragma unroll
    for (int nt = 0; nt < 4; ++nt) {
        int ncol = blockIdx.y * 128 + wn * 64 + nt * 16 + l16;
        float bn = bias[ncol];
        int h = ncol >> 6, d = ncol & 63;
        #pragma unroll
        for (int mt = 0; mt < 4; ++mt) {
            int mbase = blockIdx.x * 128 + wm * 64 + mt * 16 + quad * 4;
            int bidx = mbase >> 11, s0 = mbase & 2047;
            if (vmode == 1) {
                sh4 pk;
                #pragma unroll
                for (int reg = 0; reg < 4; ++reg) pk[reg] = (short)f2bf(acc[mt][nt][reg] + bn);
                *(sh4*)&outp[(((size_t)bidx * NH + h) * 64 + d) * SQ + s0] = pk;
            } else {
                int sp = (vmode == 2) ? prem(s0) : s0;   // prem(s0+reg) == prem(s0)+reg for 4-aligned s0
                size_t base = ((size_t)bidx * NH + h) * SQ;
                #pragma unroll
                for (int reg = 0; reg < 4; ++reg)
                    outp[(base + sp + reg) * 64 + d] = f2bf(acc[mt][nt][reg] + bn);
            }
        }
    }
}

// ---------------- flash attention (S^T form, register-resident P, K=32 PV) ----------------
// S^T = K*Q^T with K rows stored in permuted position space: lane(quad,l16)'s
// S-regs over tile pair (2g,2g+1) hold actual keys g*32 + 8*quad + 0..7 for
// q-row l16 — exactly the A-fragment of mfma_f32_16x16x32_bf16. PV thus runs
// at K=32 (16 MFMAs/iter instead of 32 K=16 MFMAs), B = V^T b128 fragments.
// P is packed to bf16 IMMEDIATELY after exp2 (per 32-key group) so the f32
// scores die before PV — keeps peak live VGPRs under the 4-wave/EU cap.
__global__ __launch_bounds__(256, 4) void attn(const u16* __restrict__ qw, const u16* __restrict__ kw,
                                               const u16* __restrict__ vtw, const float* __restrict__ mbias,
                                               float* __restrict__ outp) {
    __shared__ u16 Ks[2][64 * 64];   // [key-position][64 d], 16B-chunk XOR swizzled
    __shared__ u16 Vs[2][64 * 64];   // [d][64 keys], 16B-chunk XOR swizzled
    int tid = threadIdx.x;
    int w = tid >> 6, lane = tid & 63, quad = lane >> 4, l16 = lane & 15;
    int r8 = lane >> 3, sl = lane & 7;
    int bh = blockIdx.x, b = bh >> 4;   // grid.x = bh for XCD L2 locality
    int h = bh & 15;
    int qbase = blockIdx.y * 128 + w * 32;
    const u16* qp = qw + (size_t)bh * SQ * 64;
    const u16* kp = kw + (size_t)bh * SQ * 64;
    const u16* vp = vtw + (size_t)bh * 64 * SQ;
    const float* mbp = mbias + b * SQ;

    bf16x8 aq[2][2];  // Q frags (B-operand of S^T)
    #pragma unroll
    for (int mt = 0; mt < 2; ++mt)
        #pragma unroll
        for (int ks = 0; ks < 2; ++ks)
            aq[mt][ks] = *(const bf16x8*)&qp[(size_t)(qbase + mt * 16 + l16) * 64 + ks * 32 + quad * 8];

    f4 o[2][4];
    float lrow[2] = {0.f, 0.f};  // per-lane partial row-sum for q-row l16
    #pragma unroll
    for (int mt = 0; mt < 2; ++mt)
        #pragma unroll
        for (int nt = 0; nt < 4; ++nt) o[mt][nt] = f4{0.f, 0.f, 0.f, 0.f};

    auto stage = [&](int buf, int k0) {
        #pragma unroll
        for (int j = 0; j < 2; ++j) {
            int row = w * 16 + j * 8 + r8;
            int gsl = sl ^ (row & 7);
            GLD16(kp + (size_t)(k0 + row) * 64 + gsl * 8, &Ks[buf][(w * 16 + j * 8) * 64]);
            GLD16(vp + (size_t)row * SQ + k0 + gsl * 8, &Vs[buf][(w * 16 + j * 8) * 64]);
        }
    };

    stage(0, 0);
    for (int kb = 0; kb < 32; ++kb) {
        int buf = kb & 1;
        int k0 = kb * 64;
        __syncthreads();  // staging of `buf` done; all waves done reading buf^1
        // mask-bias loads BEFORE the prefetch so their vmcnt wait doesn't drain it
        fv4 bias4[4];
        #pragma unroll
        for (int kt = 0; kt < 4; ++kt)
            bias4[kt] = *(const fv4*)&mbp[k0 + kt * 16 + quad * 4];
        if (kb + 1 < 32) stage(buf ^ 1, k0 + 64);

        // K frags (A-operand of S^T)
        bf16x8 bk[4][2];
        #pragma unroll
        for (int kt = 0; kt < 4; ++kt)
            #pragma unroll
            for (int ks = 0; ks < 2; ++ks) {
                int r = kt * 16 + l16;
                int slot = (ks * 4 + quad) ^ (r & 7);
                bk[kt][ks] = *(const bf16x8*)&Ks[buf][r * 64 + slot * 8];
            }
        // S^T[kt][mt]: lane(quad,l16) regs = key-positions 16kt+4quad+r, q-row = l16
        f4 S[4][2];
        #pragma unroll
        for (int kt = 0; kt < 4; ++kt)
            #pragma unroll
            for (int mt = 0; mt < 2; ++mt) {
                f4 s = f4{0.f, 0.f, 0.f, 0.f};
                s = __builtin_amdgcn_mfma_f32_16x16x32_bf16(bk[kt][0], aq[mt][0], s, 0, 0, 0);
                s = __builtin_amdgcn_mfma_f32_16x16x32_bf16(bk[kt][1], aq[mt][1], s, 0, 0, 0);
                S[kt][mt] = s;
            }
        // softmax numerator + IMMEDIATE bf16 pack: per 32-key group g, the tile
        // pair (2g,2g+1) becomes one A-fragment pa8[g][mt] (keys g*32+8q+0..7).
        bf16x8 pa8[2][2];
        #pragma unroll
        for (int g = 0; g < 2; ++g)
            #pragma unroll
            for (int mt = 0; mt < 2; ++mt) {
                f4 se = S[2 * g][mt], so = S[2 * g + 1][mt];
                float p0 = fast_exp2(se[0] * SCALE2 + bias4[2 * g][0]);
                float p1 = fast_exp2(se[1] * SCALE2 + bias4[2 * g][1]);
                float p2 = fast_exp2(se[2] * SCALE2 + bias4[2 * g][2]);
                float p3 = fast_exp2(se[3] * SCALE2 + bias4[2 * g][3]);
                float q0 = fast_exp2(so[0] * SCALE2 + bias4[2 * g + 1][0]);
                float q1 = fast_exp2(so[1] * SCALE2 + bias4[2 * g + 1][1]);
                float q2 = fast_exp2(so[2] * SCALE2 + bias4[2 * g + 1][2]);
                float q3 = fast_exp2(so[3] * SCALE2 + bias4[2 * g + 1][3]);
                lrow[mt] += ((p0 + p1) + (p2 + p3)) + ((q0 + q1) + (q2 + q3));
                uv4 wv;
                wv[0] = (__float_as_uint(p1) & 0xFFFF0000u) | (__float_as_uint(p0) >> 16);
                wv[1] = (__float_as_uint(p3) & 0xFFFF0000u) | (__float_as_uint(p2) >> 16);
                wv[2] = (__float_as_uint(q1) & 0xFFFF0000u) | (__float_as_uint(q0) >> 16);
                wv[3] = (__float_as_uint(q3) & 0xFFFF0000u) | (__float_as_uint(q2) >> 16);
                pa8[g][mt] = __builtin_bit_cast(bf16x8, wv);
            }
        // PV at K=32: B = V^T b128 fragments (8 consecutive actual keys).
        #pragma unroll
        for (int g = 0; g < 2; ++g) {
            bf16x8 bv8[4];
            #pragma unroll
            for (int nt = 0; nt < 4; ++nt) {
                int row = nt * 16 + l16;  // d
                int ch = (g * 4 + quad) ^ (row & 7);
                bv8[nt] = *(const bf16x8*)&Vs[buf][row * 64 + ch * 8];
            }
            #pragma unroll
            for (int mt = 0; mt < 2; ++mt)
                #pragma unroll
                for (int nt = 0; nt < 4; ++nt)
                    o[mt][nt] = __builtin_amdgcn_mfma_f32_16x16x32_bf16(pa8[g][mt], bv8[nt], o[mt][nt], 0, 0, 0);
        }
    }

    // row sums: each q-row l16's partials live in the 4 quads; reduce, redistribute
    #pragma unroll
    for (int mt = 0; mt < 2; ++mt) {
        float v = lrow[mt];
        v += __shfl_xor(v, 16);
        v += __shfl_xor(v, 32);
        #pragma unroll
        for (int reg = 0; reg < 4; ++reg) {
            float inv = 1.f / __shfl(v, quad * 4 + reg);
            int row = qbase + mt * 16 + quad * 4 + reg;
            size_t obase = ((size_t)b * SQ + row) * DM + h * 64;
            #pragma unroll
            for (int nt = 0; nt < 4; ++nt)
                outp[obase + nt * 16 + l16] = o[mt][nt][reg] * inv;
        }
    }
}

extern "C" void kernel_launch(void* const* d_in, const int* in_sizes, int n_in,
                              void* d_out, int out_size, void* d_ws, size_t ws_size,
                              hipStream_t stream) {
    (void)in_sizes; (void)n_in; (void)out_size; (void)ws_size;
    const float* Q  = (const float*)d_in[0];
    const float* K  = (const float*)d_in[1];
    const float* V  = (const float*)d_in[2];
    const int* mask = (const int*)d_in[3];
    const float* Wq = (const float*)d_in[4];
    const float* bq = (const float*)d_in[5];
    const float* Wk = (const float*)d_in[6];
    const float* bk = (const float*)d_in[7];
    const float* Wv = (const float*)d_in[8];
    const float* bv = (const float*)d_in[9];
    float* out = (float*)d_out;
    char* ws = (char*)d_ws;
    u16* q_ws  = (u16*)(ws);                                  // 16 MB  [b][h][s][d]
    u16* k_ws  = (u16*)(ws + (size_t)16 * 1024 * 1024);       // 16 MB  [b][h][prem(s)][d]
    u16* v_ws  = (u16*)(ws + (size_t)32 * 1024 * 1024);       // 16 MB  [b][h][d][s]
    u16* wbuf3 = (u16*)(ws + (size_t)48 * 1024 * 1024);       //  6 MB  [3][N][K] bf16
    float* mb  = (float*)(ws + (size_t)54 * 1024 * 1024);     // 32 KB

    cvt_wT3<<<dim3(16, 16, 3), 256, 0, stream>>>(Wq, Wk, Wv, wbuf3);
    mk_mbias<<<32, 256, 0, stream>>>(mask, mb);
    gemm3<<<dim3(64, 8, 3), 256, 0, stream>>>(Q, K, V, wbuf3, bq, bk, bv, q_ws);
    attn<<<dim3(64, 16), 256, 0, stream>>>(q_ws, k_ws, v_ws, mb, out);
}

// Round 7
// 409.320 us; speedup vs baseline: 1.1687x; 1.1687x over previous
//
#include <hip/hip_runtime.h>

#define NH 16
#define DM 1024
#define SQ 2048
#define BT 4

typedef __attribute__((ext_vector_type(8))) short bf16x8;
typedef __attribute__((ext_vector_type(4))) short sh4;
typedef __attribute__((ext_vector_type(4))) float f4;
typedef __attribute__((ext_vector_type(4))) float fv4;
typedef __attribute__((ext_vector_type(4))) unsigned uv4;
typedef unsigned short u16;

#define M2BIAS 23.083120654f   /* 16 * log2(e) */
#define SCALE2 0.18033688f     /* (1/8) * log2(e) */

__device__ __forceinline__ u16 f2bf(float f) {
    union { float f; unsigned u; } v; v.f = f;
    unsigned r = v.u + 0x7FFFu + ((v.u >> 16) & 1u);
    return (u16)(r >> 16);
}

__device__ __forceinline__ float fast_exp2(float x) {
#if __has_builtin(__builtin_amdgcn_exp2f)
    return __builtin_amdgcn_exp2f(x);
#else
    return exp2f(x);
#endif
}

// Key-position permutation: actual key s (within a 32-key group, s = 8q+4t+j)
// -> LDS/position index p = 16t + 4q + j. Makes the S^T output of two 16-key
// tiles land exactly in the A-fragment layout of mfma_f32_16x16x32_bf16
// (A[m=l16][k=8*quad+j] over actual keys), so PV needs no cross-lane exchange.
__device__ __forceinline__ int prem(int s) {
    return (s & ~31) | ((s & 4) << 2) | ((s >> 1) & 12) | (s & 3);
}

#define GLD16(gp, lp) __builtin_amdgcn_global_load_lds( \
    (const __attribute__((address_space(1))) void*)(gp), \
    (__attribute__((address_space(3))) void*)(lp), 16, 0, 0)

// ---------------- fp32 W[K][N] -> bf16 Wt[N][K], all three weights in one launch ----------------
__global__ __launch_bounds__(256) void cvt_wT3(const float* __restrict__ W0, const float* __restrict__ W1,
                                               const float* __restrict__ W2, u16* __restrict__ Wt) {
    __shared__ float t[64][65];
    const float* Wsrc = blockIdx.z == 0 ? W0 : (blockIdx.z == 1 ? W1 : W2);
    u16* dst = Wt + (size_t)blockIdx.z * DM * DM;
    int r0 = blockIdx.x * 64, c0 = blockIdx.y * 64;
    #pragma unroll
    for (int i = 0; i < 16; ++i) {
        int idx = i * 256 + threadIdx.x;
        int r = idx >> 6, c = idx & 63;
        t[r][c] = Wsrc[(size_t)(r0 + r) * DM + c0 + c];
    }
    __syncthreads();
    #pragma unroll
    for (int i = 0; i < 16; ++i) {
        int idx = i * 256 + threadIdx.x;
        int n = idx >> 6, k = idx & 63;
        dst[(size_t)(c0 + n) * DM + r0 + k] = f2bf(t[k][n]);
    }
}

// ---------------- mask -> float bias, stored at PERMUTED key position ----------------
__global__ __launch_bounds__(256) void mk_mbias(const int* __restrict__ mask, float* __restrict__ mb) {
    int i = blockIdx.x * 256 + threadIdx.x;
    mb[prem(i)] = mask[i] ? -M2BIAS : -__builtin_inff();
}

// ---------------- fused projection GEMMs: z in {Q,K,V}, [8192,1024]x[1024,1024]+bias ----------------
// A-DIRECT-TO-REGISTER: rounds 3/5 showed the A LDS round-trip (loadA -> cvt ->
// ds_write -> barrier -> ds_read) is a serial chain that phase-locked blocks
// cannot hide (117us under two different barrier disciplines). Here each lane
// loads its OWN A-fragment straight from global in MFMA layout (rows
// wm*64+mt*16+l16, cols kt*64+ks*32+quad*8+j as fp32), converts via
// v_cvt_pk_bf16_f32, and feeds MFMA from registers. A is read 2x per block
// (wn pair) but is L2/L3-resident (FETCH ~= unique bytes in r3/r5), so the
// re-read is cheap and load latency is ~L2 (~200-400cy), covered by
// distance-1 half-step prefetch. LDS = Bs only (32KB, double-buffered).
// VGPR budget (round-6 spill lesson: keep <=150): acc 64 + ar 32 + pa 16 +
// bfr 16 + addr ~15 = ~143 under the (256,3) cap of ~168.
// Counted waits: cvt's implicit vmcnt drains A(kt,ks) and (older) B(kt);
// pre-MFMA barrier leaves {B(kt+1),A(kt,1)} = 12 in flight (8 at kt=15).
// z=0: Q -> [b][h][s][d];  z=1: K -> [b][h][prem(s)][d];  z=2: V -> [b][h][d][s]
__global__ __launch_bounds__(256, 3) void gemm3(const float* __restrict__ Qf, const float* __restrict__ Kf,
                                                const float* __restrict__ Vf, const u16* __restrict__ Wt3,
                                                const float* __restrict__ bq, const float* __restrict__ bk,
                                                const float* __restrict__ bv, u16* __restrict__ out3) {
    __shared__ u16 Bs[2][128 * 64];
    int z = blockIdx.z;
    const float* Af = z == 0 ? Qf : (z == 1 ? Kf : Vf);
    const float* bias = z == 0 ? bq : (z == 1 ? bk : bv);
    int vmode = z == 0 ? 0 : (z == 1 ? 2 : 1);
    const u16* Bg = Wt3 + (size_t)z * DM * DM + (size_t)blockIdx.y * 128 * DM;
    u16* outp = out3 + (size_t)z * 8388608u;   // 8192*1024 u16 per projection

    int tid = threadIdx.x;
    int w = tid >> 6, lane = tid & 63, quad = lane >> 4, l16 = lane & 15;
    int wm = w >> 1, wn = w & 1;
    int r8 = lane >> 3, cg = (lane & 7) ^ r8;

    // per-lane A-fragment base: row block (wm*64 + l16), col offset quad*8
    const float* aF = Af + (size_t)(blockIdx.x * 128 + wm * 64 + l16) * DM + quad * 8;

    f4 acc[4][4];
    #pragma unroll
    for (int mt = 0; mt < 4; ++mt)
        #pragma unroll
        for (int nt = 0; nt < 4; ++nt) acc[mt][nt] = f4{0.f, 0.f, 0.f, 0.f};

    fv4 ar[8];   // one 32-col half of the lane's A-fragments: 4 mt x 8 fp32
    auto loadA = [&](int kt, int ks) {
        const float* s = aF + kt * 64 + ks * 32;
        #pragma unroll
        for (int mt = 0; mt < 4; ++mt) {
            ar[2 * mt]     = *(const fv4*)(s + (size_t)mt * 16 * DM);
            ar[2 * mt + 1] = *(const fv4*)(s + (size_t)mt * 16 * DM + 4);
        }
    };
    auto cvtA = [&](bf16x8* pa) {
        #pragma unroll
        for (int mt = 0; mt < 4; ++mt) {
            unsigned u0, u1, u2, u3;
            asm("v_cvt_pk_bf16_f32 %0, %1, %2" : "=v"(u0) : "v"(ar[2 * mt][0]), "v"(ar[2 * mt][1]));
            asm("v_cvt_pk_bf16_f32 %0, %1, %2" : "=v"(u1) : "v"(ar[2 * mt][2]), "v"(ar[2 * mt][3]));
            asm("v_cvt_pk_bf16_f32 %0, %1, %2" : "=v"(u2) : "v"(ar[2 * mt + 1][0]), "v"(ar[2 * mt + 1][1]));
            asm("v_cvt_pk_bf16_f32 %0, %1, %2" : "=v"(u3) : "v"(ar[2 * mt + 1][2]), "v"(ar[2 * mt + 1][3]));
            uv4 wv; wv[0] = u0; wv[1] = u1; wv[2] = u2; wv[3] = u3;
            pa[mt] = __builtin_bit_cast(bf16x8, wv);
        }
    };
    auto stageB = [&](int buf, int kt) {
        int kofs = kt * 64 + cg * 8;
        #pragma unroll
        for (int c = 0; c < 4; ++c) {
            int rbase = w * 32 + c * 8;
            GLD16(Bg + (size_t)(rbase + r8) * DM + kofs, &Bs[buf][rbase * 64]);
        }
    };
    auto mfmaHalf = [&](int bufidx, int ks, const bf16x8* pa) {
        bf16x8 bfr[4];
        #pragma unroll
        for (int nt = 0; nt < 4; ++nt) {
            int row = wn * 64 + nt * 16 + l16;
            int ch = (ks * 4 + quad) ^ (row & 7);
            bfr[nt] = *(const bf16x8*)&Bs[bufidx][row * 64 + ch * 8];
        }
        #pragma unroll
        for (int mt = 0; mt < 4; ++mt)
            #pragma unroll
            for (int nt = 0; nt < 4; ++nt)
                acc[mt][nt] = __builtin_amdgcn_mfma_f32_16x16x32_bf16(pa[mt], bfr[nt], acc[mt][nt], 0, 0, 0);
    };

    stageB(0, 0);
    loadA(0, 0);

    for (int kt = 0; kt < 16; ++kt) {
        if (kt + 1 < 16) stageB((kt + 1) & 1, kt + 1);
        bf16x8 pa[4];
        cvtA(pa);          // implicit vmcnt drains A(kt,0) AND (older) B(kt)
        loadA(kt, 1);      // prefetch second half (WAR: after cvt read ar)
        // pre-MFMA barrier: B(kt) already drained per-wave; leave the 12 (8 at
        // tail) newer prefetches {B(kt+1), A(kt,1)} in flight.
        if (kt < 15) {
            asm volatile("s_waitcnt vmcnt(12)" ::: "memory");
        } else {
            asm volatile("s_waitcnt vmcnt(8)" ::: "memory");
        }
        __builtin_amdgcn_s_barrier();
        asm volatile("" ::: "memory");
        mfmaHalf(kt & 1, 0, pa);
        cvtA(pa);          // implicit vmcnt drains A(kt,1); B(kt+1) stays in flight
        if (kt + 1 < 16) loadA(kt + 1, 0);
        mfmaHalf(kt & 1, 1, pa);
        // post-MFMA barrier: all waves done reading Bs[kt&1] before next
        // iteration's stageB(kt+2) overwrites it.
        asm volatile("" ::: "memory");
        __builtin_amdgcn_s_barrier();
        asm volatile("" ::: "memory");
    }

    #pragma unroll
    for (int nt = 0; nt < 4; ++nt) {
        int ncol = blockIdx.y * 128 + wn * 64 + nt * 16 + l16;
        float bn = bias[ncol];
        int h = ncol >> 6, d = ncol & 63;
        #pragma unroll
        for (int mt = 0; mt < 4; ++mt) {
            int mbase = blockIdx.x * 128 + wm * 64 + mt * 16 + quad * 4;
            int bidx = mbase >> 11, s0 = mbase & 2047;
            if (vmode == 1) {
                sh4 pk;
                #pragma unroll
                for (int reg = 0; reg < 4; ++reg) pk[reg] = (short)f2bf(acc[mt][nt][reg] + bn);
                *(sh4*)&outp[(((size_t)bidx * NH + h) * 64 + d) * SQ + s0] = pk;
            } else {
                int sp = (vmode == 2) ? prem(s0) : s0;   // prem(s0+reg) == prem(s0)+reg for 4-aligned s0
                size_t base = ((size_t)bidx * NH + h) * SQ;
                #pragma unroll
                for (int reg = 0; reg < 4; ++reg)
                    outp[(base + sp + reg) * 64 + d] = f2bf(acc[mt][nt][reg] + bn);
            }
        }
    }
}

// ---------------- flash attention (S^T form, register-resident P, K=32 PV) ----------------
// S^T = K*Q^T with K rows stored in permuted position space: lane(quad,l16)'s
// S-regs over tile pair (2g,2g+1) hold actual keys g*32 + 8*quad + 0..7 for
// q-row l16 — exactly the A-fragment of mfma_f32_16x16x32_bf16. PV thus runs
// at K=32 (16 MFMAs/iter instead of 32 K=16 MFMAs), B = V^T b128 fragments.
// P is packed to bf16 IMMEDIATELY after exp2 (per 32-key group) so the f32
// scores die before PV — keeps peak live VGPRs under the 4-wave/EU cap.
__global__ __launch_bounds__(256, 4) void attn(const u16* __restrict__ qw, const u16* __restrict__ kw,
                                               const u16* __restrict__ vtw, const float* __restrict__ mbias,
                                               float* __restrict__ outp) {
    __shared__ u16 Ks[2][64 * 64];   // [key-position][64 d], 16B-chunk XOR swizzled
    __shared__ u16 Vs[2][64 * 64];   // [d][64 keys], 16B-chunk XOR swizzled
    int tid = threadIdx.x;
    int w = tid >> 6, lane = tid & 63, quad = lane >> 4, l16 = lane & 15;
    int r8 = lane >> 3, sl = lane & 7;
    int bh = blockIdx.x, b = bh >> 4;   // grid.x = bh for XCD L2 locality
    int h = bh & 15;
    int qbase = blockIdx.y * 128 + w * 32;
    const u16* qp = qw + (size_t)bh * SQ * 64;
    const u16* kp = kw + (size_t)bh * SQ * 64;
    const u16* vp = vtw + (size_t)bh * 64 * SQ;
    const float* mbp = mbias + b * SQ;

    bf16x8 aq[2][2];  // Q frags (B-operand of S^T)
    #pragma unroll
    for (int mt = 0; mt < 2; ++mt)
        #pragma unroll
        for (int ks = 0; ks < 2; ++ks)
            aq[mt][ks] = *(const bf16x8*)&qp[(size_t)(qbase + mt * 16 + l16) * 64 + ks * 32 + quad * 8];

    f4 o[2][4];
    float lrow[2] = {0.f, 0.f};  // per-lane partial row-sum for q-row l16
    #pragma unroll
    for (int mt = 0; mt < 2; ++mt)
        #pragma unroll
        for (int nt = 0; nt < 4; ++nt) o[mt][nt] = f4{0.f, 0.f, 0.f, 0.f};

    auto stage = [&](int buf, int k0) {
        #pragma unroll
        for (int j = 0; j < 2; ++j) {
            int row = w * 16 + j * 8 + r8;
            int gsl = sl ^ (row & 7);
            GLD16(kp + (size_t)(k0 + row) * 64 + gsl * 8, &Ks[buf][(w * 16 + j * 8) * 64]);
            GLD16(vp + (size_t)row * SQ + k0 + gsl * 8, &Vs[buf][(w * 16 + j * 8) * 64]);
        }
    };

    stage(0, 0);
    for (int kb = 0; kb < 32; ++kb) {
        int buf = kb & 1;
        int k0 = kb * 64;
        __syncthreads();  // staging of `buf` done; all waves done reading buf^1
        // mask-bias loads BEFORE the prefetch so their vmcnt wait doesn't drain it
        fv4 bias4[4];
        #pragma unroll
        for (int kt = 0; kt < 4; ++kt)
            bias4[kt] = *(const fv4*)&mbp[k0 + kt * 16 + quad * 4];
        if (kb + 1 < 32) stage(buf ^ 1, k0 + 64);

        // K frags (A-operand of S^T)
        bf16x8 bk[4][2];
        #pragma unroll
        for (int kt = 0; kt < 4; ++kt)
            #pragma unroll
            for (int ks = 0; ks < 2; ++ks) {
                int r = kt * 16 + l16;
                int slot = (ks * 4 + quad) ^ (r & 7);
                bk[kt][ks] = *(const bf16x8*)&Ks[buf][r * 64 + slot * 8];
            }
        // S^T[kt][mt]: lane(quad,l16) regs = key-positions 16kt+4quad+r, q-row = l16
        f4 S[4][2];
        #pragma unroll
        for (int kt = 0; kt < 4; ++kt)
            #pragma unroll
            for (int mt = 0; mt < 2; ++mt) {
                f4 s = f4{0.f, 0.f, 0.f, 0.f};
                s = __builtin_amdgcn_mfma_f32_16x16x32_bf16(bk[kt][0], aq[mt][0], s, 0, 0, 0);
                s = __builtin_amdgcn_mfma_f32_16x16x32_bf16(bk[kt][1], aq[mt][1], s, 0, 0, 0);
                S[kt][mt] = s;
            }
        // softmax numerator + IMMEDIATE bf16 pack: per 32-key group g, the tile
        // pair (2g,2g+1) becomes one A-fragment pa8[g][mt] (keys g*32+8q+0..7).
        bf16x8 pa8[2][2];
        #pragma unroll
        for (int g = 0; g < 2; ++g)
            #pragma unroll
            for (int mt = 0; mt < 2; ++mt) {
                f4 se = S[2 * g][mt], so = S[2 * g + 1][mt];
                float p0 = fast_exp2(se[0] * SCALE2 + bias4[2 * g][0]);
                float p1 = fast_exp2(se[1] * SCALE2 + bias4[2 * g][1]);
                float p2 = fast_exp2(se[2] * SCALE2 + bias4[2 * g][2]);
                float p3 = fast_exp2(se[3] * SCALE2 + bias4[2 * g][3]);
                float q0 = fast_exp2(so[0] * SCALE2 + bias4[2 * g + 1][0]);
                float q1 = fast_exp2(so[1] * SCALE2 + bias4[2 * g + 1][1]);
                float q2 = fast_exp2(so[2] * SCALE2 + bias4[2 * g + 1][2]);
                float q3 = fast_exp2(so[3] * SCALE2 + bias4[2 * g + 1][3]);
                lrow[mt] += ((p0 + p1) + (p2 + p3)) + ((q0 + q1) + (q2 + q3));
                uv4 wv;
                wv[0] = (__float_as_uint(p1) & 0xFFFF0000u) | (__float_as_uint(p0) >> 16);
                wv[1] = (__float_as_uint(p3) & 0xFFFF0000u) | (__float_as_uint(p2) >> 16);
                wv[2] = (__float_as_uint(q1) & 0xFFFF0000u) | (__float_as_uint(q0) >> 16);
                wv[3] = (__float_as_uint(q3) & 0xFFFF0000u) | (__float_as_uint(q2) >> 16);
                pa8[g][mt] = __builtin_bit_cast(bf16x8, wv);
            }
        // PV at K=32: B = V^T b128 fragments (8 consecutive actual keys).
        #pragma unroll
        for (int g = 0; g < 2; ++g) {
            bf16x8 bv8[4];
            #pragma unroll
            for (int nt = 0; nt < 4; ++nt) {
                int row = nt * 16 + l16;  // d
                int ch = (g * 4 + quad) ^ (row & 7);
                bv8[nt] = *(const bf16x8*)&Vs[buf][row * 64 + ch * 8];
            }
            #pragma unroll
            for (int mt = 0; mt < 2; ++mt)
                #pragma unroll
                for (int nt = 0; nt < 4; ++nt)
                    o[mt][nt] = __builtin_amdgcn_mfma_f32_16x16x32_bf16(pa8[g][mt], bv8[nt], o[mt][nt], 0, 0, 0);
        }
    }

    // row sums: each q-row l16's partials live in the 4 quads; reduce, redistribute
    #pragma unroll
    for (int mt = 0; mt < 2; ++mt) {
        float v = lrow[mt];
        v += __shfl_xor(v, 16);
        v += __shfl_xor(v, 32);
        #pragma unroll
        for (int reg = 0; reg < 4; ++reg) {
            float inv = 1.f / __shfl(v, quad * 4 + reg);
            int row = qbase + mt * 16 + quad * 4 + reg;
            size_t obase = ((size_t)b * SQ + row) * DM + h * 64;
            #pragma unroll
            for (int nt = 0; nt < 4; ++nt)
                outp[obase + nt * 16 + l16] = o[mt][nt][reg] * inv;
        }
    }
}

extern "C" void kernel_launch(void* const* d_in, const int* in_sizes, int n_in,
                              void* d_out, int out_size, void* d_ws, size_t ws_size,
                              hipStream_t stream) {
    (void)in_sizes; (void)n_in; (void)out_size; (void)ws_size;
    const float* Q  = (const float*)d_in[0];
    const float* K  = (const float*)d_in[1];
    const float* V  = (const float*)d_in[2];
    const int* mask = (const int*)d_in[3];
    const float* Wq = (const float*)d_in[4];
    const float* bq = (const float*)d_in[5];
    const float* Wk = (const float*)d_in[6];
    const float* bk = (const float*)d_in[7];
    const float* Wv = (const float*)d_in[8];
    const float* bv = (const float*)d_in[9];
    float* out = (float*)d_out;
    char* ws = (char*)d_ws;
    u16* q_ws  = (u16*)(ws);                                  // 16 MB  [b][h][s][d]
    u16* k_ws  = (u16*)(ws + (size_t)16 * 1024 * 1024);       // 16 MB  [b][h][prem(s)][d]
    u16* v_ws  = (u16*)(ws + (size_t)32 * 1024 * 1024);       // 16 MB  [b][h][d][s]
    u16* wbuf3 = (u16*)(ws + (size_t)48 * 1024 * 1024);       //  6 MB  [3][N][K] bf16
    float* mb  = (float*)(ws + (size_t)54 * 1024 * 1024);     // 32 KB

    cvt_wT3<<<dim3(16, 16, 3), 256, 0, stream>>>(Wq, Wk, Wv, wbuf3);
    mk_mbias<<<32, 256, 0, stream>>>(mask, mb);
    gemm3<<<dim3(64, 8, 3), 256, 0, stream>>>(Q, K, V, wbuf3, bq, bk, bv, q_ws);
    attn<<<dim3(64, 16), 256, 0, stream>>>(q_ws, k_ws, v_ws, mb, out);
}

// Round 8
// 374.041 us; speedup vs baseline: 1.2789x; 1.0943x over previous
//
#include <hip/hip_runtime.h>

#define NH 16
#define DM 1024
#define SQ 2048
#define BT 4

typedef __attribute__((ext_vector_type(8))) short bf16x8;
typedef __attribute__((ext_vector_type(4))) short sh4;
typedef __attribute__((ext_vector_type(4))) float f4;
typedef __attribute__((ext_vector_type(4))) float fv4;
typedef __attribute__((ext_vector_type(4))) unsigned uv4;
typedef unsigned short u16;

#define M2BIAS 23.083120654f   /* 16 * log2(e) */
#define SCALE2 0.18033688f     /* (1/8) * log2(e) */

__device__ __forceinline__ u16 f2bf(float f) {
    union { float f; unsigned u; } v; v.f = f;
    unsigned r = v.u + 0x7FFFu + ((v.u >> 16) & 1u);
    return (u16)(r >> 16);
}

__device__ __forceinline__ float fast_exp2(float x) {
#if __has_builtin(__builtin_amdgcn_exp2f)
    return __builtin_amdgcn_exp2f(x);
#else
    return exp2f(x);
#endif
}

// Key-position permutation: actual key s (within a 32-key group, s = 8q+4t+j)
// -> LDS/position index p = 16t + 4q + j. Makes the S^T output of two 16-key
// tiles land exactly in the A-fragment layout of mfma_f32_16x16x32_bf16
// (A[m=l16][k=8*quad+j] over actual keys), so PV needs no cross-lane exchange.
__device__ __forceinline__ int prem(int s) {
    return (s & ~31) | ((s & 4) << 2) | ((s >> 1) & 12) | (s & 3);
}

#define GLD16(gp, lp) __builtin_amdgcn_global_load_lds( \
    (const __attribute__((address_space(1))) void*)(gp), \
    (__attribute__((address_space(3))) void*)(lp), 16, 0, 0)

// ---------------- fp32 W[K][N] -> bf16 Wt[N][K], all three weights in one launch ----------------
__global__ __launch_bounds__(256) void cvt_wT3(const float* __restrict__ W0, const float* __restrict__ W1,
                                               const float* __restrict__ W2, u16* __restrict__ Wt) {
    __shared__ float t[64][65];
    const float* Wsrc = blockIdx.z == 0 ? W0 : (blockIdx.z == 1 ? W1 : W2);
    u16* dst = Wt + (size_t)blockIdx.z * DM * DM;
    int r0 = blockIdx.x * 64, c0 = blockIdx.y * 64;
    #pragma unroll
    for (int i = 0; i < 16; ++i) {
        int idx = i * 256 + threadIdx.x;
        int r = idx >> 6, c = idx & 63;
        t[r][c] = Wsrc[(size_t)(r0 + r) * DM + c0 + c];
    }
    __syncthreads();
    #pragma unroll
    for (int i = 0; i < 16; ++i) {
        int idx = i * 256 + threadIdx.x;
        int n = idx >> 6, k = idx & 63;
        dst[(size_t)(c0 + n) * DM + r0 + k] = f2bf(t[k][n]);
    }
}

// ---------------- mask -> float bias, stored at PERMUTED key position ----------------
__global__ __launch_bounds__(256) void mk_mbias(const int* __restrict__ mask, float* __restrict__ mb) {
    int i = blockIdx.x * 256 + threadIdx.x;
    mb[prem(i)] = mask[i] ? -M2BIAS : -__builtin_inff();
}

// ---------------- fused projection GEMMs: z in {Q,K,V}, [8192,1024]x[1024,1024]+bias ----------------
// ROUND-5 STRUCTURE (best of 4 measured variants: 117us; reg-direct r7 = 212us
// due to uncoalesced per-lane A loads, dist-2 r6 = spill, r3 syncthreads = 118).
// A fp32 -> regs -> cvt_pk -> LDS; B via GLD16 double-buffered; counted vmcnt.
// z=0: Q -> [b][h][s][d];  z=1: K -> [b][h][prem(s)][d];  z=2: V -> [b][h][d][s]
__global__ __launch_bounds__(256, 3) void gemm3(const float* __restrict__ Qf, const float* __restrict__ Kf,
                                                const float* __restrict__ Vf, const u16* __restrict__ Wt3,
                                                const float* __restrict__ bq, const float* __restrict__ bk,
                                                const float* __restrict__ bv, u16* __restrict__ out3) {
    __shared__ u16 As[128 * 64];
    __shared__ u16 Bs[2][128 * 64];
    int z = blockIdx.z;
    const float* Af = z == 0 ? Qf : (z == 1 ? Kf : Vf);
    const float* bias = z == 0 ? bq : (z == 1 ? bk : bv);
    int vmode = z == 0 ? 0 : (z == 1 ? 2 : 1);
    const u16* Bg = Wt3 + (size_t)z * DM * DM + (size_t)blockIdx.y * 128 * DM;
    u16* outp = out3 + (size_t)z * 8388608u;   // 8192*1024 u16 per projection

    int tid = threadIdx.x;
    int w = tid >> 6, lane = tid & 63, quad = lane >> 4, l16 = lane & 15;
    int wm = w >> 1, wn = w & 1;
    int r8 = lane >> 3, cg = (lane & 7) ^ r8;

    int arow0 = w * 32 + (lane >> 4);
    int acol = (lane & 15) * 4;
    const float* Ag = Af + (size_t)(blockIdx.x * 128 + arow0) * DM + acol;
    int ach = (lane & 15) >> 1, asub = lane & 1;

    f4 acc[4][4];
    #pragma unroll
    for (int mt = 0; mt < 4; ++mt)
        #pragma unroll
        for (int nt = 0; nt < 4; ++nt) acc[mt][nt] = f4{0.f, 0.f, 0.f, 0.f};

    fv4 ar[8];
    auto loadA = [&](int kt) {
        const float* src = Ag + kt * 64;
        #pragma unroll
        for (int j = 0; j < 8; ++j) ar[j] = *(const fv4*)(src + (size_t)j * 4 * DM);
    };
    auto stageB = [&](int buf, int kt) {
        int kofs = kt * 64 + cg * 8;
        #pragma unroll
        for (int c = 0; c < 4; ++c) {
            int rbase = w * 32 + c * 8;
            GLD16(Bg + (size_t)(rbase + r8) * DM + kofs, &Bs[buf][rbase * 64]);
        }
    };

    stageB(0, 0);
    loadA(0);

    for (int kt = 0; kt < 16; ++kt) {
        if (kt + 1 < 16) stageB((kt + 1) & 1, kt + 1);
        #pragma unroll
        for (int j = 0; j < 8; ++j) {
            unsigned lo, hi;
            asm("v_cvt_pk_bf16_f32 %0, %1, %2" : "=v"(lo) : "v"(ar[j][0]), "v"(ar[j][1]));
            asm("v_cvt_pk_bf16_f32 %0, %1, %2" : "=v"(hi) : "v"(ar[j][2]), "v"(ar[j][3]));
            int row = arow0 + j * 4;
            uint2 pk; pk.x = lo; pk.y = hi;
            *(uint2*)&As[row * 64 + (ach ^ (row & 7)) * 8 + asub * 4] = pk;
        }
        if (kt + 1 < 16) loadA(kt + 1);

        if (kt < 15) {
            asm volatile("s_waitcnt vmcnt(12) lgkmcnt(0)" ::: "memory");
        } else {
            asm volatile("s_waitcnt vmcnt(0) lgkmcnt(0)" ::: "memory");
        }
        __builtin_amdgcn_s_barrier();
        asm volatile("" ::: "memory");

        #pragma unroll
        for (int ks = 0; ks < 2; ++ks) {
            bf16x8 afr[4], bfr[4];
            #pragma unroll
            for (int mt = 0; mt < 4; ++mt) {
                int row = wm * 64 + mt * 16 + l16;
                int ch = (ks * 4 + quad) ^ (row & 7);
                afr[mt] = *(const bf16x8*)&As[row * 64 + ch * 8];
            }
            #pragma unroll
            for (int nt = 0; nt < 4; ++nt) {
                int row = wn * 64 + nt * 16 + l16;
                int ch = (ks * 4 + quad) ^ (row & 7);
                bfr[nt] = *(const bf16x8*)&Bs[kt & 1][row * 64 + ch * 8];
            }
            #pragma unroll
            for (int mt = 0; mt < 4; ++mt)
                #pragma unroll
                for (int nt = 0; nt < 4; ++nt)
                    acc[mt][nt] = __builtin_amdgcn_mfma_f32_16x16x32_bf16(afr[mt], bfr[nt], acc[mt][nt], 0, 0, 0);
        }
        asm volatile("" ::: "memory");
        __builtin_amdgcn_s_barrier();
        asm volatile("" ::: "memory");
    }

    #pragma unroll
    for (int nt = 0; nt < 4; ++nt) {
        int ncol = blockIdx.y * 128 + wn * 64 + nt * 16 + l16;
        float bn = bias[ncol];
        int h = ncol >> 6, d = ncol & 63;
        #pragma unroll
        for (int mt = 0; mt < 4; ++mt) {
            int mbase = blockIdx.x * 128 + wm * 64 + mt * 16 + quad * 4;
            int bidx = mbase >> 11, s0 = mbase & 2047;
            if (vmode == 1) {
                sh4 pk;
                #pragma unroll
                for (int reg = 0; reg < 4; ++reg) pk[reg] = (short)f2bf(acc[mt][nt][reg] + bn);
                *(sh4*)&outp[(((size_t)bidx * NH + h) * 64 + d) * SQ + s0] = pk;
            } else {
                int sp = (vmode == 2) ? prem(s0) : s0;   // prem(s0+reg) == prem(s0)+reg for 4-aligned s0
                size_t base = ((size_t)bidx * NH + h) * SQ;
                #pragma unroll
                for (int reg = 0; reg < 4; ++reg)
                    outp[(base + sp + reg) * 64 + d] = f2bf(acc[mt][nt][reg] + bn);
            }
        }
    }
}

// ---------------- flash attention (S^T form, register-resident P, K=32 PV, V direct) ----------------
// S^T = K*Q^T with K rows stored in permuted position space: lane(quad,l16)'s
// S-regs over tile pair (2g,2g+1) hold actual keys g*32 + 8*quad + 0..7 for
// q-row l16 — exactly the A-fragment of mfma_f32_16x16x32_bf16. PV runs at
// K=32 with B-fragments loaded DIRECTLY from global V^T (no LDS staging):
// the 8KB V-tile is L1/L2-resident (16 q-blocks share each head's V), so
// staging it was pure overhead (Common-mistake #7). bv0 issued before the K
// ds_reads (covered by QK^T); bv1 after QK^T (covered by softmax+PV g0).
// LDS halves to 16KB (K only); stage() drops to 2 GLD16s -> faster barrier
// drain. P packed to bf16 per-group immediately after exp2.
__global__ __launch_bounds__(256, 4) void attn(const u16* __restrict__ qw, const u16* __restrict__ kw,
                                               const u16* __restrict__ vtw, const float* __restrict__ mbias,
                                               float* __restrict__ outp) {
    __shared__ u16 Ks[2][64 * 64];   // [key-position][64 d], 16B-chunk XOR swizzled
    int tid = threadIdx.x;
    int w = tid >> 6, lane = tid & 63, quad = lane >> 4, l16 = lane & 15;
    int r8 = lane >> 3, sl = lane & 7;
    int bh = blockIdx.x, b = bh >> 4;   // grid.x = bh for XCD L2 locality
    int h = bh & 15;
    int qbase = blockIdx.y * 128 + w * 32;
    const u16* qp = qw + (size_t)bh * SQ * 64;
    const u16* kp = kw + (size_t)bh * SQ * 64;
    const u16* vp = vtw + (size_t)bh * 64 * SQ;
    const float* mbp = mbias + b * SQ;

    bf16x8 aq[2][2];  // Q frags (B-operand of S^T)
    #pragma unroll
    for (int mt = 0; mt < 2; ++mt)
        #pragma unroll
        for (int ks = 0; ks < 2; ++ks)
            aq[mt][ks] = *(const bf16x8*)&qp[(size_t)(qbase + mt * 16 + l16) * 64 + ks * 32 + quad * 8];

    f4 o[2][4];
    float lrow[2] = {0.f, 0.f};  // per-lane partial row-sum for q-row l16
    #pragma unroll
    for (int mt = 0; mt < 2; ++mt)
        #pragma unroll
        for (int nt = 0; nt < 4; ++nt) o[mt][nt] = f4{0.f, 0.f, 0.f, 0.f};

    auto stageK = [&](int buf, int k0) {
        #pragma unroll
        for (int j = 0; j < 2; ++j) {
            int row = w * 16 + j * 8 + r8;
            int gsl = sl ^ (row & 7);
            GLD16(kp + (size_t)(k0 + row) * 64 + gsl * 8, &Ks[buf][(w * 16 + j * 8) * 64]);
        }
    };

    stageK(0, 0);
    for (int kb = 0; kb < 32; ++kb) {
        int buf = kb & 1;
        int k0 = kb * 64;
        __syncthreads();  // staging of `buf` done; all waves done reading buf^1
        // mask-bias loads BEFORE the prefetch so their vmcnt wait doesn't drain it
        fv4 bias4[4];
        #pragma unroll
        for (int kt = 0; kt < 4; ++kt)
            bias4[kt] = *(const fv4*)&mbp[k0 + kt * 16 + quad * 4];
        if (kb + 1 < 32) stageK(buf ^ 1, k0 + 64);

        // V fragments for group 0 (keys k0+quad*8..+7, rows d = nt*16+l16),
        // straight from global — latency hides under the QK^T MFMAs below.
        bf16x8 bv0[4];
        #pragma unroll
        for (int nt = 0; nt < 4; ++nt)
            bv0[nt] = *(const bf16x8*)&vp[(size_t)(nt * 16 + l16) * SQ + k0 + quad * 8];

        // K frags (A-operand of S^T)
        bf16x8 bk[4][2];
        #pragma unroll
        for (int kt = 0; kt < 4; ++kt)
            #pragma unroll
            for (int ks = 0; ks < 2; ++ks) {
                int r = kt * 16 + l16;
                int slot = (ks * 4 + quad) ^ (r & 7);
                bk[kt][ks] = *(const bf16x8*)&Ks[buf][r * 64 + slot * 8];
            }
        // S^T[kt][mt]: lane(quad,l16) regs = key-positions 16kt+4quad+r, q-row = l16
        f4 S[4][2];
        #pragma unroll
        for (int kt = 0; kt < 4; ++kt)
            #pragma unroll
            for (int mt = 0; mt < 2; ++mt) {
                f4 s = f4{0.f, 0.f, 0.f, 0.f};
                s = __builtin_amdgcn_mfma_f32_16x16x32_bf16(bk[kt][0], aq[mt][0], s, 0, 0, 0);
                s = __builtin_amdgcn_mfma_f32_16x16x32_bf16(bk[kt][1], aq[mt][1], s, 0, 0, 0);
                S[kt][mt] = s;
            }
        // V fragments for group 1 (keys k0+32+quad*8..+7) — covered by the
        // group-0 softmax+PV below.
        bf16x8 bv1[4];
        #pragma unroll
        for (int nt = 0; nt < 4; ++nt)
            bv1[nt] = *(const bf16x8*)&vp[(size_t)(nt * 16 + l16) * SQ + k0 + 32 + quad * 8];

        // per 32-key group: softmax numerator + bf16 pack + K=32 PV
        #pragma unroll
        for (int g = 0; g < 2; ++g) {
            bf16x8 pa8[2];
            #pragma unroll
            for (int mt = 0; mt < 2; ++mt) {
                f4 se = S[2 * g][mt], so = S[2 * g + 1][mt];
                float p0 = fast_exp2(se[0] * SCALE2 + bias4[2 * g][0]);
                float p1 = fast_exp2(se[1] * SCALE2 + bias4[2 * g][1]);
                float p2 = fast_exp2(se[2] * SCALE2 + bias4[2 * g][2]);
                float p3 = fast_exp2(se[3] * SCALE2 + bias4[2 * g][3]);
                float q0 = fast_exp2(so[0] * SCALE2 + bias4[2 * g + 1][0]);
                float q1 = fast_exp2(so[1] * SCALE2 + bias4[2 * g + 1][1]);
                float q2 = fast_exp2(so[2] * SCALE2 + bias4[2 * g + 1][2]);
                float q3 = fast_exp2(so[3] * SCALE2 + bias4[2 * g + 1][3]);
                lrow[mt] += ((p0 + p1) + (p2 + p3)) + ((q0 + q1) + (q2 + q3));
                uv4 wv;
                wv[0] = (__float_as_uint(p1) & 0xFFFF0000u) | (__float_as_uint(p0) >> 16);
                wv[1] = (__float_as_uint(p3) & 0xFFFF0000u) | (__float_as_uint(p2) >> 16);
                wv[2] = (__float_as_uint(q1) & 0xFFFF0000u) | (__float_as_uint(q0) >> 16);
                wv[3] = (__float_as_uint(q3) & 0xFFFF0000u) | (__float_as_uint(q2) >> 16);
                pa8[mt] = __builtin_bit_cast(bf16x8, wv);
            }
            #pragma unroll
            for (int mt = 0; mt < 2; ++mt)
                #pragma unroll
                for (int nt = 0; nt < 4; ++nt)
                    o[mt][nt] = __builtin_amdgcn_mfma_f32_16x16x32_bf16(
                        pa8[mt], g == 0 ? bv0[nt] : bv1[nt], o[mt][nt], 0, 0, 0);
        }
    }

    // row sums: each q-row l16's partials live in the 4 quads; reduce, redistribute
    #pragma unroll
    for (int mt = 0; mt < 2; ++mt) {
        float v = lrow[mt];
        v += __shfl_xor(v, 16);
        v += __shfl_xor(v, 32);
        #pragma unroll
        for (int reg = 0; reg < 4; ++reg) {
            float inv = 1.f / __shfl(v, quad * 4 + reg);
            int row = qbase + mt * 16 + quad * 4 + reg;
            size_t obase = ((size_t)b * SQ + row) * DM + h * 64;
            #pragma unroll
            for (int nt = 0; nt < 4; ++nt)
                outp[obase + nt * 16 + l16] = o[mt][nt][reg] * inv;
        }
    }
}

extern "C" void kernel_launch(void* const* d_in, const int* in_sizes, int n_in,
                              void* d_out, int out_size, void* d_ws, size_t ws_size,
                              hipStream_t stream) {
    (void)in_sizes; (void)n_in; (void)out_size; (void)ws_size;
    const float* Q  = (const float*)d_in[0];
    const float* K  = (const float*)d_in[1];
    const float* V  = (const float*)d_in[2];
    const int* mask = (const int*)d_in[3];
    const float* Wq = (const float*)d_in[4];
    const float* bq = (const float*)d_in[5];
    const float* Wk = (const float*)d_in[6];
    const float* bk = (const float*)d_in[7];
    const float* Wv = (const float*)d_in[8];
    const float* bv = (const float*)d_in[9];
    float* out = (float*)d_out;
    char* ws = (char*)d_ws;
    u16* q_ws  = (u16*)(ws);                                  // 16 MB  [b][h][s][d]
    u16* k_ws  = (u16*)(ws + (size_t)16 * 1024 * 1024);       // 16 MB  [b][h][prem(s)][d]
    u16* v_ws  = (u16*)(ws + (size_t)32 * 1024 * 1024);       // 16 MB  [b][h][d][s]
    u16* wbuf3 = (u16*)(ws + (size_t)48 * 1024 * 1024);       //  6 MB  [3][N][K] bf16
    float* mb  = (float*)(ws + (size_t)54 * 1024 * 1024);     // 32 KB

    cvt_wT3<<<dim3(16, 16, 3), 256, 0, stream>>>(Wq, Wk, Wv, wbuf3);
    mk_mbias<<<32, 256, 0, stream>>>(mask, mb);
    gemm3<<<dim3(64, 8, 3), 256, 0, stream>>>(Q, K, V, wbuf3, bq, bk, bv, q_ws);
    attn<<<dim3(64, 16), 256, 0, stream>>>(q_ws, k_ws, v_ws, mb, out);
}

// Round 9
// 350.542 us; speedup vs baseline: 1.3646x; 1.0670x over previous
//
#include <hip/hip_runtime.h>

#define NH 16
#define DM 1024
#define SQ 2048
#define BT 4

typedef __attribute__((ext_vector_type(8))) short bf16x8;
typedef __attribute__((ext_vector_type(4))) short sh4;
typedef __attribute__((ext_vector_type(4))) float f4;
typedef __attribute__((ext_vector_type(4))) float fv4;
typedef __attribute__((ext_vector_type(4))) unsigned uv4;
typedef unsigned short u16;

#define M2BIAS 23.083120654f   /* 16 * log2(e) */
#define SCALE2 0.18033688f     /* (1/8) * log2(e) */

__device__ __forceinline__ u16 f2bf(float f) {
    union { float f; unsigned u; } v; v.f = f;
    unsigned r = v.u + 0x7FFFu + ((v.u >> 16) & 1u);
    return (u16)(r >> 16);
}

__device__ __forceinline__ float fast_exp2(float x) {
#if __has_builtin(__builtin_amdgcn_exp2f)
    return __builtin_amdgcn_exp2f(x);
#else
    return exp2f(x);
#endif
}

// Key-position permutation: actual key s (within a 32-key group, s = 8q+4t+j)
// -> LDS/position index p = 16t + 4q + j. Makes the S^T output of two 16-key
// tiles land exactly in the A-fragment layout of mfma_f32_16x16x32_bf16
// (A[m=l16][k=8*quad+j] over actual keys), so PV needs no cross-lane exchange.
__device__ __forceinline__ int prem(int s) {
    return (s & ~31) | ((s & 4) << 2) | ((s >> 1) & 12) | (s & 3);
}

#define GLD16(gp, lp) __builtin_amdgcn_global_load_lds( \
    (const __attribute__((address_space(1))) void*)(gp), \
    (__attribute__((address_space(3))) void*)(lp), 16, 0, 0)

// ---------------- fp32 W[K][N] -> bf16 Wt[N][K], all three weights in one launch ----------------
__global__ __launch_bounds__(256) void cvt_wT3(const float* __restrict__ W0, const float* __restrict__ W1,
                                               const float* __restrict__ W2, u16* __restrict__ Wt) {
    __shared__ float t[64][65];
    const float* Wsrc = blockIdx.z == 0 ? W0 : (blockIdx.z == 1 ? W1 : W2);
    u16* dst = Wt + (size_t)blockIdx.z * DM * DM;
    int r0 = blockIdx.x * 64, c0 = blockIdx.y * 64;
    #pragma unroll
    for (int i = 0; i < 16; ++i) {
        int idx = i * 256 + threadIdx.x;
        int r = idx >> 6, c = idx & 63;
        t[r][c] = Wsrc[(size_t)(r0 + r) * DM + c0 + c];
    }
    __syncthreads();
    #pragma unroll
    for (int i = 0; i < 16; ++i) {
        int idx = i * 256 + threadIdx.x;
        int n = idx >> 6, k = idx & 63;
        dst[(size_t)(c0 + n) * DM + r0 + k] = f2bf(t[k][n]);
    }
}

// ---------------- mask -> float bias, stored at PERMUTED key position ----------------
__global__ __launch_bounds__(256) void mk_mbias(const int* __restrict__ mask, float* __restrict__ mb) {
    int i = blockIdx.x * 256 + threadIdx.x;
    mb[prem(i)] = mask[i] ? -M2BIAS : -__builtin_inff();
}

// ---------------- fused projection GEMMs: z in {Q,K,V}, [8192,1024]x[1024,1024]+bias ----------------
// 4-BLOCKS/CU VARIANT: single-buffered Bs (32 KB total LDS) + launch_bounds
// (256,4) -> 4 co-resident blocks/CU (vs 3 for the 48 KB double-buffered r5
// version). The 2-phase loop's barrier-drain stall is hidden ONLY by
// cross-block TLP (blocks don't share barriers); r3/r5 both measured 117-118us
// at 3 blocks/CU under two different barrier disciplines -> scheduling isn't
// the lever, occupancy is the untested axis. Cost: B(kt)'s GLD16 latency
// (~300cy, weights L2-hot) is exposed at the pre-MFMA wait; the 4th block
// covers it. Counted vmcnt(8) keeps A(kt+1)'s 8 loads in flight.
// z=0: Q -> [b][h][s][d];  z=1: K -> [b][h][prem(s)][d];  z=2: V -> [b][h][d][s]
__global__ __launch_bounds__(256, 4) void gemm3(const float* __restrict__ Qf, const float* __restrict__ Kf,
                                                const float* __restrict__ Vf, const u16* __restrict__ Wt3,
                                                const float* __restrict__ bq, const float* __restrict__ bk,
                                                const float* __restrict__ bv, u16* __restrict__ out3) {
    __shared__ u16 As[128 * 64];
    __shared__ u16 Bs[128 * 64];
    int z = blockIdx.z;
    const float* Af = z == 0 ? Qf : (z == 1 ? Kf : Vf);
    const float* bias = z == 0 ? bq : (z == 1 ? bk : bv);
    int vmode = z == 0 ? 0 : (z == 1 ? 2 : 1);
    const u16* Bg = Wt3 + (size_t)z * DM * DM + (size_t)blockIdx.y * 128 * DM;
    u16* outp = out3 + (size_t)z * 8388608u;   // 8192*1024 u16 per projection

    int tid = threadIdx.x;
    int w = tid >> 6, lane = tid & 63, quad = lane >> 4, l16 = lane & 15;
    int wm = w >> 1, wn = w & 1;
    int r8 = lane >> 3, cg = (lane & 7) ^ r8;

    int arow0 = w * 32 + (lane >> 4);
    int acol = (lane & 15) * 4;
    const float* Ag = Af + (size_t)(blockIdx.x * 128 + arow0) * DM + acol;
    int ach = (lane & 15) >> 1, asub = lane & 1;

    f4 acc[4][4];
    #pragma unroll
    for (int mt = 0; mt < 4; ++mt)
        #pragma unroll
        for (int nt = 0; nt < 4; ++nt) acc[mt][nt] = f4{0.f, 0.f, 0.f, 0.f};

    fv4 ar[8];
    auto loadA = [&](int kt) {
        const float* src = Ag + kt * 64;
        #pragma unroll
        for (int j = 0; j < 8; ++j) ar[j] = *(const fv4*)(src + (size_t)j * 4 * DM);
    };
    auto stageB = [&](int kt) {
        int kofs = kt * 64 + cg * 8;
        #pragma unroll
        for (int c = 0; c < 4; ++c) {
            int rbase = w * 32 + c * 8;
            GLD16(Bg + (size_t)(rbase + r8) * DM + kofs, &Bs[rbase * 64]);
        }
    };

    loadA(0);

    for (int kt = 0; kt < 16; ++kt) {
        // stage CURRENT B tile (single buffer; previous readers passed the
        // post-MFMA barrier below)
        stageB(kt);
        // convert A(kt) regs -> swizzled As (implicit wait drains the A loads,
        // leaving the 4 B GLD16s above in flight)
        #pragma unroll
        for (int j = 0; j < 8; ++j) {
            unsigned lo, hi;
            asm("v_cvt_pk_bf16_f32 %0, %1, %2" : "=v"(lo) : "v"(ar[j][0]), "v"(ar[j][1]));
            asm("v_cvt_pk_bf16_f32 %0, %1, %2" : "=v"(hi) : "v"(ar[j][2]), "v"(ar[j][3]));
            int row = arow0 + j * 4;
            uint2 pk; pk.x = lo; pk.y = hi;
            *(uint2*)&As[row * 64 + (ach ^ (row & 7)) * 8 + asub * 4] = pk;
        }
        // prefetch next A tile (in flight across the barrier, covered by MFMA)
        if (kt + 1 < 16) loadA(kt + 1);

        // drain B(kt) (the 8 newer A-loads stay in flight) + As ds_writes
        if (kt < 15) {
            asm volatile("s_waitcnt vmcnt(8) lgkmcnt(0)" ::: "memory");
        } else {
            asm volatile("s_waitcnt vmcnt(0) lgkmcnt(0)" ::: "memory");
        }
        __builtin_amdgcn_s_barrier();
        asm volatile("" ::: "memory");

        #pragma unroll
        for (int ks = 0; ks < 2; ++ks) {
            bf16x8 afr[4], bfr[4];
            #pragma unroll
            for (int mt = 0; mt < 4; ++mt) {
                int row = wm * 64 + mt * 16 + l16;
                int ch = (ks * 4 + quad) ^ (row & 7);
                afr[mt] = *(const bf16x8*)&As[row * 64 + ch * 8];
            }
            #pragma unroll
            for (int nt = 0; nt < 4; ++nt) {
                int row = wn * 64 + nt * 16 + l16;
                int ch = (ks * 4 + quad) ^ (row & 7);
                bfr[nt] = *(const bf16x8*)&Bs[row * 64 + ch * 8];
            }
            #pragma unroll
            for (int mt = 0; mt < 4; ++mt)
                #pragma unroll
                for (int nt = 0; nt < 4; ++nt)
                    acc[mt][nt] = __builtin_amdgcn_mfma_f32_16x16x32_bf16(afr[mt], bfr[nt], acc[mt][nt], 0, 0, 0);
        }
        asm volatile("" ::: "memory");
        __builtin_amdgcn_s_barrier();
        asm volatile("" ::: "memory");
    }

    #pragma unroll
    for (int nt = 0; nt < 4; ++nt) {
        int ncol = blockIdx.y * 128 + wn * 64 + nt * 16 + l16;
        float bn = bias[ncol];
        int h = ncol >> 6, d = ncol & 63;
        #pragma unroll
        for (int mt = 0; mt < 4; ++mt) {
            int mbase = blockIdx.x * 128 + wm * 64 + mt * 16 + quad * 4;
            int bidx = mbase >> 11, s0 = mbase & 2047;
            if (vmode == 1) {
                sh4 pk;
                #pragma unroll
                for (int reg = 0; reg < 4; ++reg) pk[reg] = (short)f2bf(acc[mt][nt][reg] + bn);
                *(sh4*)&outp[(((size_t)bidx * NH + h) * 64 + d) * SQ + s0] = pk;
            } else {
                int sp = (vmode == 2) ? prem(s0) : s0;   // prem(s0+reg) == prem(s0)+reg for 4-aligned s0
                size_t base = ((size_t)bidx * NH + h) * SQ;
                #pragma unroll
                for (int reg = 0; reg < 4; ++reg)
                    outp[(base + sp + reg) * 64 + d] = f2bf(acc[mt][nt][reg] + bn);
            }
        }
    }
}

// ---------------- flash attention (S^T form, register-resident P, K=32 PV) ----------------
// EXACT round-2 structure (measured 98.2us; the r8 V-direct variant regressed
// to 157us — per-lane stride-SQ global loads are uncoalesced, 2nd confirmation
// after r7's A-direct) + T5 s_setprio(1) around the MFMA clusters (catalog:
// +4-7% on attn, m191 A/B). K and V staged via GLD16, XOR-swizzled; K=32 PV
// via key-position permutation; P packed to bf16 immediately after exp2.
__global__ __launch_bounds__(256, 4) void attn(const u16* __restrict__ qw, const u16* __restrict__ kw,
                                               const u16* __restrict__ vtw, const float* __restrict__ mbias,
                                               float* __restrict__ outp) {
    __shared__ u16 Ks[2][64 * 64];   // [key-position][64 d], 16B-chunk XOR swizzled
    __shared__ u16 Vs[2][64 * 64];   // [d][64 keys], 16B-chunk XOR swizzled
    int tid = threadIdx.x;
    int w = tid >> 6, lane = tid & 63, quad = lane >> 4, l16 = lane & 15;
    int r8 = lane >> 3, sl = lane & 7;
    int bh = blockIdx.x, b = bh >> 4;   // grid.x = bh for XCD L2 locality
    int h = bh & 15;
    int qbase = blockIdx.y * 128 + w * 32;
    const u16* qp = qw + (size_t)bh * SQ * 64;
    const u16* kp = kw + (size_t)bh * SQ * 64;
    const u16* vp = vtw + (size_t)bh * 64 * SQ;
    const float* mbp = mbias + b * SQ;

    bf16x8 aq[2][2];  // Q frags (B-operand of S^T)
    #pragma unroll
    for (int mt = 0; mt < 2; ++mt)
        #pragma unroll
        for (int ks = 0; ks < 2; ++ks)
            aq[mt][ks] = *(const bf16x8*)&qp[(size_t)(qbase + mt * 16 + l16) * 64 + ks * 32 + quad * 8];

    f4 o[2][4];
    float lrow[2] = {0.f, 0.f};  // per-lane partial row-sum for q-row l16
    #pragma unroll
    for (int mt = 0; mt < 2; ++mt)
        #pragma unroll
        for (int nt = 0; nt < 4; ++nt) o[mt][nt] = f4{0.f, 0.f, 0.f, 0.f};

    auto stage = [&](int buf, int k0) {
        #pragma unroll
        for (int j = 0; j < 2; ++j) {
            int row = w * 16 + j * 8 + r8;
            int gsl = sl ^ (row & 7);
            GLD16(kp + (size_t)(k0 + row) * 64 + gsl * 8, &Ks[buf][(w * 16 + j * 8) * 64]);
            GLD16(vp + (size_t)row * SQ + k0 + gsl * 8, &Vs[buf][(w * 16 + j * 8) * 64]);
        }
    };

    stage(0, 0);
    for (int kb = 0; kb < 32; ++kb) {
        int buf = kb & 1;
        int k0 = kb * 64;
        __syncthreads();  // staging of `buf` done; all waves done reading buf^1
        // mask-bias loads BEFORE the prefetch so their vmcnt wait doesn't drain it
        fv4 bias4[4];
        #pragma unroll
        for (int kt = 0; kt < 4; ++kt)
            bias4[kt] = *(const fv4*)&mbp[k0 + kt * 16 + quad * 4];
        if (kb + 1 < 32) stage(buf ^ 1, k0 + 64);

        // K frags (A-operand of S^T)
        bf16x8 bk[4][2];
        #pragma unroll
        for (int kt = 0; kt < 4; ++kt)
            #pragma unroll
            for (int ks = 0; ks < 2; ++ks) {
                int r = kt * 16 + l16;
                int slot = (ks * 4 + quad) ^ (r & 7);
                bk[kt][ks] = *(const bf16x8*)&Ks[buf][r * 64 + slot * 8];
            }
        // S^T[kt][mt]: lane(quad,l16) regs = key-positions 16kt+4quad+r, q-row = l16
        f4 S[4][2];
        __builtin_amdgcn_s_setprio(1);
        #pragma unroll
        for (int kt = 0; kt < 4; ++kt)
            #pragma unroll
            for (int mt = 0; mt < 2; ++mt) {
                f4 s = f4{0.f, 0.f, 0.f, 0.f};
                s = __builtin_amdgcn_mfma_f32_16x16x32_bf16(bk[kt][0], aq[mt][0], s, 0, 0, 0);
                s = __builtin_amdgcn_mfma_f32_16x16x32_bf16(bk[kt][1], aq[mt][1], s, 0, 0, 0);
                S[kt][mt] = s;
            }
        __builtin_amdgcn_s_setprio(0);
        // softmax numerator + IMMEDIATE bf16 pack: per 32-key group g, the tile
        // pair (2g,2g+1) becomes one A-fragment pa8[g][mt] (keys g*32+8q+0..7).
        bf16x8 pa8[2][2];
        #pragma unroll
        for (int g = 0; g < 2; ++g)
            #pragma unroll
            for (int mt = 0; mt < 2; ++mt) {
                f4 se = S[2 * g][mt], so = S[2 * g + 1][mt];
                float p0 = fast_exp2(se[0] * SCALE2 + bias4[2 * g][0]);
                float p1 = fast_exp2(se[1] * SCALE2 + bias4[2 * g][1]);
                float p2 = fast_exp2(se[2] * SCALE2 + bias4[2 * g][2]);
                float p3 = fast_exp2(se[3] * SCALE2 + bias4[2 * g][3]);
                float q0 = fast_exp2(so[0] * SCALE2 + bias4[2 * g + 1][0]);
                float q1 = fast_exp2(so[1] * SCALE2 + bias4[2 * g + 1][1]);
                float q2 = fast_exp2(so[2] * SCALE2 + bias4[2 * g + 1][2]);
                float q3 = fast_exp2(so[3] * SCALE2 + bias4[2 * g + 1][3]);
                lrow[mt] += ((p0 + p1) + (p2 + p3)) + ((q0 + q1) + (q2 + q3));
                uv4 wv;
                wv[0] = (__float_as_uint(p1) & 0xFFFF0000u) | (__float_as_uint(p0) >> 16);
                wv[1] = (__float_as_uint(p3) & 0xFFFF0000u) | (__float_as_uint(p2) >> 16);
                wv[2] = (__float_as_uint(q1) & 0xFFFF0000u) | (__float_as_uint(q0) >> 16);
                wv[3] = (__float_as_uint(q3) & 0xFFFF0000u) | (__float_as_uint(q2) >> 16);
                pa8[g][mt] = __builtin_bit_cast(bf16x8, wv);
            }
        // PV at K=32: B = V^T b128 fragments (8 consecutive actual keys).
        #pragma unroll
        for (int g = 0; g < 2; ++g) {
            bf16x8 bv8[4];
            #pragma unroll
            for (int nt = 0; nt < 4; ++nt) {
                int row = nt * 16 + l16;  // d
                int ch = (g * 4 + quad) ^ (row & 7);
                bv8[nt] = *(const bf16x8*)&Vs[buf][row * 64 + ch * 8];
            }
            __builtin_amdgcn_s_setprio(1);
            #pragma unroll
            for (int mt = 0; mt < 2; ++mt)
                #pragma unroll
                for (int nt = 0; nt < 4; ++nt)
                    o[mt][nt] = __builtin_amdgcn_mfma_f32_16x16x32_bf16(pa8[g][mt], bv8[nt], o[mt][nt], 0, 0, 0);
            __builtin_amdgcn_s_setprio(0);
        }
    }

    // row sums: each q-row l16's partials live in the 4 quads; reduce, redistribute
    #pragma unroll
    for (int mt = 0; mt < 2; ++mt) {
        float v = lrow[mt];
        v += __shfl_xor(v, 16);
        v += __shfl_xor(v, 32);
        #pragma unroll
        for (int reg = 0; reg < 4; ++reg) {
            float inv = 1.f / __shfl(v, quad * 4 + reg);
            int row = qbase + mt * 16 + quad * 4 + reg;
            size_t obase = ((size_t)b * SQ + row) * DM + h * 64;
            #pragma unroll
            for (int nt = 0; nt < 4; ++nt)
                outp[obase + nt * 16 + l16] = o[mt][nt][reg] * inv;
        }
    }
}

extern "C" void kernel_launch(void* const* d_in, const int* in_sizes, int n_in,
                              void* d_out, int out_size, void* d_ws, size_t ws_size,
                              hipStream_t stream) {
    (void)in_sizes; (void)n_in; (void)out_size; (void)ws_size;
    const float* Q  = (const float*)d_in[0];
    const float* K  = (const float*)d_in[1];
    const float* V  = (const float*)d_in[2];
    const int* mask = (const int*)d_in[3];
    const float* Wq = (const float*)d_in[4];
    const float* bq = (const float*)d_in[5];
    const float* Wk = (const float*)d_in[6];
    const float* bk = (const float*)d_in[7];
    const float* Wv = (const float*)d_in[8];
    const float* bv = (const float*)d_in[9];
    float* out = (float*)d_out;
    char* ws = (char*)d_ws;
    u16* q_ws  = (u16*)(ws);                                  // 16 MB  [b][h][s][d]
    u16* k_ws  = (u16*)(ws + (size_t)16 * 1024 * 1024);       // 16 MB  [b][h][prem(s)][d]
    u16* v_ws  = (u16*)(ws + (size_t)32 * 1024 * 1024);       // 16 MB  [b][h][d][s]
    u16* wbuf3 = (u16*)(ws + (size_t)48 * 1024 * 1024);       //  6 MB  [3][N][K] bf16
    float* mb  = (float*)(ws + (size_t)54 * 1024 * 1024);     // 32 KB

    cvt_wT3<<<dim3(16, 16, 3), 256, 0, stream>>>(Wq, Wk, Wv, wbuf3);
    mk_mbias<<<32, 256, 0, stream>>>(mask, mb);
    gemm3<<<dim3(64, 8, 3), 256, 0, stream>>>(Q, K, V, wbuf3, bq, bk, bv, q_ws);
    attn<<<dim3(64, 16), 256, 0, stream>>>(q_ws, k_ws, v_ws, mb, out);
}

// Round 11
// 318.991 us; speedup vs baseline: 1.4996x; 1.0989x over previous
//
#include <hip/hip_runtime.h>

#define NH 16
#define DM 1024
#define SQ 2048
#define BT 4

typedef __attribute__((ext_vector_type(8))) short bf16x8;
typedef __attribute__((ext_vector_type(4))) short sh4;
typedef __attribute__((ext_vector_type(4))) float f4;
typedef __attribute__((ext_vector_type(4))) float fv4;
typedef __attribute__((ext_vector_type(4))) unsigned uv4;
typedef unsigned short u16;

#define M2BIAS 23.083120654f   /* 16 * log2(e) */
#define SCALE2 0.18033688f     /* (1/8) * log2(e) */

__device__ __forceinline__ u16 f2bf(float f) {
    union { float f; unsigned u; } v; v.f = f;
    unsigned r = v.u + 0x7FFFu + ((v.u >> 16) & 1u);
    return (u16)(r >> 16);
}

__device__ __forceinline__ float fast_exp2(float x) {
#if __has_builtin(__builtin_amdgcn_exp2f)
    return __builtin_amdgcn_exp2f(x);
#else
    return exp2f(x);
#endif
}

// Key-position permutation: actual key s (within a 32-key group, s = 8q+4t+j)
// -> LDS/position index p = 16t + 4q + j. Makes the S^T output of two 16-key
// tiles land exactly in the A-fragment layout of mfma_f32_16x16x32_bf16
// (A[m=l16][k=8*quad+j] over actual keys), so PV needs no cross-lane exchange.
__device__ __forceinline__ int prem(int s) {
    return (s & ~31) | ((s & 4) << 2) | ((s >> 1) & 12) | (s & 3);
}

#define GLD16(gp, lp) __builtin_amdgcn_global_load_lds( \
    (const __attribute__((address_space(1))) void*)(gp), \
    (__attribute__((address_space(3))) void*)(lp), 16, 0, 0)

// ---------------- fp32 W[K][N] -> bf16 Wt[N][K], all three weights in one launch ----------------
__global__ __launch_bounds__(256) void cvt_wT3(const float* __restrict__ W0, const float* __restrict__ W1,
                                               const float* __restrict__ W2, u16* __restrict__ Wt) {
    __shared__ float t[64][65];
    const float* Wsrc = blockIdx.z == 0 ? W0 : (blockIdx.z == 1 ? W1 : W2);
    u16* dst = Wt + (size_t)blockIdx.z * DM * DM;
    int r0 = blockIdx.x * 64, c0 = blockIdx.y * 64;
    #pragma unroll
    for (int i = 0; i < 16; ++i) {
        int idx = i * 256 + threadIdx.x;
        int r = idx >> 6, c = idx & 63;
        t[r][c] = Wsrc[(size_t)(r0 + r) * DM + c0 + c];
    }
    __syncthreads();
    #pragma unroll
    for (int i = 0; i < 16; ++i) {
        int idx = i * 256 + threadIdx.x;
        int n = idx >> 6, k = idx & 63;
        dst[(size_t)(c0 + n) * DM + r0 + k] = f2bf(t[k][n]);
    }
}

// ---------------- mask -> float bias, stored at PERMUTED key position ----------------
__global__ __launch_bounds__(256) void mk_mbias(const int* __restrict__ mask, float* __restrict__ mb) {
    int i = blockIdx.x * 256 + threadIdx.x;
    mb[prem(i)] = mask[i] ? -M2BIAS : -__builtin_inff();
}

// ---------------- fused projection GEMMs: z in {Q,K,V}, [8192,1024]x[1024,1024]+bias ----------------
// ROUND-5 STRUCTURE, measured 117.9us / passed — best of 5 variants (dist-2 =
// spill 270us, reg-direct = uncoalesced 212us, single-buf 4blk/CU = spill
// 139us, plain syncthreads = 118us). A fp32 -> regs -> cvt_pk -> swizzled LDS;
// B via GLD16 double-buffered; counted vmcnt(12) leaves the 12 prefetches
// (4 B-GLD16s + 8 A-loads) in flight across the barrier.
// z=0: Q -> [b][h][s][d];  z=1: K -> [b][h][prem(s)][d];  z=2: V -> [b][h][d][s]
__global__ __launch_bounds__(256, 3) void gemm3(const float* __restrict__ Qf, const float* __restrict__ Kf,
                                                const float* __restrict__ Vf, const u16* __restrict__ Wt3,
                                                const float* __restrict__ bq, const float* __restrict__ bk,
                                                const float* __restrict__ bv, u16* __restrict__ out3) {
    __shared__ u16 As[128 * 64];
    __shared__ u16 Bs[2][128 * 64];
    int z = blockIdx.z;
    const float* Af = z == 0 ? Qf : (z == 1 ? Kf : Vf);
    const float* bias = z == 0 ? bq : (z == 1 ? bk : bv);
    int vmode = z == 0 ? 0 : (z == 1 ? 2 : 1);
    const u16* Bg = Wt3 + (size_t)z * DM * DM + (size_t)blockIdx.y * 128 * DM;
    u16* outp = out3 + (size_t)z * 8388608u;   // 8192*1024 u16 per projection

    int tid = threadIdx.x;
    int w = tid >> 6, lane = tid & 63, quad = lane >> 4, l16 = lane & 15;
    int wm = w >> 1, wn = w & 1;
    int r8 = lane >> 3, cg = (lane & 7) ^ r8;

    int arow0 = w * 32 + (lane >> 4);
    int acol = (lane & 15) * 4;
    const float* Ag = Af + (size_t)(blockIdx.x * 128 + arow0) * DM + acol;
    int ach = (lane & 15) >> 1, asub = lane & 1;

    f4 acc[4][4];
    #pragma unroll
    for (int mt = 0; mt < 4; ++mt)
        #pragma unroll
        for (int nt = 0; nt < 4; ++nt) acc[mt][nt] = f4{0.f, 0.f, 0.f, 0.f};

    fv4 ar[8];
    auto loadA = [&](int kt) {
        const float* src = Ag + kt * 64;
        #pragma unroll
        for (int j = 0; j < 8; ++j) ar[j] = *(const fv4*)(src + (size_t)j * 4 * DM);
    };
    auto stageB = [&](int buf, int kt) {
        int kofs = kt * 64 + cg * 8;
        #pragma unroll
        for (int c = 0; c < 4; ++c) {
            int rbase = w * 32 + c * 8;
            GLD16(Bg + (size_t)(rbase + r8) * DM + kofs, &Bs[buf][rbase * 64]);
        }
    };

    stageB(0, 0);
    loadA(0);

    for (int kt = 0; kt < 16; ++kt) {
        // prefetch next B tile into the other LDS buffer (stays in flight
        // across the barrier; covered by this iteration's MFMA phase)
        if (kt + 1 < 16) stageB((kt + 1) & 1, kt + 1);
        // convert current A regs -> swizzled LDS (implicit vmcnt here waits for
        // A(kt) and thereby also drains the older B(kt) GLD16s)
        #pragma unroll
        for (int j = 0; j < 8; ++j) {
            unsigned lo, hi;
            asm("v_cvt_pk_bf16_f32 %0, %1, %2" : "=v"(lo) : "v"(ar[j][0]), "v"(ar[j][1]));
            asm("v_cvt_pk_bf16_f32 %0, %1, %2" : "=v"(hi) : "v"(ar[j][2]), "v"(ar[j][3]));
            int row = arow0 + j * 4;
            uint2 pk; pk.x = lo; pk.y = hi;
            *(uint2*)&As[row * 64 + (ach ^ (row & 7)) * 8 + asub * 4] = pk;
        }
        // prefetch next A tile into the SAME regs (WAR: after converts read them)
        if (kt + 1 < 16) loadA(kt + 1);

        // pre-MFMA barrier: drain ds_writes + anything older than this
        // iteration's 12 prefetch loads; do NOT drain the prefetches.
        if (kt < 15) {
            asm volatile("s_waitcnt vmcnt(12) lgkmcnt(0)" ::: "memory");
        } else {
            asm volatile("s_waitcnt vmcnt(0) lgkmcnt(0)" ::: "memory");
        }
        __builtin_amdgcn_s_barrier();
        asm volatile("" ::: "memory");

        #pragma unroll
        for (int ks = 0; ks < 2; ++ks) {
            bf16x8 afr[4], bfr[4];
            #pragma unroll
            for (int mt = 0; mt < 4; ++mt) {
                int row = wm * 64 + mt * 16 + l16;
                int ch = (ks * 4 + quad) ^ (row & 7);
                afr[mt] = *(const bf16x8*)&As[row * 64 + ch * 8];
            }
            #pragma unroll
            for (int nt = 0; nt < 4; ++nt) {
                int row = wn * 64 + nt * 16 + l16;
                int ch = (ks * 4 + quad) ^ (row & 7);
                bfr[nt] = *(const bf16x8*)&Bs[kt & 1][row * 64 + ch * 8];
            }
            #pragma unroll
            for (int mt = 0; mt < 4; ++mt)
                #pragma unroll
                for (int nt = 0; nt < 4; ++nt)
                    acc[mt][nt] = __builtin_amdgcn_mfma_f32_16x16x32_bf16(afr[mt], bfr[nt], acc[mt][nt], 0, 0, 0);
        }
        // post-MFMA barrier: all waves' LDS reads done before next iteration's
        // As/Bs writes.
        asm volatile("" ::: "memory");
        __builtin_amdgcn_s_barrier();
        asm volatile("" ::: "memory");
    }

    #pragma unroll
    for (int nt = 0; nt < 4; ++nt) {
        int ncol = blockIdx.y * 128 + wn * 64 + nt * 16 + l16;
        float bn = bias[ncol];
        int h = ncol >> 6, d = ncol & 63;
        #pragma unroll
        for (int mt = 0; mt < 4; ++mt) {
            int mbase = blockIdx.x * 128 + wm * 64 + mt * 16 + quad * 4;
            int bidx = mbase >> 11, s0 = mbase & 2047;
            if (vmode == 1) {
                sh4 pk;
                #pragma unroll
                for (int reg = 0; reg < 4; ++reg) pk[reg] = (short)f2bf(acc[mt][nt][reg] + bn);
                *(sh4*)&outp[(((size_t)bidx * NH + h) * 64 + d) * SQ + s0] = pk;
            } else {
                int sp = (vmode == 2) ? prem(s0) : s0;   // prem(s0+reg) == prem(s0)+reg for 4-aligned s0
                size_t base = ((size_t)bidx * NH + h) * SQ;
                #pragma unroll
                for (int reg = 0; reg < 4; ++reg)
                    outp[(base + sp + reg) * 64 + d] = f2bf(acc[mt][nt][reg] + bn);
            }
        }
    }
}

// ---------------- flash attention (S^T form, register-resident P, K=32 PV) ----------------
// EXACT round-2 structure, measured 98.2us / passed (r8 V-direct = 157us
// uncoalesced; r9 setprio = ~+8us; r10 cvt_pk-pack variant = NaN fail — all
// reverted). S^T = K*Q^T with K rows in permuted position space: lane
// (quad,l16)'s S-regs over tile pair (2g,2g+1) hold actual keys g*32+8q+0..7
// for q-row l16 — the A-fragment of mfma_f32_16x16x32_bf16, so PV runs at
// K=32 (16 MFMAs/iter) with B = V^T b128 fragments. P packed to bf16
// immediately after exp2 (bit-ops) so the f32 scores die before PV.
__global__ __launch_bounds__(256, 4) void attn(const u16* __restrict__ qw, const u16* __restrict__ kw,
                                               const u16* __restrict__ vtw, const float* __restrict__ mbias,
                                               float* __restrict__ outp) {
    __shared__ u16 Ks[2][64 * 64];   // [key-position][64 d], 16B-chunk XOR swizzled
    __shared__ u16 Vs[2][64 * 64];   // [d][64 keys], 16B-chunk XOR swizzled
    int tid = threadIdx.x;
    int w = tid >> 6, lane = tid & 63, quad = lane >> 4, l16 = lane & 15;
    int r8 = lane >> 3, sl = lane & 7;
    int bh = blockIdx.x, b = bh >> 4;   // grid.x = bh for XCD L2 locality
    int h = bh & 15;
    int qbase = blockIdx.y * 128 + w * 32;
    const u16* qp = qw + (size_t)bh * SQ * 64;
    const u16* kp = kw + (size_t)bh * SQ * 64;
    const u16* vp = vtw + (size_t)bh * 64 * SQ;
    const float* mbp = mbias + b * SQ;

    bf16x8 aq[2][2];  // Q frags (B-operand of S^T)
    #pragma unroll
    for (int mt = 0; mt < 2; ++mt)
        #pragma unroll
        for (int ks = 0; ks < 2; ++ks)
            aq[mt][ks] = *(const bf16x8*)&qp[(size_t)(qbase + mt * 16 + l16) * 64 + ks * 32 + quad * 8];

    f4 o[2][4];
    float lrow[2] = {0.f, 0.f};  // per-lane partial row-sum for q-row l16
    #pragma unroll
    for (int mt = 0; mt < 2; ++mt)
        #pragma unroll
        for (int nt = 0; nt < 4; ++nt) o[mt][nt] = f4{0.f, 0.f, 0.f, 0.f};

    auto stage = [&](int buf, int k0) {
        #pragma unroll
        for (int j = 0; j < 2; ++j) {
            int row = w * 16 + j * 8 + r8;
            int gsl = sl ^ (row & 7);
            GLD16(kp + (size_t)(k0 + row) * 64 + gsl * 8, &Ks[buf][(w * 16 + j * 8) * 64]);
            GLD16(vp + (size_t)row * SQ + k0 + gsl * 8, &Vs[buf][(w * 16 + j * 8) * 64]);
        }
    };

    stage(0, 0);
    for (int kb = 0; kb < 32; ++kb) {
        int buf = kb & 1;
        int k0 = kb * 64;
        __syncthreads();  // staging of `buf` done; all waves done reading buf^1
        // mask-bias loads BEFORE the prefetch so their vmcnt wait doesn't drain it
        fv4 bias4[4];
        #pragma unroll
        for (int kt = 0; kt < 4; ++kt)
            bias4[kt] = *(const fv4*)&mbp[k0 + kt * 16 + quad * 4];
        if (kb + 1 < 32) stage(buf ^ 1, k0 + 64);

        // K frags (A-operand of S^T)
        bf16x8 bk[4][2];
        #pragma unroll
        for (int kt = 0; kt < 4; ++kt)
            #pragma unroll
            for (int ks = 0; ks < 2; ++ks) {
                int r = kt * 16 + l16;
                int slot = (ks * 4 + quad) ^ (r & 7);
                bk[kt][ks] = *(const bf16x8*)&Ks[buf][r * 64 + slot * 8];
            }
        // S^T[kt][mt]: lane(quad,l16) regs = key-positions 16kt+4quad+r, q-row = l16
        f4 S[4][2];
        #pragma unroll
        for (int kt = 0; kt < 4; ++kt)
            #pragma unroll
            for (int mt = 0; mt < 2; ++mt) {
                f4 s = f4{0.f, 0.f, 0.f, 0.f};
                s = __builtin_amdgcn_mfma_f32_16x16x32_bf16(bk[kt][0], aq[mt][0], s, 0, 0, 0);
                s = __builtin_amdgcn_mfma_f32_16x16x32_bf16(bk[kt][1], aq[mt][1], s, 0, 0, 0);
                S[kt][mt] = s;
            }
        // softmax numerator + IMMEDIATE bf16 pack: per 32-key group g, the tile
        // pair (2g,2g+1) becomes one A-fragment pa8[g][mt] (keys g*32+8q+0..7).
        bf16x8 pa8[2][2];
        #pragma unroll
        for (int g = 0; g < 2; ++g)
            #pragma unroll
            for (int mt = 0; mt < 2; ++mt) {
                f4 se = S[2 * g][mt], so = S[2 * g + 1][mt];
                float p0 = fast_exp2(se[0] * SCALE2 + bias4[2 * g][0]);
                float p1 = fast_exp2(se[1] * SCALE2 + bias4[2 * g][1]);
                float p2 = fast_exp2(se[2] * SCALE2 + bias4[2 * g][2]);
                float p3 = fast_exp2(se[3] * SCALE2 + bias4[2 * g][3]);
                float q0 = fast_exp2(so[0] * SCALE2 + bias4[2 * g + 1][0]);
                float q1 = fast_exp2(so[1] * SCALE2 + bias4[2 * g + 1][1]);
                float q2 = fast_exp2(so[2] * SCALE2 + bias4[2 * g + 1][2]);
                float q3 = fast_exp2(so[3] * SCALE2 + bias4[2 * g + 1][3]);
                lrow[mt] += ((p0 + p1) + (p2 + p3)) + ((q0 + q1) + (q2 + q3));
                uv4 wv;
                wv[0] = (__float_as_uint(p1) & 0xFFFF0000u) | (__float_as_uint(p0) >> 16);
                wv[1] = (__float_as_uint(p3) & 0xFFFF0000u) | (__float_as_uint(p2) >> 16);
                wv[2] = (__float_as_uint(q1) & 0xFFFF0000u) | (__float_as_uint(q0) >> 16);
                wv[3] = (__float_as_uint(q3) & 0xFFFF0000u) | (__float_as_uint(q2) >> 16);
                pa8[g][mt] = __builtin_bit_cast(bf16x8, wv);
            }
        // PV at K=32: B = V^T b128 fragments (8 consecutive actual keys).
        #pragma unroll
        for (int g = 0; g < 2; ++g) {
            bf16x8 bv8[4];
            #pragma unroll
            for (int nt = 0; nt < 4; ++nt) {
                int row = nt * 16 + l16;  // d
                int ch = (g * 4 + quad) ^ (row & 7);
                bv8[nt] = *(const bf16x8*)&Vs[buf][row * 64 + ch * 8];
            }
            #pragma unroll
            for (int mt = 0; mt < 2; ++mt)
                #pragma unroll
                for (int nt = 0; nt < 4; ++nt)
                    o[mt][nt] = __builtin_amdgcn_mfma_f32_16x16x32_bf16(pa8[g][mt], bv8[nt], o[mt][nt], 0, 0, 0);
        }
    }

    // row sums: each q-row l16's partials live in the 4 quads; reduce, redistribute
    #pragma unroll
    for (int mt = 0; mt < 2; ++mt) {
        float v = lrow[mt];
        v += __shfl_xor(v, 16);
        v += __shfl_xor(v, 32);
        #pragma unroll
        for (int reg = 0; reg < 4; ++reg) {
            float inv = 1.f / __shfl(v, quad * 4 + reg);
            int row = qbase + mt * 16 + quad * 4 + reg;
            size_t obase = ((size_t)b * SQ + row) * DM + h * 64;
            #pragma unroll
            for (int nt = 0; nt < 4; ++nt)
                outp[obase + nt * 16 + l16] = o[mt][nt][reg] * inv;
        }
    }
}

extern "C" void kernel_launch(void* const* d_in, const int* in_sizes, int n_in,
                              void* d_out, int out_size, void* d_ws, size_t ws_size,
                              hipStream_t stream) {
    (void)in_sizes; (void)n_in; (void)out_size; (void)ws_size;
    const float* Q  = (const float*)d_in[0];
    const float* K  = (const float*)d_in[1];
    const float* V  = (const float*)d_in[2];
    const int* mask = (const int*)d_in[3];
    const float* Wq = (const float*)d_in[4];
    const float* bq = (const float*)d_in[5];
    const float* Wk = (const float*)d_in[6];
    const float* bk = (const float*)d_in[7];
    const float* Wv = (const float*)d_in[8];
    const float* bv = (const float*)d_in[9];
    float* out = (float*)d_out;
    char* ws = (char*)d_ws;
    u16* q_ws  = (u16*)(ws);                                  // 16 MB  [b][h][s][d]
    u16* k_ws  = (u16*)(ws + (size_t)16 * 1024 * 1024);       // 16 MB  [b][h][prem(s)][d]
    u16* v_ws  = (u16*)(ws + (size_t)32 * 1024 * 1024);       // 16 MB  [b][h][d][s]
    u16* wbuf3 = (u16*)(ws + (size_t)48 * 1024 * 1024);       //  6 MB  [3][N][K] bf16
    float* mb  = (float*)(ws + (size_t)54 * 1024 * 1024);     // 32 KB

    cvt_wT3<<<dim3(16, 16, 3), 256, 0, stream>>>(Wq, Wk, Wv, wbuf3);
    mk_mbias<<<32, 256, 0, stream>>>(mask, mb);
    gemm3<<<dim3(64, 8, 3), 256, 0, stream>>>(Q, K, V, wbuf3, bq, bk, bv, q_ws);
    attn<<<dim3(64, 16), 256, 0, stream>>>(q_ws, k_ws, v_ws, mb, out);
}

// Round 12
// 316.078 us; speedup vs baseline: 1.5134x; 1.0092x over previous
//
#include <hip/hip_runtime.h>

#define NH 16
#define DM 1024
#define SQ 2048
#define BT 4

typedef __attribute__((ext_vector_type(8))) short bf16x8;
typedef __attribute__((ext_vector_type(4))) short sh4;
typedef __attribute__((ext_vector_type(4))) float f4;
typedef __attribute__((ext_vector_type(4))) float fv4;
typedef __attribute__((ext_vector_type(4))) unsigned uv4;
typedef unsigned short u16;

#define M2BIAS 23.083120654f   /* 16 * log2(e) */
#define SCALE2 0.18033688f     /* (1/8) * log2(e) */

__device__ __forceinline__ u16 f2bf(float f) {
    union { float f; unsigned u; } v; v.f = f;
    unsigned r = v.u + 0x7FFFu + ((v.u >> 16) & 1u);
    return (u16)(r >> 16);
}

__device__ __forceinline__ float fast_exp2(float x) {
#if __has_builtin(__builtin_amdgcn_exp2f)
    return __builtin_amdgcn_exp2f(x);
#else
    return exp2f(x);
#endif
}

// Key-position permutation: actual key s (within a 32-key group, s = 8q+4t+j)
// -> LDS/position index p = 16t + 4q + j. Makes the S^T output of two 16-key
// tiles land exactly in the A-fragment layout of mfma_f32_16x16x32_bf16
// (A[m=l16][k=8*quad+j] over actual keys), so PV needs no cross-lane exchange.
__device__ __forceinline__ int prem(int s) {
    return (s & ~31) | ((s & 4) << 2) | ((s >> 1) & 12) | (s & 3);
}

#define GLD16(gp, lp) __builtin_amdgcn_global_load_lds( \
    (const __attribute__((address_space(1))) void*)(gp), \
    (__attribute__((address_space(3))) void*)(lp), 16, 0, 0)

// ---------------- fp32 W[K][N] -> bf16 Wt[N][K], all three weights in one launch ----------------
__global__ __launch_bounds__(256) void cvt_wT3(const float* __restrict__ W0, const float* __restrict__ W1,
                                               const float* __restrict__ W2, u16* __restrict__ Wt) {
    __shared__ float t[64][65];
    const float* Wsrc = blockIdx.z == 0 ? W0 : (blockIdx.z == 1 ? W1 : W2);
    u16* dst = Wt + (size_t)blockIdx.z * DM * DM;
    int r0 = blockIdx.x * 64, c0 = blockIdx.y * 64;
    #pragma unroll
    for (int i = 0; i < 16; ++i) {
        int idx = i * 256 + threadIdx.x;
        int r = idx >> 6, c = idx & 63;
        t[r][c] = Wsrc[(size_t)(r0 + r) * DM + c0 + c];
    }
    __syncthreads();
    #pragma unroll
    for (int i = 0; i < 16; ++i) {
        int idx = i * 256 + threadIdx.x;
        int n = idx >> 6, k = idx & 63;
        dst[(size_t)(c0 + n) * DM + r0 + k] = f2bf(t[k][n]);
    }
}

// ---------------- mask -> float bias, stored at PERMUTED key position ----------------
__global__ __launch_bounds__(256) void mk_mbias(const int* __restrict__ mask, float* __restrict__ mb) {
    int i = blockIdx.x * 256 + threadIdx.x;
    mb[prem(i)] = mask[i] ? -M2BIAS : -__builtin_inff();
}

// ---------------- fused projection GEMMs: z in {Q,K,V}, [8192,1024]x[1024,1024]+bias ----------------
// ROUND-5 main loop (measured 117.9us — best of 5 variants). A fp32 -> regs ->
// cvt_pk -> swizzled LDS; B via GLD16 double-buffered; counted vmcnt(12).
// NEW (r12): LDS-staged COALESCED epilogue — the old epilogue's scattered 2B
// (Q/K) and strided 8B (V) stores inflated WRITE_SIZE to 71MB vs 48MB legit
// (partial-line RMW). Now: C-tile -> Bs as a 128x128 bf16 tile ([s][ncol] for
// Q/K, [ncol][s] for V), then 8 chunks/thread of ds_read_b128 + 16B store —
// every 128B output line written by exactly one full-line pair of stores.
// Math bit-identical to r11 (same f2bf, same add order) -> absmax must stay
// exactly 0.005859375.
// z=0: Q -> [b][h][s][d];  z=1: K -> [b][h][prem(s)][d];  z=2: V -> [b][h][d][s]
__global__ __launch_bounds__(256, 3) void gemm3(const float* __restrict__ Qf, const float* __restrict__ Kf,
                                                const float* __restrict__ Vf, const u16* __restrict__ Wt3,
                                                const float* __restrict__ bq, const float* __restrict__ bk,
                                                const float* __restrict__ bv, u16* __restrict__ out3) {
    __shared__ u16 As[128 * 64];
    __shared__ u16 Bs[2][128 * 64];
    int z = blockIdx.z;
    const float* Af = z == 0 ? Qf : (z == 1 ? Kf : Vf);
    const float* bias = z == 0 ? bq : (z == 1 ? bk : bv);
    int vmode = z == 0 ? 0 : (z == 1 ? 2 : 1);
    const u16* Bg = Wt3 + (size_t)z * DM * DM + (size_t)blockIdx.y * 128 * DM;
    u16* outp = out3 + (size_t)z * 8388608u;   // 8192*1024 u16 per projection

    int tid = threadIdx.x;
    int w = tid >> 6, lane = tid & 63, quad = lane >> 4, l16 = lane & 15;
    int wm = w >> 1, wn = w & 1;
    int r8 = lane >> 3, cg = (lane & 7) ^ r8;

    int arow0 = w * 32 + (lane >> 4);
    int acol = (lane & 15) * 4;
    const float* Ag = Af + (size_t)(blockIdx.x * 128 + arow0) * DM + acol;
    int ach = (lane & 15) >> 1, asub = lane & 1;

    f4 acc[4][4];
    #pragma unroll
    for (int mt = 0; mt < 4; ++mt)
        #pragma unroll
        for (int nt = 0; nt < 4; ++nt) acc[mt][nt] = f4{0.f, 0.f, 0.f, 0.f};

    fv4 ar[8];
    auto loadA = [&](int kt) {
        const float* src = Ag + kt * 64;
        #pragma unroll
        for (int j = 0; j < 8; ++j) ar[j] = *(const fv4*)(src + (size_t)j * 4 * DM);
    };
    auto stageB = [&](int buf, int kt) {
        int kofs = kt * 64 + cg * 8;
        #pragma unroll
        for (int c = 0; c < 4; ++c) {
            int rbase = w * 32 + c * 8;
            GLD16(Bg + (size_t)(rbase + r8) * DM + kofs, &Bs[buf][rbase * 64]);
        }
    };

    stageB(0, 0);
    loadA(0);

    for (int kt = 0; kt < 16; ++kt) {
        // prefetch next B tile into the other LDS buffer (stays in flight
        // across the barrier; covered by this iteration's MFMA phase)
        if (kt + 1 < 16) stageB((kt + 1) & 1, kt + 1);
        // convert current A regs -> swizzled LDS (implicit vmcnt here waits for
        // A(kt) and thereby also drains the older B(kt) GLD16s)
        #pragma unroll
        for (int j = 0; j < 8; ++j) {
            unsigned lo, hi;
            asm("v_cvt_pk_bf16_f32 %0, %1, %2" : "=v"(lo) : "v"(ar[j][0]), "v"(ar[j][1]));
            asm("v_cvt_pk_bf16_f32 %0, %1, %2" : "=v"(hi) : "v"(ar[j][2]), "v"(ar[j][3]));
            int row = arow0 + j * 4;
            uint2 pk; pk.x = lo; pk.y = hi;
            *(uint2*)&As[row * 64 + (ach ^ (row & 7)) * 8 + asub * 4] = pk;
        }
        // prefetch next A tile into the SAME regs (WAR: after converts read them)
        if (kt + 1 < 16) loadA(kt + 1);

        // pre-MFMA barrier: drain ds_writes + anything older than this
        // iteration's 12 prefetch loads; do NOT drain the prefetches.
        if (kt < 15) {
            asm volatile("s_waitcnt vmcnt(12) lgkmcnt(0)" ::: "memory");
        } else {
            asm volatile("s_waitcnt vmcnt(0) lgkmcnt(0)" ::: "memory");
        }
        __builtin_amdgcn_s_barrier();
        asm volatile("" ::: "memory");

        #pragma unroll
        for (int ks = 0; ks < 2; ++ks) {
            bf16x8 afr[4], bfr[4];
            #pragma unroll
            for (int mt = 0; mt < 4; ++mt) {
                int row = wm * 64 + mt * 16 + l16;
                int ch = (ks * 4 + quad) ^ (row & 7);
                afr[mt] = *(const bf16x8*)&As[row * 64 + ch * 8];
            }
            #pragma unroll
            for (int nt = 0; nt < 4; ++nt) {
                int row = wn * 64 + nt * 16 + l16;
                int ch = (ks * 4 + quad) ^ (row & 7);
                bfr[nt] = *(const bf16x8*)&Bs[kt & 1][row * 64 + ch * 8];
            }
            #pragma unroll
            for (int mt = 0; mt < 4; ++mt)
                #pragma unroll
                for (int nt = 0; nt < 4; ++nt)
                    acc[mt][nt] = __builtin_amdgcn_mfma_f32_16x16x32_bf16(afr[mt], bfr[nt], acc[mt][nt], 0, 0, 0);
        }
        // post-MFMA barrier: all waves' LDS reads done before next iteration's
        // As/Bs writes.
        asm volatile("" ::: "memory");
        __builtin_amdgcn_s_barrier();
        asm volatile("" ::: "memory");
    }

    // ---- epilogue: stage C-tile (bias-added bf16) in LDS, then 16B coalesced stores ----
    // After the final post-MFMA barrier all waves are done with As/Bs.
    u16* tile = &Bs[0][0];   // 128 x 128 u16 = 32 KB exactly
    #pragma unroll
    for (int nt = 0; nt < 4; ++nt) {
        int cl = wn * 64 + nt * 16 + l16;                 // local ncol
        float bn = bias[blockIdx.y * 128 + cl];
        #pragma unroll
        for (int mt = 0; mt < 4; ++mt) {
            int sl = wm * 64 + mt * 16 + quad * 4;        // local s (base of 4)
            #pragma unroll
            for (int reg = 0; reg < 4; ++reg) {
                u16 v = f2bf(acc[mt][nt][reg] + bn);
                if (vmode == 1) tile[cl * 128 + sl + reg] = v;   // [ncol][s]
                else            tile[(sl + reg) * 128 + cl] = v; // [s][ncol]
            }
        }
    }
    __syncthreads();
    int sbase = blockIdx.x * 128;
    int bidx = sbase >> 11, s0b = sbase & 2047;
    #pragma unroll
    for (int i = 0; i < 8; ++i) {
        int chunk = i * 256 + tid;            // 2048 chunks of 8 u16 (16B)
        int row = chunk >> 4, cc = chunk & 15;
        bf16x8 val = *(const bf16x8*)&tile[row * 128 + cc * 8];
        size_t gidx;
        if (vmode == 1) {
            // out[b][h][d][s]: tile row = local ncol, 8 consecutive s
            int ncol = blockIdx.y * 128 + row;
            gidx = (((size_t)bidx * NH + (ncol >> 6)) * 64 + (ncol & 63)) * SQ + s0b + cc * 8;
        } else {
            // out[b][h][s][d]: tile row = local s, 8 consecutive d (within one h)
            int s = s0b + row;
            int sg = (vmode == 2) ? prem(s) : s;
            int ncol0 = blockIdx.y * 128 + cc * 8;
            gidx = (((size_t)bidx * NH + (ncol0 >> 6)) * SQ + sg) * 64 + (ncol0 & 63);
        }
        *(bf16x8*)&outp[gidx] = val;
    }
}

// ---------------- flash attention (S^T form, register-resident P, K=32 PV) ----------------
// EXACT round-2 structure, measured 98.2us / passed (r8 V-direct = 157us
// uncoalesced; r9 setprio = ~+8us; r10 cvt_pk-pack variant = NaN fail — all
// reverted). S^T = K*Q^T with K rows in permuted position space: lane
// (quad,l16)'s S-regs over tile pair (2g,2g+1) hold actual keys g*32+8q+0..7
// for q-row l16 — the A-fragment of mfma_f32_16x16x32_bf16, so PV runs at
// K=32 (16 MFMAs/iter) with B = V^T b128 fragments. P packed to bf16
// immediately after exp2 (bit-ops) so the f32 scores die before PV.
__global__ __launch_bounds__(256, 4) void attn(const u16* __restrict__ qw, const u16* __restrict__ kw,
                                               const u16* __restrict__ vtw, const float* __restrict__ mbias,
                                               float* __restrict__ outp) {
    __shared__ u16 Ks[2][64 * 64];   // [key-position][64 d], 16B-chunk XOR swizzled
    __shared__ u16 Vs[2][64 * 64];   // [d][64 keys], 16B-chunk XOR swizzled
    int tid = threadIdx.x;
    int w = tid >> 6, lane = tid & 63, quad = lane >> 4, l16 = lane & 15;
    int r8 = lane >> 3, sl = lane & 7;
    int bh = blockIdx.x, b = bh >> 4;   // grid.x = bh for XCD L2 locality
    int h = bh & 15;
    int qbase = blockIdx.y * 128 + w * 32;
    const u16* qp = qw + (size_t)bh * SQ * 64;
    const u16* kp = kw + (size_t)bh * SQ * 64;
    const u16* vp = vtw + (size_t)bh * 64 * SQ;
    const float* mbp = mbias + b * SQ;

    bf16x8 aq[2][2];  // Q frags (B-operand of S^T)
    #pragma unroll
    for (int mt = 0; mt < 2; ++mt)
        #pragma unroll
        for (int ks = 0; ks < 2; ++ks)
            aq[mt][ks] = *(const bf16x8*)&qp[(size_t)(qbase + mt * 16 + l16) * 64 + ks * 32 + quad * 8];

    f4 o[2][4];
    float lrow[2] = {0.f, 0.f};  // per-lane partial row-sum for q-row l16
    #pragma unroll
    for (int mt = 0; mt < 2; ++mt)
        #pragma unroll
        for (int nt = 0; nt < 4; ++nt) o[mt][nt] = f4{0.f, 0.f, 0.f, 0.f};

    auto stage = [&](int buf, int k0) {
        #pragma unroll
        for (int j = 0; j < 2; ++j) {
            int row = w * 16 + j * 8 + r8;
            int gsl = sl ^ (row & 7);
            GLD16(kp + (size_t)(k0 + row) * 64 + gsl * 8, &Ks[buf][(w * 16 + j * 8) * 64]);
            GLD16(vp + (size_t)row * SQ + k0 + gsl * 8, &Vs[buf][(w * 16 + j * 8) * 64]);
        }
    };

    stage(0, 0);
    for (int kb = 0; kb < 32; ++kb) {
        int buf = kb & 1;
        int k0 = kb * 64;
        __syncthreads();  // staging of `buf` done; all waves done reading buf^1
        // mask-bias loads BEFORE the prefetch so their vmcnt wait doesn't drain it
        fv4 bias4[4];
        #pragma unroll
        for (int kt = 0; kt < 4; ++kt)
            bias4[kt] = *(const fv4*)&mbp[k0 + kt * 16 + quad * 4];
        if (kb + 1 < 32) stage(buf ^ 1, k0 + 64);

        // K frags (A-operand of S^T)
        bf16x8 bk[4][2];
        #pragma unroll
        for (int kt = 0; kt < 4; ++kt)
            #pragma unroll
            for (int ks = 0; ks < 2; ++ks) {
                int r = kt * 16 + l16;
                int slot = (ks * 4 + quad) ^ (r & 7);
                bk[kt][ks] = *(const bf16x8*)&Ks[buf][r * 64 + slot * 8];
            }
        // S^T[kt][mt]: lane(quad,l16) regs = key-positions 16kt+4quad+r, q-row = l16
        f4 S[4][2];
        #pragma unroll
        for (int kt = 0; kt < 4; ++kt)
            #pragma unroll
            for (int mt = 0; mt < 2; ++mt) {
                f4 s = f4{0.f, 0.f, 0.f, 0.f};
                s = __builtin_amdgcn_mfma_f32_16x16x32_bf16(bk[kt][0], aq[mt][0], s, 0, 0, 0);
                s = __builtin_amdgcn_mfma_f32_16x16x32_bf16(bk[kt][1], aq[mt][1], s, 0, 0, 0);
                S[kt][mt] = s;
            }
        // softmax numerator + IMMEDIATE bf16 pack: per 32-key group g, the tile
        // pair (2g,2g+1) becomes one A-fragment pa8[g][mt] (keys g*32+8q+0..7).
        bf16x8 pa8[2][2];
        #pragma unroll
        for (int g = 0; g < 2; ++g)
            #pragma unroll
            for (int mt = 0; mt < 2; ++mt) {
                f4 se = S[2 * g][mt], so = S[2 * g + 1][mt];
                float p0 = fast_exp2(se[0] * SCALE2 + bias4[2 * g][0]);
                float p1 = fast_exp2(se[1] * SCALE2 + bias4[2 * g][1]);
                float p2 = fast_exp2(se[2] * SCALE2 + bias4[2 * g][2]);
                float p3 = fast_exp2(se[3] * SCALE2 + bias4[2 * g][3]);
                float q0 = fast_exp2(so[0] * SCALE2 + bias4[2 * g + 1][0]);
                float q1 = fast_exp2(so[1] * SCALE2 + bias4[2 * g + 1][1]);
                float q2 = fast_exp2(so[2] * SCALE2 + bias4[2 * g + 1][2]);
                float q3 = fast_exp2(so[3] * SCALE2 + bias4[2 * g + 1][3]);
                lrow[mt] += ((p0 + p1) + (p2 + p3)) + ((q0 + q1) + (q2 + q3));
                uv4 wv;
                wv[0] = (__float_as_uint(p1) & 0xFFFF0000u) | (__float_as_uint(p0) >> 16);
                wv[1] = (__float_as_uint(p3) & 0xFFFF0000u) | (__float_as_uint(p2) >> 16);
                wv[2] = (__float_as_uint(q1) & 0xFFFF0000u) | (__float_as_uint(q0) >> 16);
                wv[3] = (__float_as_uint(q3) & 0xFFFF0000u) | (__float_as_uint(q2) >> 16);
                pa8[g][mt] = __builtin_bit_cast(bf16x8, wv);
            }
        // PV at K=32: B = V^T b128 fragments (8 consecutive actual keys).
        #pragma unroll
        for (int g = 0; g < 2; ++g) {
            bf16x8 bv8[4];
            #pragma unroll
            for (int nt = 0; nt < 4; ++nt) {
                int row = nt * 16 + l16;  // d
                int ch = (g * 4 + quad) ^ (row & 7);
                bv8[nt] = *(const bf16x8*)&Vs[buf][row * 64 + ch * 8];
            }
            #pragma unroll
            for (int mt = 0; mt < 2; ++mt)
                #pragma unroll
                for (int nt = 0; nt < 4; ++nt)
                    o[mt][nt] = __builtin_amdgcn_mfma_f32_16x16x32_bf16(pa8[g][mt], bv8[nt], o[mt][nt], 0, 0, 0);
        }
    }

    // row sums: each q-row l16's partials live in the 4 quads; reduce, redistribute
    #pragma unroll
    for (int mt = 0; mt < 2; ++mt) {
        float v = lrow[mt];
        v += __shfl_xor(v, 16);
        v += __shfl_xor(v, 32);
        #pragma unroll
        for (int reg = 0; reg < 4; ++reg) {
            float inv = 1.f / __shfl(v, quad * 4 + reg);
            int row = qbase + mt * 16 + quad * 4 + reg;
            size_t obase = ((size_t)b * SQ + row) * DM + h * 64;
            #pragma unroll
            for (int nt = 0; nt < 4; ++nt)
                outp[obase + nt * 16 + l16] = o[mt][nt][reg] * inv;
        }
    }
}

extern "C" void kernel_launch(void* const* d_in, const int* in_sizes, int n_in,
                              void* d_out, int out_size, void* d_ws, size_t ws_size,
                              hipStream_t stream) {
    (void)in_sizes; (void)n_in; (void)out_size; (void)ws_size;
    const float* Q  = (const float*)d_in[0];
    const float* K  = (const float*)d_in[1];
    const float* V  = (const float*)d_in[2];
    const int* mask = (const int*)d_in[3];
    const float* Wq = (const float*)d_in[4];
    const float* bq = (const float*)d_in[5];
    const float* Wk = (const float*)d_in[6];
    const float* bk = (const float*)d_in[7];
    const float* Wv = (const float*)d_in[8];
    const float* bv = (const float*)d_in[9];
    float* out = (float*)d_out;
    char* ws = (char*)d_ws;
    u16* q_ws  = (u16*)(ws);                                  // 16 MB  [b][h][s][d]
    u16* k_ws  = (u16*)(ws + (size_t)16 * 1024 * 1024);       // 16 MB  [b][h][prem(s)][d]
    u16* v_ws  = (u16*)(ws + (size_t)32 * 1024 * 1024);       // 16 MB  [b][h][d][s]
    u16* wbuf3 = (u16*)(ws + (size_t)48 * 1024 * 1024);       //  6 MB  [3][N][K] bf16
    float* mb  = (float*)(ws + (size_t)54 * 1024 * 1024);     // 32 KB

    cvt_wT3<<<dim3(16, 16, 3), 256, 0, stream>>>(Wq, Wk, Wv, wbuf3);
    mk_mbias<<<32, 256, 0, stream>>>(mask, mb);
    gemm3<<<dim3(64, 8, 3), 256, 0, stream>>>(Q, K, V, wbuf3, bq, bk, bv, q_ws);
    attn<<<dim3(64, 16), 256, 0, stream>>>(q_ws, k_ws, v_ws, mb, out);
}

// Round 13
// 309.789 us; speedup vs baseline: 1.5441x; 1.0203x over previous
//
#include <hip/hip_runtime.h>

#define NH 16
#define DM 1024
#define SQ 2048
#define BT 4

typedef __attribute__((ext_vector_type(8))) short bf16x8;
typedef __attribute__((ext_vector_type(4))) short sh4;
typedef __attribute__((ext_vector_type(4))) float f4;
typedef __attribute__((ext_vector_type(4))) float fv4;
typedef __attribute__((ext_vector_type(4))) unsigned uv4;
typedef unsigned short u16;

#define M2BIAS 23.083120654f   /* 16 * log2(e) */
#define SCALE2 0.18033688f     /* (1/8) * log2(e) */

__device__ __forceinline__ u16 f2bf(float f) {
    union { float f; unsigned u; } v; v.f = f;
    unsigned r = v.u + 0x7FFFu + ((v.u >> 16) & 1u);
    return (u16)(r >> 16);
}

__device__ __forceinline__ float fast_exp2(float x) {
#if __has_builtin(__builtin_amdgcn_exp2f)
    return __builtin_amdgcn_exp2f(x);
#else
    return exp2f(x);
#endif
}

// Key-position permutation: actual key s (within a 32-key group, s = 8q+4t+j)
// -> LDS/position index p = 16t + 4q + j. Makes the S^T output of two 16-key
// tiles land exactly in the A-fragment layout of mfma_f32_16x16x32_bf16
// (A[m=l16][k=8*quad+j] over actual keys), so PV needs no cross-lane exchange.
__device__ __forceinline__ int prem(int s) {
    return (s & ~31) | ((s & 4) << 2) | ((s >> 1) & 12) | (s & 3);
}

#define GLD16(gp, lp) __builtin_amdgcn_global_load_lds( \
    (const __attribute__((address_space(1))) void*)(gp), \
    (__attribute__((address_space(3))) void*)(lp), 16, 0, 0)

// ---------------- fp32 W[K][N] -> bf16 Wt[N][K], all three weights in one launch ----------------
__global__ __launch_bounds__(256) void cvt_wT3(const float* __restrict__ W0, const float* __restrict__ W1,
                                               const float* __restrict__ W2, u16* __restrict__ Wt) {
    __shared__ float t[64][65];
    const float* Wsrc = blockIdx.z == 0 ? W0 : (blockIdx.z == 1 ? W1 : W2);
    u16* dst = Wt + (size_t)blockIdx.z * DM * DM;
    int r0 = blockIdx.x * 64, c0 = blockIdx.y * 64;
    #pragma unroll
    for (int i = 0; i < 16; ++i) {
        int idx = i * 256 + threadIdx.x;
        int r = idx >> 6, c = idx & 63;
        t[r][c] = Wsrc[(size_t)(r0 + r) * DM + c0 + c];
    }
    __syncthreads();
    #pragma unroll
    for (int i = 0; i < 16; ++i) {
        int idx = i * 256 + threadIdx.x;
        int n = idx >> 6, k = idx & 63;
        dst[(size_t)(c0 + n) * DM + r0 + k] = f2bf(t[k][n]);
    }
}

// ---------------- mask -> float bias, stored at PERMUTED key position ----------------
__global__ __launch_bounds__(256) void mk_mbias(const int* __restrict__ mask, float* __restrict__ mb) {
    int i = blockIdx.x * 256 + threadIdx.x;
    mb[prem(i)] = mask[i] ? -M2BIAS : -__builtin_inff();
}

// ---------------- fused projection GEMMs: z in {Q,K,V}, [8192,1024]x[1024,1024]+bias ----------------
// ROUND-5 main loop (best of 5 measured variants). A fp32 -> regs -> cvt_pk ->
// swizzled LDS; B via GLD16 double-buffered; counted vmcnt(12).
// r12: LDS-staged coalesced epilogue (WRITE 71->48MB, dur -5us, but introduced
// 4.46M LDS bank conflicts: Q/K scalar column-stores hit 8 banks 8-way, V b64
// stores ~16-way).
// r13: row-dependent chunk XOR-swizzle on the staging tile — element (row,col)
// at row*128 + ((col>>3) ^ ((row>>1)&7))*8 + (col&7). Per store instruction
// the 4 quads carry XOR values {0,2,4,6}+c, spreading 64 lanes over 32 banks
// at 2-way (= free, m136). Bijective per row; bytes identical -> absmax must
// stay exactly 0.005859375.
// z=0: Q -> [b][h][s][d];  z=1: K -> [b][h][prem(s)][d];  z=2: V -> [b][h][d][s]
__global__ __launch_bounds__(256, 3) void gemm3(const float* __restrict__ Qf, const float* __restrict__ Kf,
                                                const float* __restrict__ Vf, const u16* __restrict__ Wt3,
                                                const float* __restrict__ bq, const float* __restrict__ bk,
                                                const float* __restrict__ bv, u16* __restrict__ out3) {
    __shared__ u16 As[128 * 64];
    __shared__ u16 Bs[2][128 * 64];
    int z = blockIdx.z;
    const float* Af = z == 0 ? Qf : (z == 1 ? Kf : Vf);
    const float* bias = z == 0 ? bq : (z == 1 ? bk : bv);
    int vmode = z == 0 ? 0 : (z == 1 ? 2 : 1);
    const u16* Bg = Wt3 + (size_t)z * DM * DM + (size_t)blockIdx.y * 128 * DM;
    u16* outp = out3 + (size_t)z * 8388608u;   // 8192*1024 u16 per projection

    int tid = threadIdx.x;
    int w = tid >> 6, lane = tid & 63, quad = lane >> 4, l16 = lane & 15;
    int wm = w >> 1, wn = w & 1;
    int r8 = lane >> 3, cg = (lane & 7) ^ r8;

    int arow0 = w * 32 + (lane >> 4);
    int acol = (lane & 15) * 4;
    const float* Ag = Af + (size_t)(blockIdx.x * 128 + arow0) * DM + acol;
    int ach = (lane & 15) >> 1, asub = lane & 1;

    f4 acc[4][4];
    #pragma unroll
    for (int mt = 0; mt < 4; ++mt)
        #pragma unroll
        for (int nt = 0; nt < 4; ++nt) acc[mt][nt] = f4{0.f, 0.f, 0.f, 0.f};

    fv4 ar[8];
    auto loadA = [&](int kt) {
        const float* src = Ag + kt * 64;
        #pragma unroll
        for (int j = 0; j < 8; ++j) ar[j] = *(const fv4*)(src + (size_t)j * 4 * DM);
    };
    auto stageB = [&](int buf, int kt) {
        int kofs = kt * 64 + cg * 8;
        #pragma unroll
        for (int c = 0; c < 4; ++c) {
            int rbase = w * 32 + c * 8;
            GLD16(Bg + (size_t)(rbase + r8) * DM + kofs, &Bs[buf][rbase * 64]);
        }
    };

    stageB(0, 0);
    loadA(0);

    for (int kt = 0; kt < 16; ++kt) {
        // prefetch next B tile into the other LDS buffer (stays in flight
        // across the barrier; covered by this iteration's MFMA phase)
        if (kt + 1 < 16) stageB((kt + 1) & 1, kt + 1);
        // convert current A regs -> swizzled LDS (implicit vmcnt here waits for
        // A(kt) and thereby also drains the older B(kt) GLD16s)
        #pragma unroll
        for (int j = 0; j < 8; ++j) {
            unsigned lo, hi;
            asm("v_cvt_pk_bf16_f32 %0, %1, %2" : "=v"(lo) : "v"(ar[j][0]), "v"(ar[j][1]));
            asm("v_cvt_pk_bf16_f32 %0, %1, %2" : "=v"(hi) : "v"(ar[j][2]), "v"(ar[j][3]));
            int row = arow0 + j * 4;
            uint2 pk; pk.x = lo; pk.y = hi;
            *(uint2*)&As[row * 64 + (ach ^ (row & 7)) * 8 + asub * 4] = pk;
        }
        // prefetch next A tile into the SAME regs (WAR: after converts read them)
        if (kt + 1 < 16) loadA(kt + 1);

        // pre-MFMA barrier: drain ds_writes + anything older than this
        // iteration's 12 prefetch loads; do NOT drain the prefetches.
        if (kt < 15) {
            asm volatile("s_waitcnt vmcnt(12) lgkmcnt(0)" ::: "memory");
        } else {
            asm volatile("s_waitcnt vmcnt(0) lgkmcnt(0)" ::: "memory");
        }
        __builtin_amdgcn_s_barrier();
        asm volatile("" ::: "memory");

        #pragma unroll
        for (int ks = 0; ks < 2; ++ks) {
            bf16x8 afr[4], bfr[4];
            #pragma unroll
            for (int mt = 0; mt < 4; ++mt) {
                int row = wm * 64 + mt * 16 + l16;
                int ch = (ks * 4 + quad) ^ (row & 7);
                afr[mt] = *(const bf16x8*)&As[row * 64 + ch * 8];
            }
            #pragma unroll
            for (int nt = 0; nt < 4; ++nt) {
                int row = wn * 64 + nt * 16 + l16;
                int ch = (ks * 4 + quad) ^ (row & 7);
                bfr[nt] = *(const bf16x8*)&Bs[kt & 1][row * 64 + ch * 8];
            }
            #pragma unroll
            for (int mt = 0; mt < 4; ++mt)
                #pragma unroll
                for (int nt = 0; nt < 4; ++nt)
                    acc[mt][nt] = __builtin_amdgcn_mfma_f32_16x16x32_bf16(afr[mt], bfr[nt], acc[mt][nt], 0, 0, 0);
        }
        // post-MFMA barrier: all waves' LDS reads done before next iteration's
        // As/Bs writes.
        asm volatile("" ::: "memory");
        __builtin_amdgcn_s_barrier();
        asm volatile("" ::: "memory");
    }

    // ---- epilogue: stage C-tile (bias-added bf16) in LDS, then 16B coalesced stores ----
    // Swizzled tile: (row,col) -> row*128 + ((col>>3) ^ ((row>>1)&7))*8 + (col&7).
    u16* tile = &Bs[0][0];   // 128 x 128 u16 = 32 KB exactly
    #pragma unroll
    for (int nt = 0; nt < 4; ++nt) {
        int cl = wn * 64 + nt * 16 + l16;                 // local ncol
        float bn = bias[blockIdx.y * 128 + cl];
        #pragma unroll
        for (int mt = 0; mt < 4; ++mt) {
            int sl = wm * 64 + mt * 16 + quad * 4;        // local s (base of 4)
            #pragma unroll
            for (int reg = 0; reg < 4; ++reg) {
                u16 v = f2bf(acc[mt][nt][reg] + bn);
                if (vmode == 1) {
                    int row = cl, col = sl + reg;         // [ncol][s]
                    tile[row * 128 + (((col >> 3) ^ ((row >> 1) & 7)) << 3) + (col & 7)] = v;
                } else {
                    int row = sl + reg, col = cl;         // [s][ncol]
                    tile[row * 128 + (((col >> 3) ^ ((row >> 1) & 7)) << 3) + (col & 7)] = v;
                }
            }
        }
    }
    __syncthreads();
    int sbase = blockIdx.x * 128;
    int bidx = sbase >> 11, s0b = sbase & 2047;
    #pragma unroll
    for (int i = 0; i < 8; ++i) {
        int chunk = i * 256 + tid;            // 2048 chunks of 8 u16 (16B)
        int row = chunk >> 4, cc = chunk & 15;
        bf16x8 val = *(const bf16x8*)&tile[row * 128 + ((cc ^ ((row >> 1) & 7)) << 3)];
        size_t gidx;
        if (vmode == 1) {
            // out[b][h][d][s]: tile row = local ncol, 8 consecutive s
            int ncol = blockIdx.y * 128 + row;
            gidx = (((size_t)bidx * NH + (ncol >> 6)) * 64 + (ncol & 63)) * SQ + s0b + cc * 8;
        } else {
            // out[b][h][s][d]: tile row = local s, 8 consecutive d (within one h)
            int s = s0b + row;
            int sg = (vmode == 2) ? prem(s) : s;
            int ncol0 = blockIdx.y * 128 + cc * 8;
            gidx = (((size_t)bidx * NH + (ncol0 >> 6)) * SQ + sg) * 64 + (ncol0 & 63);
        }
        *(bf16x8*)&outp[gidx] = val;
    }
}

// ---------------- flash attention (S^T form, register-resident P, K=32 PV) ----------------
// EXACT round-2 structure, measured 98.2us / passed (r8 V-direct = 157us
// uncoalesced; r9 setprio = ~+8us; r10 cvt_pk-pack variant = NaN fail — all
// reverted). S^T = K*Q^T with K rows in permuted position space: lane
// (quad,l16)'s S-regs over tile pair (2g,2g+1) hold actual keys g*32+8q+0..7
// for q-row l16 — the A-fragment of mfma_f32_16x16x32_bf16, so PV runs at
// K=32 (16 MFMAs/iter) with B = V^T b128 fragments. P packed to bf16
// immediately after exp2 (bit-ops) so the f32 scores die before PV.
__global__ __launch_bounds__(256, 4) void attn(const u16* __restrict__ qw, const u16* __restrict__ kw,
                                               const u16* __restrict__ vtw, const float* __restrict__ mbias,
                                               float* __restrict__ outp) {
    __shared__ u16 Ks[2][64 * 64];   // [key-position][64 d], 16B-chunk XOR swizzled
    __shared__ u16 Vs[2][64 * 64];   // [d][64 keys], 16B-chunk XOR swizzled
    int tid = threadIdx.x;
    int w = tid >> 6, lane = tid & 63, quad = lane >> 4, l16 = lane & 15;
    int r8 = lane >> 3, sl = lane & 7;
    int bh = blockIdx.x, b = bh >> 4;   // grid.x = bh for XCD L2 locality
    int h = bh & 15;
    int qbase = blockIdx.y * 128 + w * 32;
    const u16* qp = qw + (size_t)bh * SQ * 64;
    const u16* kp = kw + (size_t)bh * SQ * 64;
    const u16* vp = vtw + (size_t)bh * 64 * SQ;
    const float* mbp = mbias + b * SQ;

    bf16x8 aq[2][2];  // Q frags (B-operand of S^T)
    #pragma unroll
    for (int mt = 0; mt < 2; ++mt)
        #pragma unroll
        for (int ks = 0; ks < 2; ++ks)
            aq[mt][ks] = *(const bf16x8*)&qp[(size_t)(qbase + mt * 16 + l16) * 64 + ks * 32 + quad * 8];

    f4 o[2][4];
    float lrow[2] = {0.f, 0.f};  // per-lane partial row-sum for q-row l16
    #pragma unroll
    for (int mt = 0; mt < 2; ++mt)
        #pragma unroll
        for (int nt = 0; nt < 4; ++nt) o[mt][nt] = f4{0.f, 0.f, 0.f, 0.f};

    auto stage = [&](int buf, int k0) {
        #pragma unroll
        for (int j = 0; j < 2; ++j) {
            int row = w * 16 + j * 8 + r8;
            int gsl = sl ^ (row & 7);
            GLD16(kp + (size_t)(k0 + row) * 64 + gsl * 8, &Ks[buf][(w * 16 + j * 8) * 64]);
            GLD16(vp + (size_t)row * SQ + k0 + gsl * 8, &Vs[buf][(w * 16 + j * 8) * 64]);
        }
    };

    stage(0, 0);
    for (int kb = 0; kb < 32; ++kb) {
        int buf = kb & 1;
        int k0 = kb * 64;
        __syncthreads();  // staging of `buf` done; all waves done reading buf^1
        // mask-bias loads BEFORE the prefetch so their vmcnt wait doesn't drain it
        fv4 bias4[4];
        #pragma unroll
        for (int kt = 0; kt < 4; ++kt)
            bias4[kt] = *(const fv4*)&mbp[k0 + kt * 16 + quad * 4];
        if (kb + 1 < 32) stage(buf ^ 1, k0 + 64);

        // K frags (A-operand of S^T)
        bf16x8 bk[4][2];
        #pragma unroll
        for (int kt = 0; kt < 4; ++kt)
            #pragma unroll
            for (int ks = 0; ks < 2; ++ks) {
                int r = kt * 16 + l16;
                int slot = (ks * 4 + quad) ^ (r & 7);
                bk[kt][ks] = *(const bf16x8*)&Ks[buf][r * 64 + slot * 8];
            }
        // S^T[kt][mt]: lane(quad,l16) regs = key-positions 16kt+4quad+r, q-row = l16
        f4 S[4][2];
        #pragma unroll
        for (int kt = 0; kt < 4; ++kt)
            #pragma unroll
            for (int mt = 0; mt < 2; ++mt) {
                f4 s = f4{0.f, 0.f, 0.f, 0.f};
                s = __builtin_amdgcn_mfma_f32_16x16x32_bf16(bk[kt][0], aq[mt][0], s, 0, 0, 0);
                s = __builtin_amdgcn_mfma_f32_16x16x32_bf16(bk[kt][1], aq[mt][1], s, 0, 0, 0);
                S[kt][mt] = s;
            }
        // softmax numerator + IMMEDIATE bf16 pack: per 32-key group g, the tile
        // pair (2g,2g+1) becomes one A-fragment pa8[g][mt] (keys g*32+8q+0..7).
        bf16x8 pa8[2][2];
        #pragma unroll
        for (int g = 0; g < 2; ++g)
            #pragma unroll
            for (int mt = 0; mt < 2; ++mt) {
                f4 se = S[2 * g][mt], so = S[2 * g + 1][mt];
                float p0 = fast_exp2(se[0] * SCALE2 + bias4[2 * g][0]);
                float p1 = fast_exp2(se[1] * SCALE2 + bias4[2 * g][1]);
                float p2 = fast_exp2(se[2] * SCALE2 + bias4[2 * g][2]);
                float p3 = fast_exp2(se[3] * SCALE2 + bias4[2 * g][3]);
                float q0 = fast_exp2(so[0] * SCALE2 + bias4[2 * g + 1][0]);
                float q1 = fast_exp2(so[1] * SCALE2 + bias4[2 * g + 1][1]);
                float q2 = fast_exp2(so[2] * SCALE2 + bias4[2 * g + 1][2]);
                float q3 = fast_exp2(so[3] * SCALE2 + bias4[2 * g + 1][3]);
                lrow[mt] += ((p0 + p1) + (p2 + p3)) + ((q0 + q1) + (q2 + q3));
                uv4 wv;
                wv[0] = (__float_as_uint(p1) & 0xFFFF0000u) | (__float_as_uint(p0) >> 16);
                wv[1] = (__float_as_uint(p3) & 0xFFFF0000u) | (__float_as_uint(p2) >> 16);
                wv[2] = (__float_as_uint(q1) & 0xFFFF0000u) | (__float_as_uint(q0) >> 16);
                wv[3] = (__float_as_uint(q3) & 0xFFFF0000u) | (__float_as_uint(q2) >> 16);
                pa8[g][mt] = __builtin_bit_cast(bf16x8, wv);
            }
        // PV at K=32: B = V^T b128 fragments (8 consecutive actual keys).
        #pragma unroll
        for (int g = 0; g < 2; ++g) {
            bf16x8 bv8[4];
            #pragma unroll
            for (int nt = 0; nt < 4; ++nt) {
                int row = nt * 16 + l16;  // d
                int ch = (g * 4 + quad) ^ (row & 7);
                bv8[nt] = *(const bf16x8*)&Vs[buf][row * 64 + ch * 8];
            }
            #pragma unroll
            for (int mt = 0; mt < 2; ++mt)
                #pragma unroll
                for (int nt = 0; nt < 4; ++nt)
                    o[mt][nt] = __builtin_amdgcn_mfma_f32_16x16x32_bf16(pa8[g][mt], bv8[nt], o[mt][nt], 0, 0, 0);
        }
    }

    // row sums: each q-row l16's partials live in the 4 quads; reduce, redistribute
    #pragma unroll
    for (int mt = 0; mt < 2; ++mt) {
        float v = lrow[mt];
        v += __shfl_xor(v, 16);
        v += __shfl_xor(v, 32);
        #pragma unroll
        for (int reg = 0; reg < 4; ++reg) {
            float inv = 1.f / __shfl(v, quad * 4 + reg);
            int row = qbase + mt * 16 + quad * 4 + reg;
            size_t obase = ((size_t)b * SQ + row) * DM + h * 64;
            #pragma unroll
            for (int nt = 0; nt < 4; ++nt)
                outp[obase + nt * 16 + l16] = o[mt][nt][reg] * inv;
        }
    }
}

extern "C" void kernel_launch(void* const* d_in, const int* in_sizes, int n_in,
                              void* d_out, int out_size, void* d_ws, size_t ws_size,
                              hipStream_t stream) {
    (void)in_sizes; (void)n_in; (void)out_size; (void)ws_size;
    const float* Q  = (const float*)d_in[0];
    const float* K  = (const float*)d_in[1];
    const float* V  = (const float*)d_in[2];
    const int* mask = (const int*)d_in[3];
    const float* Wq = (const float*)d_in[4];
    const float* bq = (const float*)d_in[5];
    const float* Wk = (const float*)d_in[6];
    const float* bk = (const float*)d_in[7];
    const float* Wv = (const float*)d_in[8];
    const float* bv = (const float*)d_in[9];
    float* out = (float*)d_out;
    char* ws = (char*)d_ws;
    u16* q_ws  = (u16*)(ws);                                  // 16 MB  [b][h][s][d]
    u16* k_ws  = (u16*)(ws + (size_t)16 * 1024 * 1024);       // 16 MB  [b][h][prem(s)][d]
    u16* v_ws  = (u16*)(ws + (size_t)32 * 1024 * 1024);       // 16 MB  [b][h][d][s]
    u16* wbuf3 = (u16*)(ws + (size_t)48 * 1024 * 1024);       //  6 MB  [3][N][K] bf16
    float* mb  = (float*)(ws + (size_t)54 * 1024 * 1024);     // 32 KB

    cvt_wT3<<<dim3(16, 16, 3), 256, 0, stream>>>(Wq, Wk, Wv, wbuf3);
    mk_mbias<<<32, 256, 0, stream>>>(mask, mb);
    gemm3<<<dim3(64, 8, 3), 256, 0, stream>>>(Q, K, V, wbuf3, bq, bk, bv, q_ws);
    attn<<<dim3(64, 16), 256, 0, stream>>>(q_ws, k_ws, v_ws, mb, out);
}

// Round 14
// 309.201 us; speedup vs baseline: 1.5471x; 1.0019x over previous
//
#include <hip/hip_runtime.h>

#define NH 16
#define DM 1024
#define SQ 2048
#define BT 4

typedef __attribute__((ext_vector_type(8))) short bf16x8;
typedef __attribute__((ext_vector_type(4))) short sh4;
typedef __attribute__((ext_vector_type(4))) float f4;
typedef __attribute__((ext_vector_type(4))) float fv4;
typedef __attribute__((ext_vector_type(4))) unsigned uv4;
typedef unsigned short u16;

#define M2BIAS 23.083120654f   /* 16 * log2(e) */
#define SCALE2 0.18033688f     /* (1/8) * log2(e) */

__device__ __forceinline__ u16 f2bf(float f) {
    union { float f; unsigned u; } v; v.f = f;
    unsigned r = v.u + 0x7FFFu + ((v.u >> 16) & 1u);
    return (u16)(r >> 16);
}

__device__ __forceinline__ float fast_exp2(float x) {
#if __has_builtin(__builtin_amdgcn_exp2f)
    return __builtin_amdgcn_exp2f(x);
#else
    return exp2f(x);
#endif
}

// Key-position permutation: actual key s (within a 32-key group, s = 8q+4t+j)
// -> LDS/position index p = 16t + 4q + j. Makes the S^T output of two 16-key
// tiles land exactly in the A-fragment layout of mfma_f32_16x16x32_bf16
// (A[m=l16][k=8*quad+j] over actual keys), so PV needs no cross-lane exchange.
__device__ __forceinline__ int prem(int s) {
    return (s & ~31) | ((s & 4) << 2) | ((s >> 1) & 12) | (s & 3);
}

#define GLD16(gp, lp) __builtin_amdgcn_global_load_lds( \
    (const __attribute__((address_space(1))) void*)(gp), \
    (__attribute__((address_space(3))) void*)(lp), 16, 0, 0)

// ---------------- fp32 W[K][N] -> bf16 Wt[N][K], all three weights in one launch ----------------
__global__ __launch_bounds__(256) void cvt_wT3(const float* __restrict__ W0, const float* __restrict__ W1,
                                               const float* __restrict__ W2, u16* __restrict__ Wt) {
    __shared__ float t[64][65];
    const float* Wsrc = blockIdx.z == 0 ? W0 : (blockIdx.z == 1 ? W1 : W2);
    u16* dst = Wt + (size_t)blockIdx.z * DM * DM;
    int r0 = blockIdx.x * 64, c0 = blockIdx.y * 64;
    #pragma unroll
    for (int i = 0; i < 16; ++i) {
        int idx = i * 256 + threadIdx.x;
        int r = idx >> 6, c = idx & 63;
        t[r][c] = Wsrc[(size_t)(r0 + r) * DM + c0 + c];
    }
    __syncthreads();
    #pragma unroll
    for (int i = 0; i < 16; ++i) {
        int idx = i * 256 + threadIdx.x;
        int n = idx >> 6, k = idx & 63;
        dst[(size_t)(c0 + n) * DM + r0 + k] = f2bf(t[k][n]);
    }
}

// ---------------- fused projection GEMMs: z in {Q,K,V}, [8192,1024]x[1024,1024]+bias ----------------
// ROUND-5 main loop (best of 5 measured variants). A fp32 -> regs -> cvt_pk ->
// swizzled LDS; B via GLD16 double-buffered; counted vmcnt(12).
// r12: LDS-staged coalesced epilogue (WRITE 71->48MB). r13: chunk XOR-swizzle
// on the staging tile (bank conflicts 4.46M->262K, -5us).
// r14: mk_mbias folded in — blocks (x<32, y==0, z==2) compute the 8192-elem
// mask bias BEFORE stageB(0,0)/loadA(0), so the implicit A(0) wait drains the
// mask load + mb store and the counted vmcnt(12) arithmetic is untouched.
// mb completes within this kernel; attn (next launch) consumes it.
// z=0: Q -> [b][h][s][d];  z=1: K -> [b][h][prem(s)][d];  z=2: V -> [b][h][d][s]
__global__ __launch_bounds__(256, 3) void gemm3(const float* __restrict__ Qf, const float* __restrict__ Kf,
                                                const float* __restrict__ Vf, const u16* __restrict__ Wt3,
                                                const float* __restrict__ bq, const float* __restrict__ bk,
                                                const float* __restrict__ bv, u16* __restrict__ out3,
                                                const int* __restrict__ mask, float* __restrict__ mb) {
    __shared__ u16 As[128 * 64];
    __shared__ u16 Bs[2][128 * 64];
    int z = blockIdx.z;
    const float* Af = z == 0 ? Qf : (z == 1 ? Kf : Vf);
    const float* bias = z == 0 ? bq : (z == 1 ? bk : bv);
    int vmode = z == 0 ? 0 : (z == 1 ? 2 : 1);
    const u16* Bg = Wt3 + (size_t)z * DM * DM + (size_t)blockIdx.y * 128 * DM;
    u16* outp = out3 + (size_t)z * 8388608u;   // 8192*1024 u16 per projection

    int tid = threadIdx.x;
    int w = tid >> 6, lane = tid & 63, quad = lane >> 4, l16 = lane & 15;
    int wm = w >> 1, wn = w & 1;
    int r8 = lane >> 3, cg = (lane & 7) ^ r8;

    int arow0 = w * 32 + (lane >> 4);
    int acol = (lane & 15) * 4;
    const float* Ag = Af + (size_t)(blockIdx.x * 128 + arow0) * DM + acol;
    int ach = (lane & 15) >> 1, asub = lane & 1;

    // fused mask-bias (issued before the pipeline loads so the implicit A(0)
    // wait drains it; see header comment)
    if (z == 2 && blockIdx.y == 0 && blockIdx.x < 32) {
        int i = blockIdx.x * 256 + tid;
        mb[prem(i)] = mask[i] ? -M2BIAS : -__builtin_inff();
    }

    f4 acc[4][4];
    #pragma unroll
    for (int mt = 0; mt < 4; ++mt)
        #pragma unroll
        for (int nt = 0; nt < 4; ++nt) acc[mt][nt] = f4{0.f, 0.f, 0.f, 0.f};

    fv4 ar[8];
    auto loadA = [&](int kt) {
        const float* src = Ag + kt * 64;
        #pragma unroll
        for (int j = 0; j < 8; ++j) ar[j] = *(const fv4*)(src + (size_t)j * 4 * DM);
    };
    auto stageB = [&](int buf, int kt) {
        int kofs = kt * 64 + cg * 8;
        #pragma unroll
        for (int c = 0; c < 4; ++c) {
            int rbase = w * 32 + c * 8;
            GLD16(Bg + (size_t)(rbase + r8) * DM + kofs, &Bs[buf][rbase * 64]);
        }
    };

    stageB(0, 0);
    loadA(0);

    for (int kt = 0; kt < 16; ++kt) {
        // prefetch next B tile into the other LDS buffer (stays in flight
        // across the barrier; covered by this iteration's MFMA phase)
        if (kt + 1 < 16) stageB((kt + 1) & 1, kt + 1);
        // convert current A regs -> swizzled LDS (implicit vmcnt here waits for
        // A(kt) and thereby also drains the older B(kt) GLD16s)
        #pragma unroll
        for (int j = 0; j < 8; ++j) {
            unsigned lo, hi;
            asm("v_cvt_pk_bf16_f32 %0, %1, %2" : "=v"(lo) : "v"(ar[j][0]), "v"(ar[j][1]));
            asm("v_cvt_pk_bf16_f32 %0, %1, %2" : "=v"(hi) : "v"(ar[j][2]), "v"(ar[j][3]));
            int row = arow0 + j * 4;
            uint2 pk; pk.x = lo; pk.y = hi;
            *(uint2*)&As[row * 64 + (ach ^ (row & 7)) * 8 + asub * 4] = pk;
        }
        // prefetch next A tile into the SAME regs (WAR: after converts read them)
        if (kt + 1 < 16) loadA(kt + 1);

        // pre-MFMA barrier: drain ds_writes + anything older than this
        // iteration's 12 prefetch loads; do NOT drain the prefetches.
        if (kt < 15) {
            asm volatile("s_waitcnt vmcnt(12) lgkmcnt(0)" ::: "memory");
        } else {
            asm volatile("s_waitcnt vmcnt(0) lgkmcnt(0)" ::: "memory");
        }
        __builtin_amdgcn_s_barrier();
        asm volatile("" ::: "memory");

        #pragma unroll
        for (int ks = 0; ks < 2; ++ks) {
            bf16x8 afr[4], bfr[4];
            #pragma unroll
            for (int mt = 0; mt < 4; ++mt) {
                int row = wm * 64 + mt * 16 + l16;
                int ch = (ks * 4 + quad) ^ (row & 7);
                afr[mt] = *(const bf16x8*)&As[row * 64 + ch * 8];
            }
            #pragma unroll
            for (int nt = 0; nt < 4; ++nt) {
                int row = wn * 64 + nt * 16 + l16;
                int ch = (ks * 4 + quad) ^ (row & 7);
                bfr[nt] = *(const bf16x8*)&Bs[kt & 1][row * 64 + ch * 8];
            }
            #pragma unroll
            for (int mt = 0; mt < 4; ++mt)
                #pragma unroll
                for (int nt = 0; nt < 4; ++nt)
                    acc[mt][nt] = __builtin_amdgcn_mfma_f32_16x16x32_bf16(afr[mt], bfr[nt], acc[mt][nt], 0, 0, 0);
        }
        // post-MFMA barrier: all waves' LDS reads done before next iteration's
        // As/Bs writes.
        asm volatile("" ::: "memory");
        __builtin_amdgcn_s_barrier();
        asm volatile("" ::: "memory");
    }

    // ---- epilogue: stage C-tile (bias-added bf16) in LDS, then 16B coalesced stores ----
    // Swizzled tile: (row,col) -> row*128 + ((col>>3) ^ ((row>>1)&7))*8 + (col&7).
    u16* tile = &Bs[0][0];   // 128 x 128 u16 = 32 KB exactly
    #pragma unroll
    for (int nt = 0; nt < 4; ++nt) {
        int cl = wn * 64 + nt * 16 + l16;                 // local ncol
        float bn = bias[blockIdx.y * 128 + cl];
        #pragma unroll
        for (int mt = 0; mt < 4; ++mt) {
            int sl = wm * 64 + mt * 16 + quad * 4;        // local s (base of 4)
            #pragma unroll
            for (int reg = 0; reg < 4; ++reg) {
                u16 v = f2bf(acc[mt][nt][reg] + bn);
                if (vmode == 1) {
                    int row = cl, col = sl + reg;         // [ncol][s]
                    tile[row * 128 + (((col >> 3) ^ ((row >> 1) & 7)) << 3) + (col & 7)] = v;
                } else {
                    int row = sl + reg, col = cl;         // [s][ncol]
                    tile[row * 128 + (((col >> 3) ^ ((row >> 1) & 7)) << 3) + (col & 7)] = v;
                }
            }
        }
    }
    __syncthreads();
    int sbase = blockIdx.x * 128;
    int bidx = sbase >> 11, s0b = sbase & 2047;
    #pragma unroll
    for (int i = 0; i < 8; ++i) {
        int chunk = i * 256 + tid;            // 2048 chunks of 8 u16 (16B)
        int row = chunk >> 4, cc = chunk & 15;
        bf16x8 val = *(const bf16x8*)&tile[row * 128 + ((cc ^ ((row >> 1) & 7)) << 3)];
        size_t gidx;
        if (vmode == 1) {
            // out[b][h][d][s]: tile row = local ncol, 8 consecutive s
            int ncol = blockIdx.y * 128 + row;
            gidx = (((size_t)bidx * NH + (ncol >> 6)) * 64 + (ncol & 63)) * SQ + s0b + cc * 8;
        } else {
            // out[b][h][s][d]: tile row = local s, 8 consecutive d (within one h)
            int s = s0b + row;
            int sg = (vmode == 2) ? prem(s) : s;
            int ncol0 = blockIdx.y * 128 + cc * 8;
            gidx = (((size_t)bidx * NH + (ncol0 >> 6)) * SQ + sg) * 64 + (ncol0 & 63);
        }
        *(bf16x8*)&outp[gidx] = val;
    }
}

// ---------------- flash attention (S^T form, register-resident P, K=32 PV) ----------------
// EXACT round-2 structure, measured 98.2us / passed (r8 V-direct = 157us
// uncoalesced; r9 setprio = ~+8us; r10 cvt_pk-pack variant = NaN fail — all
// reverted). S^T = K*Q^T with K rows in permuted position space: lane
// (quad,l16)'s S-regs over tile pair (2g,2g+1) hold actual keys g*32+8q+0..7
// for q-row l16 — the A-fragment of mfma_f32_16x16x32_bf16, so PV runs at
// K=32 (16 MFMAs/iter) with B = V^T b128 fragments. P packed to bf16
// immediately after exp2 (bit-ops) so the f32 scores die before PV.
__global__ __launch_bounds__(256, 4) void attn(const u16* __restrict__ qw, const u16* __restrict__ kw,
                                               const u16* __restrict__ vtw, const float* __restrict__ mbias,
                                               float* __restrict__ outp) {
    __shared__ u16 Ks[2][64 * 64];   // [key-position][64 d], 16B-chunk XOR swizzled
    __shared__ u16 Vs[2][64 * 64];   // [d][64 keys], 16B-chunk XOR swizzled
    int tid = threadIdx.x;
    int w = tid >> 6, lane = tid & 63, quad = lane >> 4, l16 = lane & 15;
    int r8 = lane >> 3, sl = lane & 7;
    int bh = blockIdx.x, b = bh >> 4;   // grid.x = bh for XCD L2 locality
    int h = bh & 15;
    int qbase = blockIdx.y * 128 + w * 32;
    const u16* qp = qw + (size_t)bh * SQ * 64;
    const u16* kp = kw + (size_t)bh * SQ * 64;
    const u16* vp = vtw + (size_t)bh * 64 * SQ;
    const float* mbp = mbias + b * SQ;

    bf16x8 aq[2][2];  // Q frags (B-operand of S^T)
    #pragma unroll
    for (int mt = 0; mt < 2; ++mt)
        #pragma unroll
        for (int ks = 0; ks < 2; ++ks)
            aq[mt][ks] = *(const bf16x8*)&qp[(size_t)(qbase + mt * 16 + l16) * 64 + ks * 32 + quad * 8];

    f4 o[2][4];
    float lrow[2] = {0.f, 0.f};  // per-lane partial row-sum for q-row l16
    #pragma unroll
    for (int mt = 0; mt < 2; ++mt)
        #pragma unroll
        for (int nt = 0; nt < 4; ++nt) o[mt][nt] = f4{0.f, 0.f, 0.f, 0.f};

    auto stage = [&](int buf, int k0) {
        #pragma unroll
        for (int j = 0; j < 2; ++j) {
            int row = w * 16 + j * 8 + r8;
            int gsl = sl ^ (row & 7);
            GLD16(kp + (size_t)(k0 + row) * 64 + gsl * 8, &Ks[buf][(w * 16 + j * 8) * 64]);
            GLD16(vp + (size_t)row * SQ + k0 + gsl * 8, &Vs[buf][(w * 16 + j * 8) * 64]);
        }
    };

    stage(0, 0);
    for (int kb = 0; kb < 32; ++kb) {
        int buf = kb & 1;
        int k0 = kb * 64;
        __syncthreads();  // staging of `buf` done; all waves done reading buf^1
        // mask-bias loads BEFORE the prefetch so their vmcnt wait doesn't drain it
        fv4 bias4[4];
        #pragma unroll
        for (int kt = 0; kt < 4; ++kt)
            bias4[kt] = *(const fv4*)&mbp[k0 + kt * 16 + quad * 4];
        if (kb + 1 < 32) stage(buf ^ 1, k0 + 64);

        // K frags (A-operand of S^T)
        bf16x8 bk[4][2];
        #pragma unroll
        for (int kt = 0; kt < 4; ++kt)
            #pragma unroll
            for (int ks = 0; ks < 2; ++ks) {
                int r = kt * 16 + l16;
                int slot = (ks * 4 + quad) ^ (r & 7);
                bk[kt][ks] = *(const bf16x8*)&Ks[buf][r * 64 + slot * 8];
            }
        // S^T[kt][mt]: lane(quad,l16) regs = key-positions 16kt+4quad+r, q-row = l16
        f4 S[4][2];
        #pragma unroll
        for (int kt = 0; kt < 4; ++kt)
            #pragma unroll
            for (int mt = 0; mt < 2; ++mt) {
                f4 s = f4{0.f, 0.f, 0.f, 0.f};
                s = __builtin_amdgcn_mfma_f32_16x16x32_bf16(bk[kt][0], aq[mt][0], s, 0, 0, 0);
                s = __builtin_amdgcn_mfma_f32_16x16x32_bf16(bk[kt][1], aq[mt][1], s, 0, 0, 0);
                S[kt][mt] = s;
            }
        // softmax numerator + IMMEDIATE bf16 pack: per 32-key group g, the tile
        // pair (2g,2g+1) becomes one A-fragment pa8[g][mt] (keys g*32+8q+0..7).
        bf16x8 pa8[2][2];
        #pragma unroll
        for (int g = 0; g < 2; ++g)
            #pragma unroll
            for (int mt = 0; mt < 2; ++mt) {
                f4 se = S[2 * g][mt], so = S[2 * g + 1][mt];
                float p0 = fast_exp2(se[0] * SCALE2 + bias4[2 * g][0]);
                float p1 = fast_exp2(se[1] * SCALE2 + bias4[2 * g][1]);
                float p2 = fast_exp2(se[2] * SCALE2 + bias4[2 * g][2]);
                float p3 = fast_exp2(se[3] * SCALE2 + bias4[2 * g][3]);
                float q0 = fast_exp2(so[0] * SCALE2 + bias4[2 * g + 1][0]);
                float q1 = fast_exp2(so[1] * SCALE2 + bias4[2 * g + 1][1]);
                float q2 = fast_exp2(so[2] * SCALE2 + bias4[2 * g + 1][2]);
                float q3 = fast_exp2(so[3] * SCALE2 + bias4[2 * g + 1][3]);
                lrow[mt] += ((p0 + p1) + (p2 + p3)) + ((q0 + q1) + (q2 + q3));
                uv4 wv;
                wv[0] = (__float_as_uint(p1) & 0xFFFF0000u) | (__float_as_uint(p0) >> 16);
                wv[1] = (__float_as_uint(p3) & 0xFFFF0000u) | (__float_as_uint(p2) >> 16);
                wv[2] = (__float_as_uint(q1) & 0xFFFF0000u) | (__float_as_uint(q0) >> 16);
                wv[3] = (__float_as_uint(q3) & 0xFFFF0000u) | (__float_as_uint(q2) >> 16);
                pa8[g][mt] = __builtin_bit_cast(bf16x8, wv);
            }
        // PV at K=32: B = V^T b128 fragments (8 consecutive actual keys).
        #pragma unroll
        for (int g = 0; g < 2; ++g) {
            bf16x8 bv8[4];
            #pragma unroll
            for (int nt = 0; nt < 4; ++nt) {
                int row = nt * 16 + l16;  // d
                int ch = (g * 4 + quad) ^ (row & 7);
                bv8[nt] = *(const bf16x8*)&Vs[buf][row * 64 + ch * 8];
            }
            #pragma unroll
            for (int mt = 0; mt < 2; ++mt)
                #pragma unroll
                for (int nt = 0; nt < 4; ++nt)
                    o[mt][nt] = __builtin_amdgcn_mfma_f32_16x16x32_bf16(pa8[g][mt], bv8[nt], o[mt][nt], 0, 0, 0);
        }
    }

    // row sums: each q-row l16's partials live in the 4 quads; reduce, redistribute
    #pragma unroll
    for (int mt = 0; mt < 2; ++mt) {
        float v = lrow[mt];
        v += __shfl_xor(v, 16);
        v += __shfl_xor(v, 32);
        #pragma unroll
        for (int reg = 0; reg < 4; ++reg) {
            float inv = 1.f / __shfl(v, quad * 4 + reg);
            int row = qbase + mt * 16 + quad * 4 + reg;
            size_t obase = ((size_t)b * SQ + row) * DM + h * 64;
            #pragma unroll
            for (int nt = 0; nt < 4; ++nt)
                outp[obase + nt * 16 + l16] = o[mt][nt][reg] * inv;
        }
    }
}

extern "C" void kernel_launch(void* const* d_in, const int* in_sizes, int n_in,
                              void* d_out, int out_size, void* d_ws, size_t ws_size,
                              hipStream_t stream) {
    (void)in_sizes; (void)n_in; (void)out_size; (void)ws_size;
    const float* Q  = (const float*)d_in[0];
    const float* K  = (const float*)d_in[1];
    const float* V  = (const float*)d_in[2];
    const int* mask = (const int*)d_in[3];
    const float* Wq = (const float*)d_in[4];
    const float* bq = (const float*)d_in[5];
    const float* Wk = (const float*)d_in[6];
    const float* bk = (const float*)d_in[7];
    const float* Wv = (const float*)d_in[8];
    const float* bv = (const float*)d_in[9];
    float* out = (float*)d_out;
    char* ws = (char*)d_ws;
    u16* q_ws  = (u16*)(ws);                                  // 16 MB  [b][h][s][d]
    u16* k_ws  = (u16*)(ws + (size_t)16 * 1024 * 1024);       // 16 MB  [b][h][prem(s)][d]
    u16* v_ws  = (u16*)(ws + (size_t)32 * 1024 * 1024);       // 16 MB  [b][h][d][s]
    u16* wbuf3 = (u16*)(ws + (size_t)48 * 1024 * 1024);       //  6 MB  [3][N][K] bf16
    float* mb  = (float*)(ws + (size_t)54 * 1024 * 1024);     // 32 KB

    cvt_wT3<<<dim3(16, 16, 3), 256, 0, stream>>>(Wq, Wk, Wv, wbuf3);
    gemm3<<<dim3(64, 8, 3), 256, 0, stream>>>(Q, K, V, wbuf3, bq, bk, bv, q_ws, mask, mb);
    attn<<<dim3(64, 16), 256, 0, stream>>>(q_ws, k_ws, v_ws, mb, out);
}

// Round 15
// 297.271 us; speedup vs baseline: 1.6092x; 1.0401x over previous
//
#include <hip/hip_runtime.h>

#define NH 16
#define DM 1024
#define SQ 2048
#define BT 4

typedef __attribute__((ext_vector_type(8))) short bf16x8;
typedef __attribute__((ext_vector_type(4))) short sh4;
typedef __attribute__((ext_vector_type(4))) float f4;
typedef __attribute__((ext_vector_type(4))) float fv4;
typedef __attribute__((ext_vector_type(4))) unsigned uv4;
typedef unsigned short u16;

#define M2BIAS 23.083120654f   /* 16 * log2(e) */
#define SCALE2 0.18033688f     /* (1/8) * log2(e) */

__device__ __forceinline__ u16 f2bf(float f) {
    union { float f; unsigned u; } v; v.f = f;
    unsigned r = v.u + 0x7FFFu + ((v.u >> 16) & 1u);
    return (u16)(r >> 16);
}

__device__ __forceinline__ float fast_exp2(float x) {
#if __has_builtin(__builtin_amdgcn_exp2f)
    return __builtin_amdgcn_exp2f(x);
#else
    return exp2f(x);
#endif
}

// Key-position permutation: actual key s (within a 32-key group, s = 8q+4t+j)
// -> LDS/position index p = 16t + 4q + j. Makes the S^T output of two 16-key
// tiles land exactly in the A-fragment layout of mfma_f32_16x16x32_bf16
// (A[m=l16][k=8*quad+j] over actual keys), so PV needs no cross-lane exchange.
__device__ __forceinline__ int prem(int s) {
    return (s & ~31) | ((s & 4) << 2) | ((s >> 1) & 12) | (s & 3);
}

#define GLD16(gp, lp) __builtin_amdgcn_global_load_lds( \
    (const __attribute__((address_space(1))) void*)(gp), \
    (__attribute__((address_space(3))) void*)(lp), 16, 0, 0)

// ---------------- fp32 W[K][N] -> bf16 Wt[N][K], all three weights in one launch ----------------
__global__ __launch_bounds__(256) void cvt_wT3(const float* __restrict__ W0, const float* __restrict__ W1,
                                               const float* __restrict__ W2, u16* __restrict__ Wt) {
    __shared__ float t[64][65];
    const float* Wsrc = blockIdx.z == 0 ? W0 : (blockIdx.z == 1 ? W1 : W2);
    u16* dst = Wt + (size_t)blockIdx.z * DM * DM;
    int r0 = blockIdx.x * 64, c0 = blockIdx.y * 64;
    #pragma unroll
    for (int i = 0; i < 16; ++i) {
        int idx = i * 256 + threadIdx.x;
        int r = idx >> 6, c = idx & 63;
        t[r][c] = Wsrc[(size_t)(r0 + r) * DM + c0 + c];
    }
    __syncthreads();
    #pragma unroll
    for (int i = 0; i < 16; ++i) {
        int idx = i * 256 + threadIdx.x;
        int n = idx >> 6, k = idx & 63;
        dst[(size_t)(c0 + n) * DM + r0 + k] = f2bf(t[k][n]);
    }
}

// ---------------- fused projection GEMMs: z in {Q,K,V}, [8192,1024]x[1024,1024]+bias ----------------
// ROUND-5 main loop (best of 5 measured variants). A fp32 -> regs -> cvt_pk ->
// swizzled LDS; B via GLD16 double-buffered; counted vmcnt(12).
// r12: LDS-staged coalesced epilogue (WRITE 71->48MB). r13: chunk XOR-swizzle
// on the staging tile (bank conflicts 4.46M->262K, -5us). r14: mk_mbias folded
// in (neutral; kept — one fewer launch).
// z=0: Q -> [b][h][s][d];  z=1: K -> [b][h][prem(s)][d];  z=2: V -> [b][h][d][s]
__global__ __launch_bounds__(256, 3) void gemm3(const float* __restrict__ Qf, const float* __restrict__ Kf,
                                                const float* __restrict__ Vf, const u16* __restrict__ Wt3,
                                                const float* __restrict__ bq, const float* __restrict__ bk,
                                                const float* __restrict__ bv, u16* __restrict__ out3,
                                                const int* __restrict__ mask, float* __restrict__ mb) {
    __shared__ u16 As[128 * 64];
    __shared__ u16 Bs[2][128 * 64];
    int z = blockIdx.z;
    const float* Af = z == 0 ? Qf : (z == 1 ? Kf : Vf);
    const float* bias = z == 0 ? bq : (z == 1 ? bk : bv);
    int vmode = z == 0 ? 0 : (z == 1 ? 2 : 1);
    const u16* Bg = Wt3 + (size_t)z * DM * DM + (size_t)blockIdx.y * 128 * DM;
    u16* outp = out3 + (size_t)z * 8388608u;   // 8192*1024 u16 per projection

    int tid = threadIdx.x;
    int w = tid >> 6, lane = tid & 63, quad = lane >> 4, l16 = lane & 15;
    int wm = w >> 1, wn = w & 1;
    int r8 = lane >> 3, cg = (lane & 7) ^ r8;

    int arow0 = w * 32 + (lane >> 4);
    int acol = (lane & 15) * 4;
    const float* Ag = Af + (size_t)(blockIdx.x * 128 + arow0) * DM + acol;
    int ach = (lane & 15) >> 1, asub = lane & 1;

    // fused mask-bias (issued before the pipeline loads so the implicit A(0)
    // wait drains it)
    if (z == 2 && blockIdx.y == 0 && blockIdx.x < 32) {
        int i = blockIdx.x * 256 + tid;
        mb[prem(i)] = mask[i] ? -M2BIAS : -__builtin_inff();
    }

    f4 acc[4][4];
    #pragma unroll
    for (int mt = 0; mt < 4; ++mt)
        #pragma unroll
        for (int nt = 0; nt < 4; ++nt) acc[mt][nt] = f4{0.f, 0.f, 0.f, 0.f};

    fv4 ar[8];
    auto loadA = [&](int kt) {
        const float* src = Ag + kt * 64;
        #pragma unroll
        for (int j = 0; j < 8; ++j) ar[j] = *(const fv4*)(src + (size_t)j * 4 * DM);
    };
    auto stageB = [&](int buf, int kt) {
        int kofs = kt * 64 + cg * 8;
        #pragma unroll
        for (int c = 0; c < 4; ++c) {
            int rbase = w * 32 + c * 8;
            GLD16(Bg + (size_t)(rbase + r8) * DM + kofs, &Bs[buf][rbase * 64]);
        }
    };

    stageB(0, 0);
    loadA(0);

    for (int kt = 0; kt < 16; ++kt) {
        // prefetch next B tile into the other LDS buffer (stays in flight
        // across the barrier; covered by this iteration's MFMA phase)
        if (kt + 1 < 16) stageB((kt + 1) & 1, kt + 1);
        // convert current A regs -> swizzled LDS (implicit vmcnt here waits for
        // A(kt) and thereby also drains the older B(kt) GLD16s)
        #pragma unroll
        for (int j = 0; j < 8; ++j) {
            unsigned lo, hi;
            asm("v_cvt_pk_bf16_f32 %0, %1, %2" : "=v"(lo) : "v"(ar[j][0]), "v"(ar[j][1]));
            asm("v_cvt_pk_bf16_f32 %0, %1, %2" : "=v"(hi) : "v"(ar[j][2]), "v"(ar[j][3]));
            int row = arow0 + j * 4;
            uint2 pk; pk.x = lo; pk.y = hi;
            *(uint2*)&As[row * 64 + (ach ^ (row & 7)) * 8 + asub * 4] = pk;
        }
        // prefetch next A tile into the SAME regs (WAR: after converts read them)
        if (kt + 1 < 16) loadA(kt + 1);

        // pre-MFMA barrier: drain ds_writes + anything older than this
        // iteration's 12 prefetch loads; do NOT drain the prefetches.
        if (kt < 15) {
            asm volatile("s_waitcnt vmcnt(12) lgkmcnt(0)" ::: "memory");
        } else {
            asm volatile("s_waitcnt vmcnt(0) lgkmcnt(0)" ::: "memory");
        }
        __builtin_amdgcn_s_barrier();
        asm volatile("" ::: "memory");

        #pragma unroll
        for (int ks = 0; ks < 2; ++ks) {
            bf16x8 afr[4], bfr[4];
            #pragma unroll
            for (int mt = 0; mt < 4; ++mt) {
                int row = wm * 64 + mt * 16 + l16;
                int ch = (ks * 4 + quad) ^ (row & 7);
                afr[mt] = *(const bf16x8*)&As[row * 64 + ch * 8];
            }
            #pragma unroll
            for (int nt = 0; nt < 4; ++nt) {
                int row = wn * 64 + nt * 16 + l16;
                int ch = (ks * 4 + quad) ^ (row & 7);
                bfr[nt] = *(const bf16x8*)&Bs[kt & 1][row * 64 + ch * 8];
            }
            #pragma unroll
            for (int mt = 0; mt < 4; ++mt)
                #pragma unroll
                for (int nt = 0; nt < 4; ++nt)
                    acc[mt][nt] = __builtin_amdgcn_mfma_f32_16x16x32_bf16(afr[mt], bfr[nt], acc[mt][nt], 0, 0, 0);
        }
        // post-MFMA barrier: all waves' LDS reads done before next iteration's
        // As/Bs writes.
        asm volatile("" ::: "memory");
        __builtin_amdgcn_s_barrier();
        asm volatile("" ::: "memory");
    }

    // ---- epilogue: stage C-tile (bias-added bf16) in LDS, then 16B coalesced stores ----
    // Swizzled tile: (row,col) -> row*128 + ((col>>3) ^ ((row>>1)&7))*8 + (col&7).
    u16* tile = &Bs[0][0];   // 128 x 128 u16 = 32 KB exactly
    #pragma unroll
    for (int nt = 0; nt < 4; ++nt) {
        int cl = wn * 64 + nt * 16 + l16;                 // local ncol
        float bn = bias[blockIdx.y * 128 + cl];
        #pragma unroll
        for (int mt = 0; mt < 4; ++mt) {
            int sl = wm * 64 + mt * 16 + quad * 4;        // local s (base of 4)
            #pragma unroll
            for (int reg = 0; reg < 4; ++reg) {
                u16 v = f2bf(acc[mt][nt][reg] + bn);
                if (vmode == 1) {
                    int row = cl, col = sl + reg;         // [ncol][s]
                    tile[row * 128 + (((col >> 3) ^ ((row >> 1) & 7)) << 3) + (col & 7)] = v;
                } else {
                    int row = sl + reg, col = cl;         // [s][ncol]
                    tile[row * 128 + (((col >> 3) ^ ((row >> 1) & 7)) << 3) + (col & 7)] = v;
                }
            }
        }
    }
    __syncthreads();
    int sbase = blockIdx.x * 128;
    int bidx = sbase >> 11, s0b = sbase & 2047;
    #pragma unroll
    for (int i = 0; i < 8; ++i) {
        int chunk = i * 256 + tid;            // 2048 chunks of 8 u16 (16B)
        int row = chunk >> 4, cc = chunk & 15;
        bf16x8 val = *(const bf16x8*)&tile[row * 128 + ((cc ^ ((row >> 1) & 7)) << 3)];
        size_t gidx;
        if (vmode == 1) {
            // out[b][h][d][s]: tile row = local ncol, 8 consecutive s
            int ncol = blockIdx.y * 128 + row;
            gidx = (((size_t)bidx * NH + (ncol >> 6)) * 64 + (ncol & 63)) * SQ + s0b + cc * 8;
        } else {
            // out[b][h][s][d]: tile row = local s, 8 consecutive d (within one h)
            int s = s0b + row;
            int sg = (vmode == 2) ? prem(s) : s;
            int ncol0 = blockIdx.y * 128 + cc * 8;
            gidx = (((size_t)bidx * NH + (ncol0 >> 6)) * SQ + sg) * 64 + (ncol0 & 63);
        }
        *(bf16x8*)&outp[gidx] = val;
    }
}

// ---------------- flash attention (S^T form, register-resident P, K=32 PV) ----------------
// Round-2 structure (98.2us; r8 V-direct = 157us uncoalesced; r9 setprio =
// +8us; r10 cvt_pk-pack = NaN — all reverted). r15: mask-bias staged into LDS
// ONCE per block (8KB, coalesced) instead of per-iteration global loads —
// removes 128 vmem ops/block from the loop and the bias-before-prefetch
// ordering constraint; in-loop bias reads are quad-uniform LDS broadcasts
// drained by the existing syncthreads. Bytes identical -> absmax unchanged.
// LDS 32->40KB, still 4 blocks/CU (160/40).
__global__ __launch_bounds__(256, 4) void attn(const u16* __restrict__ qw, const u16* __restrict__ kw,
                                               const u16* __restrict__ vtw, const float* __restrict__ mbias,
                                               float* __restrict__ outp) {
    __shared__ u16 Ks[2][64 * 64];   // [key-position][64 d], 16B-chunk XOR swizzled
    __shared__ u16 Vs[2][64 * 64];   // [d][64 keys], 16B-chunk XOR swizzled
    __shared__ float mbL[SQ];        // 8 KB: whole mask-bias row for this batch
    int tid = threadIdx.x;
    int w = tid >> 6, lane = tid & 63, quad = lane >> 4, l16 = lane & 15;
    int r8 = lane >> 3, sl = lane & 7;
    int bh = blockIdx.x, b = bh >> 4;   // grid.x = bh for XCD L2 locality
    int h = bh & 15;
    int qbase = blockIdx.y * 128 + w * 32;
    const u16* qp = qw + (size_t)bh * SQ * 64;
    const u16* kp = kw + (size_t)bh * SQ * 64;
    const u16* vp = vtw + (size_t)bh * 64 * SQ;
    const float* mbp = mbias + b * SQ;

    // stage mask-bias row into LDS (coalesced; ordered by the kb=0 syncthreads)
    #pragma unroll
    for (int i = 0; i < 2; ++i) {
        int idx = (i * 256 + tid) * 4;
        *(fv4*)&mbL[idx] = *(const fv4*)&mbp[idx];
    }

    bf16x8 aq[2][2];  // Q frags (B-operand of S^T)
    #pragma unroll
    for (int mt = 0; mt < 2; ++mt)
        #pragma unroll
        for (int ks = 0; ks < 2; ++ks)
            aq[mt][ks] = *(const bf16x8*)&qp[(size_t)(qbase + mt * 16 + l16) * 64 + ks * 32 + quad * 8];

    f4 o[2][4];
    float lrow[2] = {0.f, 0.f};  // per-lane partial row-sum for q-row l16
    #pragma unroll
    for (int mt = 0; mt < 2; ++mt)
        #pragma unroll
        for (int nt = 0; nt < 4; ++nt) o[mt][nt] = f4{0.f, 0.f, 0.f, 0.f};

    auto stage = [&](int buf, int k0) {
        #pragma unroll
        for (int j = 0; j < 2; ++j) {
            int row = w * 16 + j * 8 + r8;
            int gsl = sl ^ (row & 7);
            GLD16(kp + (size_t)(k0 + row) * 64 + gsl * 8, &Ks[buf][(w * 16 + j * 8) * 64]);
            GLD16(vp + (size_t)row * SQ + k0 + gsl * 8, &Vs[buf][(w * 16 + j * 8) * 64]);
        }
    };

    stage(0, 0);
    for (int kb = 0; kb < 32; ++kb) {
        int buf = kb & 1;
        int k0 = kb * 64;
        __syncthreads();  // staging of `buf` done; all waves done reading buf^1
        if (kb + 1 < 32) stage(buf ^ 1, k0 + 64);

        // mask-bias from LDS (quad-uniform -> broadcast, conflict-free)
        fv4 bias4[4];
        #pragma unroll
        for (int kt = 0; kt < 4; ++kt)
            bias4[kt] = *(const fv4*)&mbL[k0 + kt * 16 + quad * 4];

        // K frags (A-operand of S^T)
        bf16x8 bk[4][2];
        #pragma unroll
        for (int kt = 0; kt < 4; ++kt)
            #pragma unroll
            for (int ks = 0; ks < 2; ++ks) {
                int r = kt * 16 + l16;
                int slot = (ks * 4 + quad) ^ (r & 7);
                bk[kt][ks] = *(const bf16x8*)&Ks[buf][r * 64 + slot * 8];
            }
        // S^T[kt][mt]: lane(quad,l16) regs = key-positions 16kt+4quad+r, q-row = l16
        f4 S[4][2];
        #pragma unroll
        for (int kt = 0; kt < 4; ++kt)
            #pragma unroll
            for (int mt = 0; mt < 2; ++mt) {
                f4 s = f4{0.f, 0.f, 0.f, 0.f};
                s = __builtin_amdgcn_mfma_f32_16x16x32_bf16(bk[kt][0], aq[mt][0], s, 0, 0, 0);
                s = __builtin_amdgcn_mfma_f32_16x16x32_bf16(bk[kt][1], aq[mt][1], s, 0, 0, 0);
                S[kt][mt] = s;
            }
        // softmax numerator + IMMEDIATE bf16 pack: per 32-key group g, the tile
        // pair (2g,2g+1) becomes one A-fragment pa8[g][mt] (keys g*32+8q+0..7).
        bf16x8 pa8[2][2];
        #pragma unroll
        for (int g = 0; g < 2; ++g)
            #pragma unroll
            for (int mt = 0; mt < 2; ++mt) {
                f4 se = S[2 * g][mt], so = S[2 * g + 1][mt];
                float p0 = fast_exp2(se[0] * SCALE2 + bias4[2 * g][0]);
                float p1 = fast_exp2(se[1] * SCALE2 + bias4[2 * g][1]);
                float p2 = fast_exp2(se[2] * SCALE2 + bias4[2 * g][2]);
                float p3 = fast_exp2(se[3] * SCALE2 + bias4[2 * g][3]);
                float q0 = fast_exp2(so[0] * SCALE2 + bias4[2 * g + 1][0]);
                float q1 = fast_exp2(so[1] * SCALE2 + bias4[2 * g + 1][1]);
                float q2 = fast_exp2(so[2] * SCALE2 + bias4[2 * g + 1][2]);
                float q3 = fast_exp2(so[3] * SCALE2 + bias4[2 * g + 1][3]);
                lrow[mt] += ((p0 + p1) + (p2 + p3)) + ((q0 + q1) + (q2 + q3));
                uv4 wv;
                wv[0] = (__float_as_uint(p1) & 0xFFFF0000u) | (__float_as_uint(p0) >> 16);
                wv[1] = (__float_as_uint(p3) & 0xFFFF0000u) | (__float_as_uint(p2) >> 16);
                wv[2] = (__float_as_uint(q1) & 0xFFFF0000u) | (__float_as_uint(q0) >> 16);
                wv[3] = (__float_as_uint(q3) & 0xFFFF0000u) | (__float_as_uint(q2) >> 16);
                pa8[g][mt] = __builtin_bit_cast(bf16x8, wv);
            }
        // PV at K=32: B = V^T b128 fragments (8 consecutive actual keys).
        #pragma unroll
        for (int g = 0; g < 2; ++g) {
            bf16x8 bv8[4];
            #pragma unroll
            for (int nt = 0; nt < 4; ++nt) {
                int row = nt * 16 + l16;  // d
                int ch = (g * 4 + quad) ^ (row & 7);
                bv8[nt] = *(const bf16x8*)&Vs[buf][row * 64 + ch * 8];
            }
            #pragma unroll
            for (int mt = 0; mt < 2; ++mt)
                #pragma unroll
                for (int nt = 0; nt < 4; ++nt)
                    o[mt][nt] = __builtin_amdgcn_mfma_f32_16x16x32_bf16(pa8[g][mt], bv8[nt], o[mt][nt], 0, 0, 0);
        }
    }

    // row sums: each q-row l16's partials live in the 4 quads; reduce, redistribute
    #pragma unroll
    for (int mt = 0; mt < 2; ++mt) {
        float v = lrow[mt];
        v += __shfl_xor(v, 16);
        v += __shfl_xor(v, 32);
        #pragma unroll
        for (int reg = 0; reg < 4; ++reg) {
            float inv = 1.f / __shfl(v, quad * 4 + reg);
            int row = qbase + mt * 16 + quad * 4 + reg;
            size_t obase = ((size_t)b * SQ + row) * DM + h * 64;
            #pragma unroll
            for (int nt = 0; nt < 4; ++nt)
                outp[obase + nt * 16 + l16] = o[mt][nt][reg] * inv;
        }
    }
}

extern "C" void kernel_launch(void* const* d_in, const int* in_sizes, int n_in,
                              void* d_out, int out_size, void* d_ws, size_t ws_size,
                              hipStream_t stream) {
    (void)in_sizes; (void)n_in; (void)out_size; (void)ws_size;
    const float* Q  = (const float*)d_in[0];
    const float* K  = (const float*)d_in[1];
    const float* V  = (const float*)d_in[2];
    const int* mask = (const int*)d_in[3];
    const float* Wq = (const float*)d_in[4];
    const float* bq = (const float*)d_in[5];
    const float* Wk = (const float*)d_in[6];
    const float* bk = (const float*)d_in[7];
    const float* Wv = (const float*)d_in[8];
    const float* bv = (const float*)d_in[9];
    float* out = (float*)d_out;
    char* ws = (char*)d_ws;
    u16* q_ws  = (u16*)(ws);                                  // 16 MB  [b][h][s][d]
    u16* k_ws  = (u16*)(ws + (size_t)16 * 1024 * 1024);       // 16 MB  [b][h][prem(s)][d]
    u16* v_ws  = (u16*)(ws + (size_t)32 * 1024 * 1024);       // 16 MB  [b][h][d][s]
    u16* wbuf3 = (u16*)(ws + (size_t)48 * 1024 * 1024);       //  6 MB  [3][N][K] bf16
    float* mb  = (float*)(ws + (size_t)54 * 1024 * 1024);     // 32 KB

    cvt_wT3<<<dim3(16, 16, 3), 256, 0, stream>>>(Wq, Wk, Wv, wbuf3);
    gemm3<<<dim3(64, 8, 3), 256, 0, stream>>>(Q, K, V, wbuf3, bq, bk, bv, q_ws, mask, mb);
    attn<<<dim3(64, 16), 256, 0, stream>>>(q_ws, k_ws, v_ws, mb, out);
}

// Round 16
// 293.180 us; speedup vs baseline: 1.6316x; 1.0140x over previous
//
#include <hip/hip_runtime.h>

#define NH 16
#define DM 1024
#define SQ 2048
#define BT 4

typedef __attribute__((ext_vector_type(8))) short bf16x8;
typedef __attribute__((ext_vector_type(4))) short sh4;
typedef __attribute__((ext_vector_type(4))) float f4;
typedef __attribute__((ext_vector_type(4))) float fv4;
typedef __attribute__((ext_vector_type(4))) unsigned uv4;
typedef unsigned short u16;

#define M2BIAS 23.083120654f   /* 16 * log2(e) */
#define SCALE2 0.18033688f     /* (1/8) * log2(e) */

__device__ __forceinline__ u16 f2bf(float f) {
    union { float f; unsigned u; } v; v.f = f;
    unsigned r = v.u + 0x7FFFu + ((v.u >> 16) & 1u);
    return (u16)(r >> 16);
}

__device__ __forceinline__ float fast_exp2(float x) {
#if __has_builtin(__builtin_amdgcn_exp2f)
    return __builtin_amdgcn_exp2f(x);
#else
    return exp2f(x);
#endif
}

// Key-position permutation: actual key s (within a 32-key group, s = 8q+4t+j)
// -> LDS/position index p = 16t + 4q + j. Makes the S^T output of two 16-key
// tiles land exactly in the A-fragment layout of mfma_f32_16x16x32_bf16
// (A[m=l16][k=8*quad+j] over actual keys), so PV needs no cross-lane exchange.
__device__ __forceinline__ int prem(int s) {
    return (s & ~31) | ((s & 4) << 2) | ((s >> 1) & 12) | (s & 3);
}

#define GLD16(gp, lp) __builtin_amdgcn_global_load_lds( \
    (const __attribute__((address_space(1))) void*)(gp), \
    (__attribute__((address_space(3))) void*)(lp), 16, 0, 0)

// ---------------- fp32 W[K][N] -> bf16 Wt[N][K], all three weights in one launch ----------------
// r16: vectorized global access — fv4 16B loads (4 iters vs 16) and sh4 8B
// stores (values/order bit-identical). LDS t[64][65] stores stay scalar (odd
// stride 65 spreads banks; an fv4 LDS store would be unaligned for odd rows).
__global__ __launch_bounds__(256) void cvt_wT3(const float* __restrict__ W0, const float* __restrict__ W1,
                                               const float* __restrict__ W2, u16* __restrict__ Wt) {
    __shared__ float t[64][65];
    const float* Wsrc = blockIdx.z == 0 ? W0 : (blockIdx.z == 1 ? W1 : W2);
    u16* dst = Wt + (size_t)blockIdx.z * DM * DM;
    int r0 = blockIdx.x * 64, c0 = blockIdx.y * 64;
    #pragma unroll
    for (int i = 0; i < 4; ++i) {
        int idx = i * 256 + threadIdx.x;
        int r = idx >> 4, c4 = (idx & 15) * 4;
        fv4 v = *(const fv4*)&Wsrc[(size_t)(r0 + r) * DM + c0 + c4];
        #pragma unroll
        for (int j = 0; j < 4; ++j) t[r][c4 + j] = v[j];
    }
    __syncthreads();
    #pragma unroll
    for (int i = 0; i < 4; ++i) {
        int idx = i * 256 + threadIdx.x;
        int n = idx >> 4, k4 = (idx & 15) * 4;
        sh4 pk;
        #pragma unroll
        for (int j = 0; j < 4; ++j) pk[j] = (short)f2bf(t[k4 + j][n]);
        *(sh4*)&dst[(size_t)(c0 + n) * DM + r0 + k4] = pk;
    }
}

// ---------------- fused projection GEMMs: z in {Q,K,V}, [8192,1024]x[1024,1024]+bias ----------------
// ROUND-5 main loop (best of 5 measured variants). A fp32 -> regs -> cvt_pk ->
// swizzled LDS; B via GLD16 double-buffered; counted vmcnt(12).
// r12: LDS-staged coalesced epilogue (WRITE 71->48MB). r13: chunk XOR-swizzle
// on the staging tile (bank conflicts 4.46M->262K, -5us). r14: mk_mbias folded
// in (neutral; kept — one fewer launch).
// z=0: Q -> [b][h][s][d];  z=1: K -> [b][h][prem(s)][d];  z=2: V -> [b][h][d][s]
__global__ __launch_bounds__(256, 3) void gemm3(const float* __restrict__ Qf, const float* __restrict__ Kf,
                                                const float* __restrict__ Vf, const u16* __restrict__ Wt3,
                                                const float* __restrict__ bq, const float* __restrict__ bk,
                                                const float* __restrict__ bv, u16* __restrict__ out3,
                                                const int* __restrict__ mask, float* __restrict__ mb) {
    __shared__ u16 As[128 * 64];
    __shared__ u16 Bs[2][128 * 64];
    int z = blockIdx.z;
    const float* Af = z == 0 ? Qf : (z == 1 ? Kf : Vf);
    const float* bias = z == 0 ? bq : (z == 1 ? bk : bv);
    int vmode = z == 0 ? 0 : (z == 1 ? 2 : 1);
    const u16* Bg = Wt3 + (size_t)z * DM * DM + (size_t)blockIdx.y * 128 * DM;
    u16* outp = out3 + (size_t)z * 8388608u;   // 8192*1024 u16 per projection

    int tid = threadIdx.x;
    int w = tid >> 6, lane = tid & 63, quad = lane >> 4, l16 = lane & 15;
    int wm = w >> 1, wn = w & 1;
    int r8 = lane >> 3, cg = (lane & 7) ^ r8;

    int arow0 = w * 32 + (lane >> 4);
    int acol = (lane & 15) * 4;
    const float* Ag = Af + (size_t)(blockIdx.x * 128 + arow0) * DM + acol;
    int ach = (lane & 15) >> 1, asub = lane & 1;

    // fused mask-bias (issued before the pipeline loads so the implicit A(0)
    // wait drains it)
    if (z == 2 && blockIdx.y == 0 && blockIdx.x < 32) {
        int i = blockIdx.x * 256 + tid;
        mb[prem(i)] = mask[i] ? -M2BIAS : -__builtin_inff();
    }

    f4 acc[4][4];
    #pragma unroll
    for (int mt = 0; mt < 4; ++mt)
        #pragma unroll
        for (int nt = 0; nt < 4; ++nt) acc[mt][nt] = f4{0.f, 0.f, 0.f, 0.f};

    fv4 ar[8];
    auto loadA = [&](int kt) {
        const float* src = Ag + kt * 64;
        #pragma unroll
        for (int j = 0; j < 8; ++j) ar[j] = *(const fv4*)(src + (size_t)j * 4 * DM);
    };
    auto stageB = [&](int buf, int kt) {
        int kofs = kt * 64 + cg * 8;
        #pragma unroll
        for (int c = 0; c < 4; ++c) {
            int rbase = w * 32 + c * 8;
            GLD16(Bg + (size_t)(rbase + r8) * DM + kofs, &Bs[buf][rbase * 64]);
        }
    };

    stageB(0, 0);
    loadA(0);

    for (int kt = 0; kt < 16; ++kt) {
        // prefetch next B tile into the other LDS buffer (stays in flight
        // across the barrier; covered by this iteration's MFMA phase)
        if (kt + 1 < 16) stageB((kt + 1) & 1, kt + 1);
        // convert current A regs -> swizzled LDS (implicit vmcnt here waits for
        // A(kt) and thereby also drains the older B(kt) GLD16s)
        #pragma unroll
        for (int j = 0; j < 8; ++j) {
            unsigned lo, hi;
            asm("v_cvt_pk_bf16_f32 %0, %1, %2" : "=v"(lo) : "v"(ar[j][0]), "v"(ar[j][1]));
            asm("v_cvt_pk_bf16_f32 %0, %1, %2" : "=v"(hi) : "v"(ar[j][2]), "v"(ar[j][3]));
            int row = arow0 + j * 4;
            uint2 pk; pk.x = lo; pk.y = hi;
            *(uint2*)&As[row * 64 + (ach ^ (row & 7)) * 8 + asub * 4] = pk;
        }
        // prefetch next A tile into the SAME regs (WAR: after converts read them)
        if (kt + 1 < 16) loadA(kt + 1);

        // pre-MFMA barrier: drain ds_writes + anything older than this
        // iteration's 12 prefetch loads; do NOT drain the prefetches.
        if (kt < 15) {
            asm volatile("s_waitcnt vmcnt(12) lgkmcnt(0)" ::: "memory");
        } else {
            asm volatile("s_waitcnt vmcnt(0) lgkmcnt(0)" ::: "memory");
        }
        __builtin_amdgcn_s_barrier();
        asm volatile("" ::: "memory");

        #pragma unroll
        for (int ks = 0; ks < 2; ++ks) {
            bf16x8 afr[4], bfr[4];
            #pragma unroll
            for (int mt = 0; mt < 4; ++mt) {
                int row = wm * 64 + mt * 16 + l16;
                int ch = (ks * 4 + quad) ^ (row & 7);
                afr[mt] = *(const bf16x8*)&As[row * 64 + ch * 8];
            }
            #pragma unroll
            for (int nt = 0; nt < 4; ++nt) {
                int row = wn * 64 + nt * 16 + l16;
                int ch = (ks * 4 + quad) ^ (row & 7);
                bfr[nt] = *(const bf16x8*)&Bs[kt & 1][row * 64 + ch * 8];
            }
            #pragma unroll
            for (int mt = 0; mt < 4; ++mt)
                #pragma unroll
                for (int nt = 0; nt < 4; ++nt)
                    acc[mt][nt] = __builtin_amdgcn_mfma_f32_16x16x32_bf16(afr[mt], bfr[nt], acc[mt][nt], 0, 0, 0);
        }
        // post-MFMA barrier: all waves' LDS reads done before next iteration's
        // As/Bs writes.
        asm volatile("" ::: "memory");
        __builtin_amdgcn_s_barrier();
        asm volatile("" ::: "memory");
    }

    // ---- epilogue: stage C-tile (bias-added bf16) in LDS, then 16B coalesced stores ----
    // Swizzled tile: (row,col) -> row*128 + ((col>>3) ^ ((row>>1)&7))*8 + (col&7).
    u16* tile = &Bs[0][0];   // 128 x 128 u16 = 32 KB exactly
    #pragma unroll
    for (int nt = 0; nt < 4; ++nt) {
        int cl = wn * 64 + nt * 16 + l16;                 // local ncol
        float bn = bias[blockIdx.y * 128 + cl];
        #pragma unroll
        for (int mt = 0; mt < 4; ++mt) {
            int sl = wm * 64 + mt * 16 + quad * 4;        // local s (base of 4)
            #pragma unroll
            for (int reg = 0; reg < 4; ++reg) {
                u16 v = f2bf(acc[mt][nt][reg] + bn);
                if (vmode == 1) {
                    int row = cl, col = sl + reg;         // [ncol][s]
                    tile[row * 128 + (((col >> 3) ^ ((row >> 1) & 7)) << 3) + (col & 7)] = v;
                } else {
                    int row = sl + reg, col = cl;         // [s][ncol]
                    tile[row * 128 + (((col >> 3) ^ ((row >> 1) & 7)) << 3) + (col & 7)] = v;
                }
            }
        }
    }
    __syncthreads();
    int sbase = blockIdx.x * 128;
    int bidx = sbase >> 11, s0b = sbase & 2047;
    #pragma unroll
    for (int i = 0; i < 8; ++i) {
        int chunk = i * 256 + tid;            // 2048 chunks of 8 u16 (16B)
        int row = chunk >> 4, cc = chunk & 15;
        bf16x8 val = *(const bf16x8*)&tile[row * 128 + ((cc ^ ((row >> 1) & 7)) << 3)];
        size_t gidx;
        if (vmode == 1) {
            // out[b][h][d][s]: tile row = local ncol, 8 consecutive s
            int ncol = blockIdx.y * 128 + row;
            gidx = (((size_t)bidx * NH + (ncol >> 6)) * 64 + (ncol & 63)) * SQ + s0b + cc * 8;
        } else {
            // out[b][h][s][d]: tile row = local s, 8 consecutive d (within one h)
            int s = s0b + row;
            int sg = (vmode == 2) ? prem(s) : s;
            int ncol0 = blockIdx.y * 128 + cc * 8;
            gidx = (((size_t)bidx * NH + (ncol0 >> 6)) * SQ + sg) * 64 + (ncol0 & 63);
        }
        *(bf16x8*)&outp[gidx] = val;
    }
}

// ---------------- flash attention (S^T form, register-resident P, K=32 PV) ----------------
// Round-2 structure (98.2us) + r15 mask-bias-in-LDS (-12us: removed the last
// in-loop global access; in-loop bias reads are quad-uniform LDS broadcasts).
// S^T = K*Q^T with K rows in permuted position space: lane (quad,l16)'s S-regs
// over tile pair (2g,2g+1) hold actual keys g*32+8q+0..7 for q-row l16 — the
// A-fragment of mfma_f32_16x16x32_bf16, so PV runs at K=32 (16 MFMAs/iter)
// with B = V^T b128 fragments. P packed to bf16 immediately after exp2.
__global__ __launch_bounds__(256, 4) void attn(const u16* __restrict__ qw, const u16* __restrict__ kw,
                                               const u16* __restrict__ vtw, const float* __restrict__ mbias,
                                               float* __restrict__ outp) {
    __shared__ u16 Ks[2][64 * 64];   // [key-position][64 d], 16B-chunk XOR swizzled
    __shared__ u16 Vs[2][64 * 64];   // [d][64 keys], 16B-chunk XOR swizzled
    __shared__ float mbL[SQ];        // 8 KB: whole mask-bias row for this batch
    int tid = threadIdx.x;
    int w = tid >> 6, lane = tid & 63, quad = lane >> 4, l16 = lane & 15;
    int r8 = lane >> 3, sl = lane & 7;
    int bh = blockIdx.x, b = bh >> 4;   // grid.x = bh for XCD L2 locality
    int h = bh & 15;
    int qbase = blockIdx.y * 128 + w * 32;
    const u16* qp = qw + (size_t)bh * SQ * 64;
    const u16* kp = kw + (size_t)bh * SQ * 64;
    const u16* vp = vtw + (size_t)bh * 64 * SQ;
    const float* mbp = mbias + b * SQ;

    // stage mask-bias row into LDS (coalesced; ordered by the kb=0 syncthreads)
    #pragma unroll
    for (int i = 0; i < 2; ++i) {
        int idx = (i * 256 + tid) * 4;
        *(fv4*)&mbL[idx] = *(const fv4*)&mbp[idx];
    }

    bf16x8 aq[2][2];  // Q frags (B-operand of S^T)
    #pragma unroll
    for (int mt = 0; mt < 2; ++mt)
        #pragma unroll
        for (int ks = 0; ks < 2; ++ks)
            aq[mt][ks] = *(const bf16x8*)&qp[(size_t)(qbase + mt * 16 + l16) * 64 + ks * 32 + quad * 8];

    f4 o[2][4];
    float lrow[2] = {0.f, 0.f};  // per-lane partial row-sum for q-row l16
    #pragma unroll
    for (int mt = 0; mt < 2; ++mt)
        #pragma unroll
        for (int nt = 0; nt < 4; ++nt) o[mt][nt] = f4{0.f, 0.f, 0.f, 0.f};

    auto stage = [&](int buf, int k0) {
        #pragma unroll
        for (int j = 0; j < 2; ++j) {
            int row = w * 16 + j * 8 + r8;
            int gsl = sl ^ (row & 7);
            GLD16(kp + (size_t)(k0 + row) * 64 + gsl * 8, &Ks[buf][(w * 16 + j * 8) * 64]);
            GLD16(vp + (size_t)row * SQ + k0 + gsl * 8, &Vs[buf][(w * 16 + j * 8) * 64]);
        }
    };

    stage(0, 0);
    for (int kb = 0; kb < 32; ++kb) {
        int buf = kb & 1;
        int k0 = kb * 64;
        __syncthreads();  // staging of `buf` done; all waves done reading buf^1
        if (kb + 1 < 32) stage(buf ^ 1, k0 + 64);

        // mask-bias from LDS (quad-uniform -> broadcast, conflict-free)
        fv4 bias4[4];
        #pragma unroll
        for (int kt = 0; kt < 4; ++kt)
            bias4[kt] = *(const fv4*)&mbL[k0 + kt * 16 + quad * 4];

        // K frags (A-operand of S^T)
        bf16x8 bk[4][2];
        #pragma unroll
        for (int kt = 0; kt < 4; ++kt)
            #pragma unroll
            for (int ks = 0; ks < 2; ++ks) {
                int r = kt * 16 + l16;
                int slot = (ks * 4 + quad) ^ (r & 7);
                bk[kt][ks] = *(const bf16x8*)&Ks[buf][r * 64 + slot * 8];
            }
        // S^T[kt][mt]: lane(quad,l16) regs = key-positions 16kt+4quad+r, q-row = l16
        f4 S[4][2];
        #pragma unroll
        for (int kt = 0; kt < 4; ++kt)
            #pragma unroll
            for (int mt = 0; mt < 2; ++mt) {
                f4 s = f4{0.f, 0.f, 0.f, 0.f};
                s = __builtin_amdgcn_mfma_f32_16x16x32_bf16(bk[kt][0], aq[mt][0], s, 0, 0, 0);
                s = __builtin_amdgcn_mfma_f32_16x16x32_bf16(bk[kt][1], aq[mt][1], s, 0, 0, 0);
                S[kt][mt] = s;
            }
        // softmax numerator + IMMEDIATE bf16 pack: per 32-key group g, the tile
        // pair (2g,2g+1) becomes one A-fragment pa8[g][mt] (keys g*32+8q+0..7).
        bf16x8 pa8[2][2];
        #pragma unroll
        for (int g = 0; g < 2; ++g)
            #pragma unroll
            for (int mt = 0; mt < 2; ++mt) {
                f4 se = S[2 * g][mt], so = S[2 * g + 1][mt];
                float p0 = fast_exp2(se[0] * SCALE2 + bias4[2 * g][0]);
                float p1 = fast_exp2(se[1] * SCALE2 + bias4[2 * g][1]);
                float p2 = fast_exp2(se[2] * SCALE2 + bias4[2 * g][2]);
                float p3 = fast_exp2(se[3] * SCALE2 + bias4[2 * g][3]);
                float q0 = fast_exp2(so[0] * SCALE2 + bias4[2 * g + 1][0]);
                float q1 = fast_exp2(so[1] * SCALE2 + bias4[2 * g + 1][1]);
                float q2 = fast_exp2(so[2] * SCALE2 + bias4[2 * g + 1][2]);
                float q3 = fast_exp2(so[3] * SCALE2 + bias4[2 * g + 1][3]);
                lrow[mt] += ((p0 + p1) + (p2 + p3)) + ((q0 + q1) + (q2 + q3));
                uv4 wv;
                wv[0] = (__float_as_uint(p1) & 0xFFFF0000u) | (__float_as_uint(p0) >> 16);
                wv[1] = (__float_as_uint(p3) & 0xFFFF0000u) | (__float_as_uint(p2) >> 16);
                wv[2] = (__float_as_uint(q1) & 0xFFFF0000u) | (__float_as_uint(q0) >> 16);
                wv[3] = (__float_as_uint(q3) & 0xFFFF0000u) | (__float_as_uint(q2) >> 16);
                pa8[g][mt] = __builtin_bit_cast(bf16x8, wv);
            }
        // PV at K=32: B = V^T b128 fragments (8 consecutive actual keys).
        #pragma unroll
        for (int g = 0; g < 2; ++g) {
            bf16x8 bv8[4];
            #pragma unroll
            for (int nt = 0; nt < 4; ++nt) {
                int row = nt * 16 + l16;  // d
                int ch = (g * 4 + quad) ^ (row & 7);
                bv8[nt] = *(const bf16x8*)&Vs[buf][row * 64 + ch * 8];
            }
            #pragma unroll
            for (int mt = 0; mt < 2; ++mt)
                #pragma unroll
                for (int nt = 0; nt < 4; ++nt)
                    o[mt][nt] = __builtin_amdgcn_mfma_f32_16x16x32_bf16(pa8[g][mt], bv8[nt], o[mt][nt], 0, 0, 0);
        }
    }

    // row sums: each q-row l16's partials live in the 4 quads; reduce, redistribute
    #pragma unroll
    for (int mt = 0; mt < 2; ++mt) {
        float v = lrow[mt];
        v += __shfl_xor(v, 16);
        v += __shfl_xor(v, 32);
        #pragma unroll
        for (int reg = 0; reg < 4; ++reg) {
            float inv = 1.f / __shfl(v, quad * 4 + reg);
            int row = qbase + mt * 16 + quad * 4 + reg;
            size_t obase = ((size_t)b * SQ + row) * DM + h * 64;
            #pragma unroll
            for (int nt = 0; nt < 4; ++nt)
                outp[obase + nt * 16 + l16] = o[mt][nt][reg] * inv;
        }
    }
}

extern "C" void kernel_launch(void* const* d_in, const int* in_sizes, int n_in,
                              void* d_out, int out_size, void* d_ws, size_t ws_size,
                              hipStream_t stream) {
    (void)in_sizes; (void)n_in; (void)out_size; (void)ws_size;
    const float* Q  = (const float*)d_in[0];
    const float* K  = (const float*)d_in[1];
    const float* V  = (const float*)d_in[2];
    const int* mask = (const int*)d_in[3];
    const float* Wq = (const float*)d_in[4];
    const float* bq = (const float*)d_in[5];
    const float* Wk = (const float*)d_in[6];
    const float* bk = (const float*)d_in[7];
    const float* Wv = (const float*)d_in[8];
    const float* bv = (const float*)d_in[9];
    float* out = (float*)d_out;
    char* ws = (char*)d_ws;
    u16* q_ws  = (u16*)(ws);                                  // 16 MB  [b][h][s][d]
    u16* k_ws  = (u16*)(ws + (size_t)16 * 1024 * 1024);       // 16 MB  [b][h][prem(s)][d]
    u16* v_ws  = (u16*)(ws + (size_t)32 * 1024 * 1024);       // 16 MB  [b][h][d][s]
    u16* wbuf3 = (u16*)(ws + (size_t)48 * 1024 * 1024);       //  6 MB  [3][N][K] bf16
    float* mb  = (float*)(ws + (size_t)54 * 1024 * 1024);     // 32 KB

    cvt_wT3<<<dim3(16, 16, 3), 256, 0, stream>>>(Wq, Wk, Wv, wbuf3);
    gemm3<<<dim3(64, 8, 3), 256, 0, stream>>>(Q, K, V, wbuf3, bq, bk, bv, q_ws, mask, mb);
    attn<<<dim3(64, 16), 256, 0, stream>>>(q_ws, k_ws, v_ws, mb, out);
}